// Round 7
// baseline (1250.578 us; speedup 1.0000x reference)
//
#include <hip/hip_runtime.h>
#include <math.h>

#define NN 20000
#define EE 100000
#define FIN 167
#define KP1 256    // layer-1 K padded to mult of 64
#define HID 1024   // H*O = 4*256
#define OO 256
#define NB 16      // nodes per k_gath block

typedef unsigned short u16;
typedef short bf16x8 __attribute__((ext_vector_type(8)));
typedef short s16x4  __attribute__((ext_vector_type(4)));
typedef float f32x4  __attribute__((ext_vector_type(4)));

__device__ __forceinline__ float bf(u16 u){ return __uint_as_float(((unsigned)u)<<16); }
__device__ __forceinline__ u16 fb(float v){            // f32 -> bf16 RNE
  unsigned u = __float_as_uint(v);
  return (u16)((u + 0x7FFFu + ((u>>16)&1u)) >> 16);
}
__device__ __forceinline__ float ldv(const float* p, long i){ return p[i]; }
__device__ __forceinline__ float ldv(const u16*   p, long i){ return bf(p[i]); }

// ---------------- CSR build ----------------
__global__ void k_count(const int* __restrict__ ei, int* __restrict__ counts){
  int e = blockIdx.x*256 + threadIdx.x;
  if (e < EE) atomicAdd(&counts[ei[EE+e]], 1);
}

__global__ __launch_bounds__(256) void k_scan(const int* __restrict__ counts, int* __restrict__ iptr){
  __shared__ int sd[256];
  int tid = threadIdx.x;
  int carry = 0;
  for (int base=0; base<NN; base+=256){
    int i = base+tid;
    int v = (i<NN)? counts[i] : 0;
    sd[tid]=v;
    __syncthreads();
    for (int off=1; off<256; off<<=1){
      int t = (tid>=off)? sd[tid-off] : 0;
      __syncthreads();
      sd[tid] += t;
      __syncthreads();
    }
    if (i<NN) iptr[i] = carry + sd[tid] - v;
    carry += sd[255];
    __syncthreads();
  }
  if (tid==0) iptr[NN]=carry;
}

__global__ void k_fill(const int* __restrict__ ei, const int* __restrict__ iptr,
                       int* __restrict__ cursor, int* __restrict__ eid){
  int e = blockIdx.x*256 + threadIdx.x;
  if (e < EE){
    int d = ei[EE+e];
    int pos = atomicAdd(&cursor[d],1);
    eid[iptr[d]+pos] = e;
  }
}

// ---------------- BatchNorm stats ----------------
// layer-1 (float input, F=167): original coalesced version
template<typename T>
__global__ void k_bnstats(const T* __restrict__ X, float* __restrict__ sums, int F){
  int f = blockIdx.y*256 + threadIdx.x;
  if (f >= F) return;
  int r0 = blockIdx.x*100, r1 = r0+100;
  float s=0.f, s2=0.f;
  for (int r=r0;r<r1;r++){ float v = ldv(X,(long)r*F+f); s += v; s2 += v*v; }
  atomicAdd(&sums[f], s);
  atomicAdd(&sums[F+f], s2);
}

// layers 2/3 (bf16 input, F=HID): bf16x8-vectorized, LDS-combined atomics.
// grid = 800 (25 rows/block) — full-GPU parallelism (round-6's grid=40 starved 216 CUs).
__global__ __launch_bounds__(256) void k_bnstats8(const u16* __restrict__ X, float* __restrict__ sums){
  int tid = threadIdx.x;
  int f8 = (tid & 127)*8;
  int rbase = blockIdx.x*25;            // grid.x = 800
  float s[8]={0,0,0,0,0,0,0,0}, s2[8]={0,0,0,0,0,0,0,0};
  for (int r=rbase + (tid>>7); r<rbase+25; r+=2){
    bf16x8 v = *(const bf16x8*)(X + (long)r*HID + f8);
    #pragma unroll
    for (int j=0;j<8;j++){ float x=bf((u16)v[j]); s[j]+=x; s2[j]+=x*x; }
  }
  __shared__ float red[256][8];
  #pragma unroll
  for (int j=0;j<8;j++) red[tid][j]=s[j];
  __syncthreads();
  if (tid<128){
    #pragma unroll
    for (int j=0;j<8;j++) atomicAdd(&sums[f8+j], red[tid][j]+red[tid+128][j]);
  }
  __syncthreads();
  #pragma unroll
  for (int j=0;j<8;j++) red[tid][j]=s2[j];
  __syncthreads();
  if (tid<128){
    #pragma unroll
    for (int j=0;j<8;j++) atomicAdd(&sums[HID+f8+j], red[tid][j]+red[tid+128][j]);
  }
}

__global__ void k_bnfin(const float* __restrict__ sums, const float* __restrict__ g,
                        const float* __restrict__ b, float* __restrict__ scale,
                        float* __restrict__ shift, int F){
  int f = blockIdx.x*256 + threadIdx.x;
  if (f >= F) return;
  float mu  = sums[f]   * (1.f/NN);
  float var = sums[F+f] * (1.f/NN) - mu*mu;
  float sc  = rsqrtf(var + 1e-5f) * g[f];
  scale[f] = sc;
  shift[f] = b[f] - mu*sc;
}

// ---------------- BN-folded fused weight prep ----------------
__global__ __launch_bounds__(256) void k_foldT(const float* __restrict__ Wg, const float* __restrict__ Wl,
                        const float* __restrict__ scale,
                        u16* __restrict__ Wt, int K, int Kp){
  __shared__ float t[32][33];
  int k0 = blockIdx.x*32, c0 = blockIdx.y*32;
  int tx = threadIdx.x & 31, ty = threadIdx.x >> 5;
  bool second = (c0 >= HID);
  const float* W = second ? Wl : Wg;
  int cc0 = second ? c0 - HID : c0;
  #pragma unroll
  for (int i=0;i<4;i++){
    int k = k0 + ty + i*8;
    t[ty+i*8][tx] = (k < K) ? W[(long)k*HID + cc0 + tx] * scale[k] : 0.f;
  }
  __syncthreads();
  #pragma unroll
  for (int i=0;i<4;i++){
    int c = c0 + ty + i*8;
    Wt[(long)c*Kp + k0 + tx] = fb(t[tx][ty+i*8]);
  }
}

// cst init: lb for lin half, 0 for hg half
__global__ void k_cinit(const float* __restrict__ lb, float* __restrict__ cst){
  int c = blockIdx.x*256 + threadIdx.x;
  if (c < 2*HID) cst[c] = (c >= HID) ? lb[c-HID] : 0.f;
}

// cst[c] += sum_k shift[k]*W[k][c]  — parallel reduction, coalesced
__global__ __launch_bounds__(256) void k_const(const float* __restrict__ Wg, const float* __restrict__ Wl,
                        const float* __restrict__ shift, float* __restrict__ cst, int K){
  int tx = threadIdx.x & 63, ty = threadIdx.x >> 6;
  int c = blockIdx.x*64 + tx;
  bool second = c >= HID;
  const float* W = second ? Wl : Wg;
  int cc = second ? c-HID : c;
  int k0 = blockIdx.y*128;
  int k1 = min(K, k0+128);
  float s = 0.f;
  for (int k=k0+ty; k<k1; k+=4) s += shift[k]*W[(long)k*HID+cc];
  __shared__ float red[256];
  red[threadIdx.x] = s;
  __syncthreads();
  if (ty == 0){
    float tot = red[tx] + red[tx+64] + red[tx+128] + red[tx+192];
    atomicAdd(&cst[c], tot);
  }
}

__global__ void k_cast(const float* __restrict__ x, u16* __restrict__ xb){
  long idx = (long)blockIdx.x*256 + threadIdx.x;
  if (idx >= (long)NN*KP1) return;
  int n = (int)(idx / KP1), k = (int)(idx % KP1);
  xb[idx] = (k<FIN)? fb(x[(long)n*FIN+k]) : (u16)0;
}

__global__ void k_we16(const float* __restrict__ We, u16* __restrict__ We16){
  int i = blockIdx.x*256 + threadIdx.x;
  if (i < 10*HID) We16[i] = fb(We[i]);
}

// ---------------- MFMA GEMM (round-4 verified, FROZEN) ----------------
#define MF(a_,b_,c_) __builtin_amdgcn_mfma_f32_16x16x32_bf16(a_,b_,c_,0,0,0)
#define FENCE asm volatile("" ::: "memory")
#define BAR do { FENCE; __builtin_amdgcn_s_barrier(); FENCE; } while(0)

__global__ __launch_bounds__(512,2) void k_gemm(const u16* __restrict__ A, int K,
                     const u16* __restrict__ Wt, const float* __restrict__ cst,
                     u16* __restrict__ Chg, u16* __restrict__ Clin){
  __shared__ u16 lds[2][24576];   // [buf][Ak0|Ak1|Bk0|Bk1] = 16K+16K+8K+8K bytes, total 96 KB
  int b = blockIdx.x;
  int wg = (b & 7)*158 + (b >> 3);          // 1264 % 8 == 0 -> bijective XCD swizzle
  int row0 = (wg >> 4)*256, col0 = (wg & 15)*128;
  int tid = threadIdx.x;
  int wave = tid >> 6, lane = tid & 63, quad = lane >> 4, lo = lane & 15;
  int wm = wave >> 1, wn = wave & 1;        // 4 M-waves x 2 N-waves, 64x64 out each
  const u16* Apt[2];
  #pragma unroll
  for (int i=0;i<2;i++){
    int s = i*512 + tid, srow = s>>2;
    int gr = row0 + srow; if (gr >= NN) gr = NN-1;      // clamp: garbage rows never stored
    Apt[i] = A + (long)gr*K + (((s&3)^(srow&3))*8);
  }
  int brow = tid>>2;
  const u16* Bpt = Wt + (long)(col0 + brow)*K + ((((tid&3)^(brow&3)))*8);
  const char* ldsc = (const char*)&lds[0][0];
  int axor = lo & 3;
  int aoff = (wm*64 + lo)*64 + ((quad^axor)*16);
  int boff = 32768 + (wn*64 + lo)*64 + ((quad^axor)*16);
  int NT = K >> 6;
  f32x4 acc[4][4] = {};
  {
    u16* d = (u16*)&lds[0][0];
    __builtin_amdgcn_global_load_lds(Apt[0],      d +          tid*8, 16, 0, 0);
    __builtin_amdgcn_global_load_lds(Apt[1],      d +  4096 +  tid*8, 16, 0, 0);
    __builtin_amdgcn_global_load_lds(Bpt,         d + 16384 +  tid*8, 16, 0, 0);
    __builtin_amdgcn_global_load_lds(Apt[0] + 32, d +  8192 +  tid*8, 16, 0, 0);
    __builtin_amdgcn_global_load_lds(Apt[1] + 32, d + 12288 +  tid*8, 16, 0, 0);
    __builtin_amdgcn_global_load_lds(Bpt    + 32, d + 20480 +  tid*8, 16, 0, 0);
    asm volatile("s_waitcnt vmcnt(3)" ::: "memory");
    BAR;
  }
  for (int t=0; t<NT; t++){
    const char* Lb = ldsc + (t&1)*49152;
    u16* Sb = (u16*)&lds[0][0] + ((t&1)^1)*24576;
    int k0n = (t+1) << 6;
    int nx = (t+1 < NT);
    bf16x8 af[4], bfr[4];
    #pragma unroll
    for (int i=0;i<4;i++) af[i]  = *(const bf16x8*)(Lb + aoff + i*1024);
    #pragma unroll
    for (int n=0;n<4;n++) bfr[n] = *(const bf16x8*)(Lb + boff + n*1024);
    if (nx){
      __builtin_amdgcn_global_load_lds(Apt[0] + k0n, Sb +          tid*8, 16, 0, 0);
      __builtin_amdgcn_global_load_lds(Apt[1] + k0n, Sb +  4096 +  tid*8, 16, 0, 0);
      __builtin_amdgcn_global_load_lds(Bpt    + k0n, Sb + 16384 +  tid*8, 16, 0, 0);
    }
    #pragma unroll
    for (int i=0;i<4;i++)
      #pragma unroll
      for (int n=0;n<4;n++)
        acc[i][n] = MF(af[i], bfr[n], acc[i][n]);
    if (nx) asm volatile("s_waitcnt vmcnt(3)" ::: "memory");
    else    asm volatile("s_waitcnt vmcnt(0)" ::: "memory");
    BAR;
    #pragma unroll
    for (int i=0;i<4;i++) af[i]  = *(const bf16x8*)(Lb + 16384 + aoff + i*1024);
    #pragma unroll
    for (int n=0;n<4;n++) bfr[n] = *(const bf16x8*)(Lb +  8192 + boff + n*1024);
    if (nx){
      __builtin_amdgcn_global_load_lds(Apt[0] + k0n + 32, Sb +  8192 +  tid*8, 16, 0, 0);
      __builtin_amdgcn_global_load_lds(Apt[1] + k0n + 32, Sb + 12288 +  tid*8, 16, 0, 0);
      __builtin_amdgcn_global_load_lds(Bpt    + k0n + 32, Sb + 20480 +  tid*8, 16, 0, 0);
    }
    #pragma unroll
    for (int i=0;i<4;i++)
      #pragma unroll
      for (int n=0;n<4;n++)
        acc[i][n] = MF(af[i], bfr[n], acc[i][n]);
    if (nx) asm volatile("s_waitcnt vmcnt(3)" ::: "memory");
    BAR;
  }
  #pragma unroll
  for (int i=0;i<4;i++){
    #pragma unroll
    for (int n=0;n<4;n++){
      int col = col0 + wn*64 + n*16 + lo;
      float cs = cst[col];
      #pragma unroll
      for (int r=0;r<4;r++){
        int row = row0 + wm*64 + i*16 + quad*4 + r;   // C/D: col=lane&15, row=quad*4+reg
        if (row < NN){
          u16 o = fb(acc[i][n][r] + cs);
          if (col < HID) Chg[(long)row*HID + col] = o;
          else           Clin[(long)row*HID + col - HID] = o;
        }
      }
    }
  }
}
#undef MF
#undef BAR
#undef FENCE

// ---------------- per-(node,head) attention dots: wave-parallel, coalesced ----------------
__global__ __launch_bounds__(256) void k_sdot(const u16* __restrict__ hg, const float* __restrict__ attn,
                       float* __restrict__ ssrc, float* __restrict__ sdst){
  int unit = blockIdx.x*4 + (threadIdx.x >> 6);   // one wave per (n,h)
  if (unit >= NN*4) return;
  int lane = threadIdx.x & 63;
  int n = unit >> 2, h = unit & 3;
  const u16* hp = hg + (long)n*HID + h*OO + lane*4;
  s16x4 v = *(const s16x4*)hp;
  float4 x0 = *(const float4*)(attn + h*OO + lane*4);
  float4 x1 = *(const float4*)(attn + HID + h*OO + lane*4);
  float f0 = bf((u16)v.x), f1 = bf((u16)v.y), f2 = bf((u16)v.z), f3 = bf((u16)v.w);
  float ss = f0*x0.x + f1*x0.y + f2*x0.z + f3*x0.w;
  float sd = f0*x1.x + f1*x1.y + f2*x1.z + f3*x1.w;
  #pragma unroll
  for (int off=32; off>0; off>>=1){
    ss += __shfl_down(ss, off);
    sd += __shfl_down(sd, off);
  }
  if (lane==0){ ssrc[unit]=ss; sdst[unit]=sd; }
}

__global__ void k_q(const float* __restrict__ We, const float* __restrict__ attn,
                    float* __restrict__ q){
  int t = threadIdx.x;
  if (t >= 40) return;
  int k = t >> 2, h = t & 3;
  float s = 0.f;
  for (int d=0; d<OO; d++) s += We[(long)k*HID + h*OO + d] * attn[2*HID + h*OO + d];
  q[k*4+h] = s;
}

// per-EDGE logits: ea read once, all 4 heads computed, float4 write
__global__ void k_logits(const int* __restrict__ ei, const float* __restrict__ ea,
                         const float* __restrict__ q, const float* __restrict__ at,
                         const float* __restrict__ ssrc, const float* __restrict__ sdst,
                         float* __restrict__ L){
  int e = blockIdx.x*256 + threadIdx.x;
  if (e >= EE) return;
  int s = ei[e], dd = ei[EE+e];
  float4 a0 = *(const float4*)(ea + (long)e*12);
  float4 a1 = *(const float4*)(ea + (long)e*12 + 4);
  float4 a2 = *(const float4*)(ea + (long)e*12 + 8);
  float t = a0.x;
  float cc[10] = {a0.y,a0.z,a0.w, a1.x,a1.y,a1.z,a1.w, a2.x,a2.y,a2.z};
  float4 ss = *(const float4*)(ssrc + (long)s*4);
  float4 sd = *(const float4*)(sdst + (long)dd*4);
  float sv[4] = {ss.x+sd.x, ss.y+sd.y, ss.z+sd.z, ss.w+sd.w};
  float4 out;
  #pragma unroll
  for (int h=0;h<4;h++){
    float se = 0.f;
    #pragma unroll
    for (int k=0;k<10;k++) se += cc[k]*q[k*4+h];
    float v = sv[h] + se + t*at[h];
    ((float*)&out)[h] = (v>0.f)? v : 0.2f*v;
  }
  *(float4*)(L + (long)e*4) = out;
}

// per-NODE softmax finalize: writes w = exp(L-m)*dinv IN PLACE into L (float4),
// accumulates cw[n][4][10] with ea read ONCE per edge
__global__ void k_mden(const int* __restrict__ iptr, const int* __restrict__ eid,
                       const float* __restrict__ ea, float* __restrict__ L,
                       float* __restrict__ cw){
  int n = blockIdx.x*256 + threadIdx.x;
  if (n >= NN) return;
  int b = iptr[n], e1 = iptr[n+1];
  float m0=-INFINITY, m1=-INFINITY, m2=-INFINITY, m3=-INFINITY;
  for (int i=b;i<e1;i++){
    float4 l = *(const float4*)(L + (long)eid[i]*4);
    m0=fmaxf(m0,l.x); m1=fmaxf(m1,l.y); m2=fmaxf(m2,l.z); m3=fmaxf(m3,l.w);
  }
  if (b==e1){ m0=m1=m2=m3=0.f; }
  float s0=0.f,s1=0.f,s2=0.f,s3=0.f;
  for (int i=b;i<e1;i++){
    float4 l = *(const float4*)(L + (long)eid[i]*4);
    s0+=expf(l.x-m0); s1+=expf(l.y-m1); s2+=expf(l.z-m2); s3+=expf(l.w-m3);
  }
  float d0=1.f/(s0+1e-16f), d1=1.f/(s1+1e-16f), d2=1.f/(s2+1e-16f), d3=1.f/(s3+1e-16f);
  float c[4][10] = {};
  for (int i=b;i<e1;i++){
    int e = eid[i];
    float4 l = *(const float4*)(L + (long)e*4);
    float4 w = { expf(l.x-m0)*d0, expf(l.y-m1)*d1, expf(l.z-m2)*d2, expf(l.w-m3)*d3 };
    *(float4*)(L + (long)e*4) = w;
    float4 a0 = *(const float4*)(ea + (long)e*12);
    float4 a1 = *(const float4*)(ea + (long)e*12 + 4);
    float4 a2 = *(const float4*)(ea + (long)e*12 + 8);
    float cc[10] = {a0.y,a0.z,a0.w, a1.x,a1.y,a1.z,a1.w, a2.x,a2.y,a2.z};
    #pragma unroll
    for (int k=0;k<10;k++){
      c[0][k] += w.x*cc[k]; c[1][k] += w.y*cc[k];
      c[2][k] += w.z*cc[k]; c[3][k] += w.w*cc[k];
    }
  }
  float* cp = cw + (long)n*40;
  #pragma unroll
  for (int h=0;h<4;h++)
    #pragma unroll
    for (int k=0;k<10;k++) cp[h*10+k] = c[h][k];
}

// ---------------- edge gather v3: 8B/lane vectorized h[src] gather ----------------
// thread t owns features [4t, 4t+4) — all in head h = t>>6, so ONE broadcast weight
// per edge per thread and one s16x4 (8B) load: 512B contiguous per wave per edge.
// Per-feature edge accumulation order identical to v2 -> bit-identical output.
__global__ __launch_bounds__(256) void k_gath(
    const u16* __restrict__ hg, const int* __restrict__ ei,
    const int* __restrict__ iptr, const int* __restrict__ eid,
    const float* __restrict__ L,      // holds w[e][h] (from k_mden)
    const float* __restrict__ cw,     // [NN][4][10]
    const u16* __restrict__ We16, const float* __restrict__ cb,
    u16* __restrict__ lio)
{
  __shared__ u16  sWe[10*HID];   // 20 KB
  __shared__ float scb[HID];     // 4 KB
  int tid = threadIdx.x;
  for (int i=tid;i<10*HID;i+=256) sWe[i] = We16[i];
  for (int i=tid;i<HID;i+=256) scb[i] = cb[i];
  __syncthreads();
  int h = tid >> 6;
  int f0 = tid*4;
  int d0 = blockIdx.x*NB, dend = min(NN, d0+NB);
  for (int d=d0; d<dend; d++){
    s16x4 a0 = *(const s16x4*)(lio + (long)d*HID + f0);
    float acc0=bf((u16)a0.x), acc1=bf((u16)a0.y), acc2=bf((u16)a0.z), acc3=bf((u16)a0.w);
    int b0 = iptr[d], en = iptr[d+1];
    for (int i=b0;i<en;i++){
      int e = eid[i], s_ = ei[e];
      float w = L[(long)e*4 + h];                       // wave-uniform broadcast
      s16x4 v = *(const s16x4*)(hg + (long)s_*HID + f0);
      acc0 += w*bf((u16)v.x); acc1 += w*bf((u16)v.y);
      acc2 += w*bf((u16)v.z); acc3 += w*bf((u16)v.w);
    }
    const float* cp = cw + (long)d*40 + h*10;
    float ew0=0.f, ew1=0.f, ew2=0.f, ew3=0.f;
    #pragma unroll
    for (int k=0;k<10;k++){
      float c = cp[k];
      s16x4 wv = *(const s16x4*)(sWe + k*HID + f0);
      ew0 += c*bf((u16)wv.x); ew1 += c*bf((u16)wv.y);
      ew2 += c*bf((u16)wv.z); ew3 += c*bf((u16)wv.w);
    }
    acc0 += ew0; acc1 += ew1; acc2 += ew2; acc3 += ew3;
    u16 o[4];
    o[0] = fb(fmaxf(acc0 + scb[f0  ], 0.f));
    o[1] = fb(fmaxf(acc1 + scb[f0+1], 0.f));
    o[2] = fb(fmaxf(acc2 + scb[f0+2], 0.f));
    o[3] = fb(fmaxf(acc3 + scb[f0+3], 0.f));
    *(s16x4*)(lio + (long)d*HID + f0) = *(const s16x4*)o;
  }
}

// ---------------- layer 3 ----------------
__global__ void k_c4init(const float* __restrict__ lb, float* __restrict__ c4){
  if (threadIdx.x==0 && blockIdx.x==0){ c4[0]=0.f; c4[1]=0.f; c4[2]=lb[0]; c4[3]=lb[1]; }
}

// fold BN scale into interleaved weights W4[k][4] = {Wg0,Wg1,lw0,lw1}*sc; shift -> c4
__global__ __launch_bounds__(256) void k_fold3(const float* __restrict__ Wg, const float* __restrict__ lw,
                        const float* __restrict__ scale, const float* __restrict__ shift,
                        float* __restrict__ W4, float* __restrict__ c4){
  int k = blockIdx.x*256 + threadIdx.x;   // grid 4, covers HID exactly
  float sc = scale[k], sh = shift[k];
  float w0=Wg[k*2], w1=Wg[k*2+1], l0=lw[k*2], l1=lw[k*2+1];
  float4 o = {w0*sc, w1*sc, l0*sc, l1*sc};
  *(float4*)(W4 + (long)k*4) = o;
  __shared__ float red[256][4];
  int tid = threadIdx.x;
  red[tid][0]=sh*w0; red[tid][1]=sh*w1; red[tid][2]=sh*l0; red[tid][3]=sh*l1;
  __syncthreads();
  for (int o2=128;o2>0;o2>>=1){
    if (tid<o2){
      #pragma unroll
      for (int j=0;j<4;j++) red[tid][j]+=red[tid+o2][j];
    }
    __syncthreads();
  }
  if (tid==0){
    #pragma unroll
    for (int j=0;j<4;j++) atomicAdd(&c4[j], red[0][j]);
  }
}

// wave-per-node GEMV: x-rows and W4 staged in LDS, shuffle reduce, no post-stage barriers
__global__ __launch_bounds__(256) void k_n3(const u16* __restrict__ in,
    const float* __restrict__ W4, const float* __restrict__ c4,
    const float* __restrict__ attn,
    float* __restrict__ hg3, float* __restrict__ lin3,
    float* __restrict__ ssrc, float* __restrict__ sdst)
{
  __shared__ float sW[HID*4];   // 16 KB
  __shared__ float sx[4][HID];  // 16 KB
  int tid = threadIdx.x;
  int n0 = blockIdx.x*4;        // grid 5000 exact
  for (int i=tid; i<HID; i+=256) *(float4*)&sW[i*4] = *(const float4*)(W4 + (long)i*4);
  for (int idx=tid; idx<512; idx+=256){
    int rr = idx>>7, ch = idx&127;
    bf16x8 v = *(const bf16x8*)(in + (long)(n0+rr)*HID + ch*8);
    #pragma unroll
    for (int j=0;j<8;j++) sx[rr][ch*8+j] = bf((u16)v[j]);
  }
  __syncthreads();
  int w = tid>>6, lane = tid&63;
  float p0=0.f,p1=0.f,p2=0.f,p3=0.f;
  #pragma unroll
  for (int g=0; g<16; g++){
    int k = g*64 + lane;                      // lanes consecutive -> conflict-free
    float x = sx[w][k];
    float4 wv = *(const float4*)&sW[k*4];
    p0 += x*wv.x; p1 += x*wv.y; p2 += x*wv.z; p3 += x*wv.w;
  }
  #pragma unroll
  for (int off=32; off>0; off>>=1){
    p0 += __shfl_down(p0, off);
    p1 += __shfl_down(p1, off);
    p2 += __shfl_down(p2, off);
    p3 += __shfl_down(p3, off);
  }
  if (lane==0){
    int n = n0 + w;
    float r0=p0+c4[0], r1=p1+c4[1], r2=p2+c4[2], r3=p3+c4[3];
    hg3[n*2]=r0; hg3[n*2+1]=r1;
    lin3[n*2]=r2; lin3[n*2+1]=r3;
    ssrc[n]=r0*attn[0]+r1*attn[1];
    sdst[n]=r0*attn[2]+r1*attn[3];
  }
}

__global__ void k_logits3(const int* __restrict__ ei, const float* __restrict__ ea,
                          const float* __restrict__ We, const float* __restrict__ attn,
                          const float* __restrict__ at, const float* __restrict__ ssrc,
                          const float* __restrict__ sdst, float* __restrict__ L){
  int e = blockIdx.x*256 + threadIdx.x;
  if (e >= EE) return;
  int s = ei[e], d = ei[EE+e];
  float e0=0.f, e1=0.f;
  #pragma unroll
  for (int k=0;k<10;k++){
    float c = ea[e*12+1+k];
    e0 += c*We[k*2]; e1 += c*We[k*2+1];
  }
  float se = e0*attn[4] + e1*attn[5];
  float v = ssrc[s] + sdst[d] + se + ea[e*12]*at[0];
  L[e] = (v>0.f)? v : 0.2f*v;
}

// layer-3 softmax finalize: w in place + cw3[n][k]
__global__ void k_mden3(const int* __restrict__ iptr, const int* __restrict__ eid,
                        const float* __restrict__ ea, float* __restrict__ L,
                        float* __restrict__ cw){
  int n = blockIdx.x*256 + threadIdx.x;
  if (n >= NN) return;
  int b = iptr[n], e1 = iptr[n+1];
  float mx = -INFINITY;
  for (int i=b;i<e1;i++) mx = fmaxf(mx, L[eid[i]]);
  if (b == e1) mx = 0.f;
  float s = 0.f;
  for (int i=b;i<e1;i++) s += expf(L[eid[i]] - mx);
  float dv = 1.f/(s+1e-16f);
  float c[10] = {0.f,0.f,0.f,0.f,0.f,0.f,0.f,0.f,0.f,0.f};
  for (int i=b;i<e1;i++){
    int e = eid[i];
    float w = expf(L[e]-mx)*dv;
    L[e] = w;
    #pragma unroll
    for (int k=0;k<10;k++) c[k] += w*ea[e*12+1+k];
  }
  float* cp = cw + (long)n*10;
  #pragma unroll
  for (int k=0;k<10;k++) cp[k] = c[k];
}

__global__ void k_gather3(const int* __restrict__ ei,
                          const int* __restrict__ iptr, const int* __restrict__ eid,
                          const float* __restrict__ L,      // holds w[e]
                          const float* __restrict__ cw,     // [NN][10]
                          const float* __restrict__ hg3,
                          const float* __restrict__ We, const float* __restrict__ lin3,
                          const float* __restrict__ cb, float* __restrict__ out){
  int n = blockIdx.x*256 + threadIdx.x;
  if (n >= NN) return;
  int b = iptr[n], en = iptr[n+1];
  const float* cp = cw + (long)n*10;
  float e0f=0.f, e1f=0.f;
  #pragma unroll
  for (int k=0;k<10;k++){ e0f += cp[k]*We[k*2]; e1f += cp[k]*We[k*2+1]; }
  float a0=0.f, a1=0.f;
  for (int i=b;i<en;i++){
    int e = eid[i], s_ = ei[e];
    float w = L[e];
    a0 += w*hg3[s_*2];
    a1 += w*hg3[s_*2+1];
  }
  out[n*2]   = fmaxf(lin3[n*2]  +a0+e0f+cb[0], 0.f);
  out[n*2+1] = fmaxf(lin3[n*2+1]+a1+e1f+cb[1], 0.f);
}

extern "C" void kernel_launch(void* const* d_in, const int* in_sizes, int n_in,
                              void* d_out, int out_size, void* d_ws, size_t ws_size,
                              hipStream_t stream){
  const int* ei = (const int*)d_in[1];

  long long sz[64];
  {
    const long long* s64 = (const long long*)(const void*)in_sizes;
    bool is64 = (n_in >= 2) && (in_sizes[0] == 3340000) && (in_sizes[1] == 0)
                && (s64[1] == 200000);
    for (int i=0;i<n_in && i<64;i++) sz[i] = is64 ? s64[i] : (long long)in_sizes[i];
  }

  int IWg[3], IWe[3], IAttn[3], IAt[3], ICb[3], ILw[3], ILb[3], IG[3], IB[3];
  if (n_in > 8 && sz[8] == (long long)HID*HID){ // setup_inputs() dict order
    for (int l=0;l<3;l++){
      IWg[l]=3+l*5; IWe[l]=4+l*5; IAttn[l]=5+l*5; IAt[l]=6+l*5; ICb[l]=7+l*5;
      ILw[l]=18+l*4; ILb[l]=19+l*4; IG[l]=20+l*4; IB[l]=21+l*4;
    }
  } else {
    int idx=3;
    for (int l=0;l<3;l++){
      IWg[l]=idx++; IWe[l]=idx++; IAttn[l]=idx++; IAt[l]=idx++; ICb[l]=idx++;
      ILw[l]=idx++; ILb[l]=idx++; IG[l]=idx++; IB[l]=idx++;
    }
  }
  #define FP(i) ((const float*)d_in[(i)])

  char* ws = (char*)d_ws;
  size_t off = 0;
  auto alloc = [&](size_t bytes)->void*{ void* p = ws + off; off += (bytes + 255) & ~(size_t)255; return p; };
  auto G = [](long n){ return (int)((n+255)/256); };

  u16*   buf0 = (u16*)  alloc((size_t)NN*HID*2);   // hg (bf16)
  u16*   bufA = (u16*)  alloc((size_t)NN*HID*2);   // layer-1 lin/result
  u16*   bufB = (u16*)  alloc((size_t)NN*HID*2);   // layer-2 lin/result
  u16*   xbf  = (u16*)  alloc((size_t)NN*KP1*2);   // layer-1 A (bf16, padded)
  u16*   Wt   = (u16*)  alloc((size_t)2*HID*HID*2);// fused folded weights [2048][K] K-major
  u16*   We16 = (u16*)  alloc((size_t)10*HID*2);
  float* cst  = (float*)alloc(2*HID*4);
  float* L    = (float*)alloc((size_t)EE*4*4);
  float* ssrc = (float*)alloc((size_t)NN*4*4);
  float* sdst = (float*)alloc((size_t)NN*4*4);
  int*   iptr = (int*)  alloc((size_t)(NN+4)*4);
  int*   cnts = (int*)  alloc((size_t)NN*4);
  int*   eid  = (int*)  alloc((size_t)EE*4);
  float* stats= (float*)alloc(2*HID*4);
  float* scale= (float*)alloc(HID*4);
  float* shift= (float*)alloc(HID*4);
  float* qbuf = (float*)alloc(64*4);
  float* hg3  = (float*)alloc((size_t)NN*2*4);
  float* lin3 = (float*)alloc((size_t)NN*2*4);
  float* cw   = (float*)alloc((size_t)NN*40*4);    // factored edge-feature weights
  float* W4   = (float*)alloc((size_t)HID*4*4);    // layer-3 folded interleaved weights
  float* c4   = (float*)alloc(4*4);

  // ---- CSR by dst ----
  hipMemsetAsync(cnts, 0, NN*sizeof(int), stream);
  k_count<<<G(EE),256,0,stream>>>(ei, cnts);
  k_scan<<<1,256,0,stream>>>(cnts, iptr);
  hipMemsetAsync(cnts, 0, NN*sizeof(int), stream);
  k_fill<<<G(EE),256,0,stream>>>(ei, iptr, cnts, eid);

  int gg = 1264;   // 79 row-tiles (256 rows) x 16 col-tiles (128 cols), XCD-swizzled in-kernel
  int gsd = (NN*4+3)/4;   // k_sdot: one wave per (n,h)

  // ---- layer 1 (A = bf16(x), Kp=256) ----
  {
    hipMemsetAsync(stats, 0, 2*FIN*sizeof(float), stream);
    dim3 bg(200, 1);
    k_bnstats<float><<<bg,256,0,stream>>>(FP(0), stats, FIN);
    k_bnfin<<<1,256,0,stream>>>(stats, FP(IG[0]), FP(IB[0]), scale, shift, FIN);
    k_cast<<<G((long)NN*KP1),256,0,stream>>>(FP(0), xbf);
    dim3 ft(KP1/32, 64);
    k_foldT<<<ft,256,0,stream>>>(FP(IWg[0]), FP(ILw[0]), scale, Wt, FIN, KP1);
    k_cinit<<<8,256,0,stream>>>(FP(ILb[0]), cst);
    dim3 cg(32, (FIN+127)/128);
    k_const<<<cg,256,0,stream>>>(FP(IWg[0]), FP(ILw[0]), shift, cst, FIN);
    k_we16<<<40,256,0,stream>>>(FP(IWe[0]), We16);
    k_gemm<<<gg,512,0,stream>>>(xbf, KP1, Wt, cst, buf0, bufA);
    k_sdot<<<gsd,256,0,stream>>>(buf0, FP(IAttn[0]), ssrc, sdst);
    k_q<<<1,64,0,stream>>>(FP(IWe[0]), FP(IAttn[0]), qbuf);
    k_logits<<<G(EE),256,0,stream>>>(ei, FP(2), qbuf, FP(IAt[0]), ssrc, sdst, L);
    k_mden<<<G(NN),256,0,stream>>>(iptr, eid, FP(2), L, cw);
    k_gath<<<(NN+NB-1)/NB,256,0,stream>>>(buf0, ei, iptr, eid, L, cw,
                                          We16, FP(ICb[0]), bufA);
  }
  // ---- layer 2 (A = bufA, K=1024) ----
  {
    hipMemsetAsync(stats, 0, 2*HID*sizeof(float), stream);
    k_bnstats8<<<800,256,0,stream>>>(bufA, stats);
    k_bnfin<<<4,256,0,stream>>>(stats, FP(IG[1]), FP(IB[1]), scale, shift, HID);
    dim3 ft(HID/32, 64);
    k_foldT<<<ft,256,0,stream>>>(FP(IWg[1]), FP(ILw[1]), scale, Wt, HID, HID);
    k_cinit<<<8,256,0,stream>>>(FP(ILb[1]), cst);
    dim3 cg(32, HID/128);
    k_const<<<cg,256,0,stream>>>(FP(IWg[1]), FP(ILw[1]), shift, cst, HID);
    k_we16<<<40,256,0,stream>>>(FP(IWe[1]), We16);
    k_gemm<<<gg,512,0,stream>>>(bufA, HID, Wt, cst, buf0, bufB);
    k_sdot<<<gsd,256,0,stream>>>(buf0, FP(IAttn[1]), ssrc, sdst);
    k_q<<<1,64,0,stream>>>(FP(IWe[1]), FP(IAttn[1]), qbuf);
    k_logits<<<G(EE),256,0,stream>>>(ei, FP(2), qbuf, FP(IAt[1]), ssrc, sdst, L);
    k_mden<<<G(NN),256,0,stream>>>(iptr, eid, FP(2), L, cw);
    k_gath<<<(NN+NB-1)/NB,256,0,stream>>>(buf0, ei, iptr, eid, L, cw,
                                          We16, FP(ICb[1]), bufB);
  }

  // ---- layer 3 (input = bufB) ----
  hipMemsetAsync(stats, 0, 2*HID*sizeof(float), stream);
  k_bnstats8<<<800,256,0,stream>>>(bufB, stats);
  k_bnfin<<<4,256,0,stream>>>(stats, FP(IG[2]), FP(IB[2]), scale, shift, HID);
  k_c4init<<<1,64,0,stream>>>(FP(ILb[2]), c4);
  k_fold3<<<HID/256,256,0,stream>>>(FP(IWg[2]), FP(ILw[2]), scale, shift, W4, c4);
  k_n3<<<NN/4,256,0,stream>>>(bufB, W4, c4, FP(IAttn[2]), hg3, lin3, ssrc, sdst);
  k_logits3<<<G(EE),256,0,stream>>>(ei, FP(2), FP(IWe[2]), FP(IAttn[2]), FP(IAt[2]), ssrc, sdst, L);
  k_mden3<<<G(NN),256,0,stream>>>(iptr, eid, FP(2), L, cw);
  k_gather3<<<G(NN),256,0,stream>>>(ei, iptr, eid, L, cw, hg3,
                                    FP(IWe[2]), lin3, FP(ICb[2]), (float*)d_out);
}

// Round 8
// 891.044 us; speedup vs baseline: 1.4035x; 1.4035x over previous
//
#include <hip/hip_runtime.h>
#include <math.h>

#define NN 20000
#define EE 100000
#define FIN 167
#define KP1 256    // layer-1 K padded to mult of 64
#define HID 1024   // H*O = 4*256
#define OO 256
#define NB 16      // nodes per k_gath block

typedef unsigned short u16;
typedef short bf16x8 __attribute__((ext_vector_type(8)));
typedef short s16x4  __attribute__((ext_vector_type(4)));
typedef float f32x4  __attribute__((ext_vector_type(4)));

__device__ __forceinline__ float bf(u16 u){ return __uint_as_float(((unsigned)u)<<16); }
__device__ __forceinline__ u16 fb(float v){            // f32 -> bf16 RNE
  unsigned u = __float_as_uint(v);
  return (u16)((u + 0x7FFFu + ((u>>16)&1u)) >> 16);
}
__device__ __forceinline__ float ldv(const float* p, long i){ return p[i]; }
__device__ __forceinline__ float ldv(const u16*   p, long i){ return bf(p[i]); }

// ---------------- CSR build ----------------
__global__ void k_count(const int* __restrict__ ei, int* __restrict__ counts){
  int e = blockIdx.x*256 + threadIdx.x;
  if (e < EE) atomicAdd(&counts[ei[EE+e]], 1);
}

__global__ __launch_bounds__(256) void k_scan(const int* __restrict__ counts, int* __restrict__ iptr){
  __shared__ int sd[256];
  int tid = threadIdx.x;
  int carry = 0;
  for (int base=0; base<NN; base+=256){
    int i = base+tid;
    int v = (i<NN)? counts[i] : 0;
    sd[tid]=v;
    __syncthreads();
    for (int off=1; off<256; off<<=1){
      int t = (tid>=off)? sd[tid-off] : 0;
      __syncthreads();
      sd[tid] += t;
      __syncthreads();
    }
    if (i<NN) iptr[i] = carry + sd[tid] - v;
    carry += sd[255];
    __syncthreads();
  }
  if (tid==0) iptr[NN]=carry;
}

__global__ void k_fill(const int* __restrict__ ei, const int* __restrict__ iptr,
                       int* __restrict__ cursor, int* __restrict__ eid){
  int e = blockIdx.x*256 + threadIdx.x;
  if (e < EE){
    int d = ei[EE+e];
    int pos = atomicAdd(&cursor[d],1);
    eid[iptr[d]+pos] = e;
  }
}

// ---------------- BatchNorm stats ----------------
// layer-1 (float input, F=167): original coalesced version (never hot; 67K atomics OK)
template<typename T>
__global__ void k_bnstats(const T* __restrict__ X, float* __restrict__ sums, int F){
  int f = blockIdx.y*256 + threadIdx.x;
  if (f >= F) return;
  int r0 = blockIdx.x*100, r1 = r0+100;
  float s=0.f, s2=0.f;
  for (int r=r0;r<r1;r++){ float v = ldv(X,(long)r*F+f); s += v; s2 += v*v; }
  atomicAdd(&sums[f], s);
  atomicAdd(&sums[F+f], s2);
}

// layers 2/3 (bf16, F=HID) stage A: ZERO-ATOMIC. bf16x8 reads, LDS pair-reduce,
// non-atomic partial write part[block][2048]. (round-7's 1.6M atomicAdds onto 2048
// addrs = 800/addr dense bursts -> 210us atomic storm, WRITE_SIZE 51MB; this is ~2MB.)
__global__ __launch_bounds__(256) void k_bnstats8(const u16* __restrict__ X, float* __restrict__ part){
  int tid = threadIdx.x;
  int f8 = (tid & 127)*8;
  int r0 = blockIdx.x*79, r1 = min(NN, r0+79);     // grid 256
  float s[8]={0,0,0,0,0,0,0,0}, s2[8]={0,0,0,0,0,0,0,0};
  for (int r=r0 + (tid>>7); r<r1; r+=2){
    bf16x8 v = *(const bf16x8*)(X + (long)r*HID + f8);
    #pragma unroll
    for (int j=0;j<8;j++){ float x=bf((u16)v[j]); s[j]+=x; s2[j]+=x*x; }
  }
  __shared__ float red[256][8];
  float* pb = part + (long)blockIdx.x*2048;
  #pragma unroll
  for (int j=0;j<8;j++) red[tid][j]=s[j];
  __syncthreads();
  if (tid<128){
    #pragma unroll
    for (int j=0;j<8;j++) pb[f8+j] = red[tid][j]+red[tid+128][j];
  }
  __syncthreads();
  #pragma unroll
  for (int j=0;j<8;j++) red[tid][j]=s2[j];
  __syncthreads();
  if (tid<128){
    #pragma unroll
    for (int j=0;j<8;j++) pb[1024+f8+j] = red[tid][j]+red[tid+128][j];
  }
}

// stage B: reduce 256 partials -> sums[2048]; consecutive threads = consecutive addrs
__global__ __launch_bounds__(256) void k_pred(const float* __restrict__ part, float* __restrict__ sums){
  int idx = blockIdx.x*256 + threadIdx.x;   // grid 8 -> 2048 threads
  float s = 0.f;
  #pragma unroll 8
  for (int b=0;b<256;b++) s += part[(long)b*2048 + idx];
  sums[idx] = s;
}

__global__ void k_bnfin(const float* __restrict__ sums, const float* __restrict__ g,
                        const float* __restrict__ b, float* __restrict__ scale,
                        float* __restrict__ shift, int F){
  int f = blockIdx.x*256 + threadIdx.x;
  if (f >= F) return;
  float mu  = sums[f]   * (1.f/NN);
  float var = sums[F+f] * (1.f/NN) - mu*mu;
  float sc  = rsqrtf(var + 1e-5f) * g[f];
  scale[f] = sc;
  shift[f] = b[f] - mu*sc;
}

// ---------------- BN-folded fused weight prep ----------------
__global__ __launch_bounds__(256) void k_foldT(const float* __restrict__ Wg, const float* __restrict__ Wl,
                        const float* __restrict__ scale,
                        u16* __restrict__ Wt, int K, int Kp){
  __shared__ float t[32][33];
  int k0 = blockIdx.x*32, c0 = blockIdx.y*32;
  int tx = threadIdx.x & 31, ty = threadIdx.x >> 5;
  bool second = (c0 >= HID);
  const float* W = second ? Wl : Wg;
  int cc0 = second ? c0 - HID : c0;
  #pragma unroll
  for (int i=0;i<4;i++){
    int k = k0 + ty + i*8;
    t[ty+i*8][tx] = (k < K) ? W[(long)k*HID + cc0 + tx] * scale[k] : 0.f;
  }
  __syncthreads();
  #pragma unroll
  for (int i=0;i<4;i++){
    int c = c0 + ty + i*8;
    Wt[(long)c*Kp + k0 + tx] = fb(t[tx][ty+i*8]);
  }
}

// cst init: lb for lin half, 0 for hg half
__global__ void k_cinit(const float* __restrict__ lb, float* __restrict__ cst){
  int c = blockIdx.x*256 + threadIdx.x;
  if (c < 2*HID) cst[c] = (c >= HID) ? lb[c-HID] : 0.f;
}

// cst[c] += sum_k shift[k]*W[k][c]  — parallel reduction, coalesced
__global__ __launch_bounds__(256) void k_const(const float* __restrict__ Wg, const float* __restrict__ Wl,
                        const float* __restrict__ shift, float* __restrict__ cst, int K){
  int tx = threadIdx.x & 63, ty = threadIdx.x >> 6;
  int c = blockIdx.x*64 + tx;
  bool second = c >= HID;
  const float* W = second ? Wl : Wg;
  int cc = second ? c-HID : c;
  int k0 = blockIdx.y*128;
  int k1 = min(K, k0+128);
  float s = 0.f;
  for (int k=k0+ty; k<k1; k+=4) s += shift[k]*W[(long)k*HID+cc];
  __shared__ float red[256];
  red[threadIdx.x] = s;
  __syncthreads();
  if (ty == 0){
    float tot = red[tx] + red[tx+64] + red[tx+128] + red[tx+192];
    atomicAdd(&cst[c], tot);
  }
}

__global__ void k_cast(const float* __restrict__ x, u16* __restrict__ xb){
  long idx = (long)blockIdx.x*256 + threadIdx.x;
  if (idx >= (long)NN*KP1) return;
  int n = (int)(idx / KP1), k = (int)(idx % KP1);
  xb[idx] = (k<FIN)? fb(x[(long)n*FIN+k]) : (u16)0;
}

__global__ void k_we16(const float* __restrict__ We, u16* __restrict__ We16){
  int i = blockIdx.x*256 + threadIdx.x;
  if (i < 10*HID) We16[i] = fb(We[i]);
}

// ---------------- MFMA GEMM (round-4 verified, FROZEN) ----------------
#define MF(a_,b_,c_) __builtin_amdgcn_mfma_f32_16x16x32_bf16(a_,b_,c_,0,0,0)
#define FENCE asm volatile("" ::: "memory")
#define BAR do { FENCE; __builtin_amdgcn_s_barrier(); FENCE; } while(0)

__global__ __launch_bounds__(512,2) void k_gemm(const u16* __restrict__ A, int K,
                     const u16* __restrict__ Wt, const float* __restrict__ cst,
                     u16* __restrict__ Chg, u16* __restrict__ Clin){
  __shared__ u16 lds[2][24576];   // [buf][Ak0|Ak1|Bk0|Bk1] = 16K+16K+8K+8K bytes, total 96 KB
  int b = blockIdx.x;
  int wg = (b & 7)*158 + (b >> 3);          // 1264 % 8 == 0 -> bijective XCD swizzle
  int row0 = (wg >> 4)*256, col0 = (wg & 15)*128;
  int tid = threadIdx.x;
  int wave = tid >> 6, lane = tid & 63, quad = lane >> 4, lo = lane & 15;
  int wm = wave >> 1, wn = wave & 1;        // 4 M-waves x 2 N-waves, 64x64 out each
  const u16* Apt[2];
  #pragma unroll
  for (int i=0;i<2;i++){
    int s = i*512 + tid, srow = s>>2;
    int gr = row0 + srow; if (gr >= NN) gr = NN-1;      // clamp: garbage rows never stored
    Apt[i] = A + (long)gr*K + (((s&3)^(srow&3))*8);
  }
  int brow = tid>>2;
  const u16* Bpt = Wt + (long)(col0 + brow)*K + ((((tid&3)^(brow&3)))*8);
  const char* ldsc = (const char*)&lds[0][0];
  int axor = lo & 3;
  int aoff = (wm*64 + lo)*64 + ((quad^axor)*16);
  int boff = 32768 + (wn*64 + lo)*64 + ((quad^axor)*16);
  int NT = K >> 6;
  f32x4 acc[4][4] = {};
  {
    u16* d = (u16*)&lds[0][0];
    __builtin_amdgcn_global_load_lds(Apt[0],      d +          tid*8, 16, 0, 0);
    __builtin_amdgcn_global_load_lds(Apt[1],      d +  4096 +  tid*8, 16, 0, 0);
    __builtin_amdgcn_global_load_lds(Bpt,         d + 16384 +  tid*8, 16, 0, 0);
    __builtin_amdgcn_global_load_lds(Apt[0] + 32, d +  8192 +  tid*8, 16, 0, 0);
    __builtin_amdgcn_global_load_lds(Apt[1] + 32, d + 12288 +  tid*8, 16, 0, 0);
    __builtin_amdgcn_global_load_lds(Bpt    + 32, d + 20480 +  tid*8, 16, 0, 0);
    asm volatile("s_waitcnt vmcnt(3)" ::: "memory");
    BAR;
  }
  for (int t=0; t<NT; t++){
    const char* Lb = ldsc + (t&1)*49152;
    u16* Sb = (u16*)&lds[0][0] + ((t&1)^1)*24576;
    int k0n = (t+1) << 6;
    int nx = (t+1 < NT);
    bf16x8 af[4], bfr[4];
    #pragma unroll
    for (int i=0;i<4;i++) af[i]  = *(const bf16x8*)(Lb + aoff + i*1024);
    #pragma unroll
    for (int n=0;n<4;n++) bfr[n] = *(const bf16x8*)(Lb + boff + n*1024);
    if (nx){
      __builtin_amdgcn_global_load_lds(Apt[0] + k0n, Sb +          tid*8, 16, 0, 0);
      __builtin_amdgcn_global_load_lds(Apt[1] + k0n, Sb +  4096 +  tid*8, 16, 0, 0);
      __builtin_amdgcn_global_load_lds(Bpt    + k0n, Sb + 16384 +  tid*8, 16, 0, 0);
    }
    #pragma unroll
    for (int i=0;i<4;i++)
      #pragma unroll
      for (int n=0;n<4;n++)
        acc[i][n] = MF(af[i], bfr[n], acc[i][n]);
    if (nx) asm volatile("s_waitcnt vmcnt(3)" ::: "memory");
    else    asm volatile("s_waitcnt vmcnt(0)" ::: "memory");
    BAR;
    #pragma unroll
    for (int i=0;i<4;i++) af[i]  = *(const bf16x8*)(Lb + 16384 + aoff + i*1024);
    #pragma unroll
    for (int n=0;n<4;n++) bfr[n] = *(const bf16x8*)(Lb +  8192 + boff + n*1024);
    if (nx){
      __builtin_amdgcn_global_load_lds(Apt[0] + k0n + 32, Sb +  8192 +  tid*8, 16, 0, 0);
      __builtin_amdgcn_global_load_lds(Apt[1] + k0n + 32, Sb + 12288 +  tid*8, 16, 0, 0);
      __builtin_amdgcn_global_load_lds(Bpt    + k0n + 32, Sb + 20480 +  tid*8, 16, 0, 0);
    }
    #pragma unroll
    for (int i=0;i<4;i++)
      #pragma unroll
      for (int n=0;n<4;n++)
        acc[i][n] = MF(af[i], bfr[n], acc[i][n]);
    if (nx) asm volatile("s_waitcnt vmcnt(3)" ::: "memory");
    BAR;
  }
  #pragma unroll
  for (int i=0;i<4;i++){
    #pragma unroll
    for (int n=0;n<4;n++){
      int col = col0 + wn*64 + n*16 + lo;
      float cs = cst[col];
      #pragma unroll
      for (int r=0;r<4;r++){
        int row = row0 + wm*64 + i*16 + quad*4 + r;   // C/D: col=lane&15, row=quad*4+reg
        if (row < NN){
          u16 o = fb(acc[i][n][r] + cs);
          if (col < HID) Chg[(long)row*HID + col] = o;
          else           Clin[(long)row*HID + col - HID] = o;
        }
      }
    }
  }
}
#undef MF
#undef BAR
#undef FENCE

// ---------------- per-(node,head) attention dots: wave-parallel, coalesced ----------------
__global__ __launch_bounds__(256) void k_sdot(const u16* __restrict__ hg, const float* __restrict__ attn,
                       float* __restrict__ ssrc, float* __restrict__ sdst){
  int unit = blockIdx.x*4 + (threadIdx.x >> 6);   // one wave per (n,h)
  if (unit >= NN*4) return;
  int lane = threadIdx.x & 63;
  int n = unit >> 2, h = unit & 3;
  const u16* hp = hg + (long)n*HID + h*OO + lane*4;
  s16x4 v = *(const s16x4*)hp;
  float4 x0 = *(const float4*)(attn + h*OO + lane*4);
  float4 x1 = *(const float4*)(attn + HID + h*OO + lane*4);
  float f0 = bf((u16)v.x), f1 = bf((u16)v.y), f2 = bf((u16)v.z), f3 = bf((u16)v.w);
  float ss = f0*x0.x + f1*x0.y + f2*x0.z + f3*x0.w;
  float sd = f0*x1.x + f1*x1.y + f2*x1.z + f3*x1.w;
  #pragma unroll
  for (int off=32; off>0; off>>=1){
    ss += __shfl_down(ss, off);
    sd += __shfl_down(sd, off);
  }
  if (lane==0){ ssrc[unit]=ss; sdst[unit]=sd; }
}

__global__ void k_q(const float* __restrict__ We, const float* __restrict__ attn,
                    float* __restrict__ q){
  int t = threadIdx.x;
  if (t >= 40) return;
  int k = t >> 2, h = t & 3;
  float s = 0.f;
  for (int d=0; d<OO; d++) s += We[(long)k*HID + h*OO + d] * attn[2*HID + h*OO + d];
  q[k*4+h] = s;
}

// per-EDGE logits: ea read once, all 4 heads computed, float4 write
__global__ void k_logits(const int* __restrict__ ei, const float* __restrict__ ea,
                         const float* __restrict__ q, const float* __restrict__ at,
                         const float* __restrict__ ssrc, const float* __restrict__ sdst,
                         float* __restrict__ L){
  int e = blockIdx.x*256 + threadIdx.x;
  if (e >= EE) return;
  int s = ei[e], dd = ei[EE+e];
  float4 a0 = *(const float4*)(ea + (long)e*12);
  float4 a1 = *(const float4*)(ea + (long)e*12 + 4);
  float4 a2 = *(const float4*)(ea + (long)e*12 + 8);
  float t = a0.x;
  float cc[10] = {a0.y,a0.z,a0.w, a1.x,a1.y,a1.z,a1.w, a2.x,a2.y,a2.z};
  float4 ss = *(const float4*)(ssrc + (long)s*4);
  float4 sd = *(const float4*)(sdst + (long)dd*4);
  float sv[4] = {ss.x+sd.x, ss.y+sd.y, ss.z+sd.z, ss.w+sd.w};
  float4 out;
  #pragma unroll
  for (int h=0;h<4;h++){
    float se = 0.f;
    #pragma unroll
    for (int k=0;k<10;k++) se += cc[k]*q[k*4+h];
    float v = sv[h] + se + t*at[h];
    ((float*)&out)[h] = (v>0.f)? v : 0.2f*v;
  }
  *(float4*)(L + (long)e*4) = out;
}

// per-NODE softmax finalize: writes w = exp(L-m)*dinv IN PLACE into L (float4),
// accumulates cw[n][4][10] with ea read ONCE per edge
__global__ void k_mden(const int* __restrict__ iptr, const int* __restrict__ eid,
                       const float* __restrict__ ea, float* __restrict__ L,
                       float* __restrict__ cw){
  int n = blockIdx.x*256 + threadIdx.x;
  if (n >= NN) return;
  int b = iptr[n], e1 = iptr[n+1];
  float m0=-INFINITY, m1=-INFINITY, m2=-INFINITY, m3=-INFINITY;
  for (int i=b;i<e1;i++){
    float4 l = *(const float4*)(L + (long)eid[i]*4);
    m0=fmaxf(m0,l.x); m1=fmaxf(m1,l.y); m2=fmaxf(m2,l.z); m3=fmaxf(m3,l.w);
  }
  if (b==e1){ m0=m1=m2=m3=0.f; }
  float s0=0.f,s1=0.f,s2=0.f,s3=0.f;
  for (int i=b;i<e1;i++){
    float4 l = *(const float4*)(L + (long)eid[i]*4);
    s0+=expf(l.x-m0); s1+=expf(l.y-m1); s2+=expf(l.z-m2); s3+=expf(l.w-m3);
  }
  float d0=1.f/(s0+1e-16f), d1=1.f/(s1+1e-16f), d2=1.f/(s2+1e-16f), d3=1.f/(s3+1e-16f);
  float c[4][10] = {};
  for (int i=b;i<e1;i++){
    int e = eid[i];
    float4 l = *(const float4*)(L + (long)e*4);
    float4 w = { expf(l.x-m0)*d0, expf(l.y-m1)*d1, expf(l.z-m2)*d2, expf(l.w-m3)*d3 };
    *(float4*)(L + (long)e*4) = w;
    float4 a0 = *(const float4*)(ea + (long)e*12);
    float4 a1 = *(const float4*)(ea + (long)e*12 + 4);
    float4 a2 = *(const float4*)(ea + (long)e*12 + 8);
    float cc[10] = {a0.y,a0.z,a0.w, a1.x,a1.y,a1.z,a1.w, a2.x,a2.y,a2.z};
    #pragma unroll
    for (int k=0;k<10;k++){
      c[0][k] += w.x*cc[k]; c[1][k] += w.y*cc[k];
      c[2][k] += w.z*cc[k]; c[3][k] += w.w*cc[k];
    }
  }
  float* cp = cw + (long)n*40;
  #pragma unroll
  for (int h=0;h<4;h++)
    #pragma unroll
    for (int k=0;k<10;k++) cp[h*10+k] = c[h][k];
}

// ---------------- edge gather v3: 8B/lane vectorized h[src] gather ----------------
// thread t owns features [4t, 4t+4) — all in head h = t>>6, so ONE broadcast weight
// per edge per thread and one s16x4 (8B) load: 512B contiguous per wave per edge.
__global__ __launch_bounds__(256) void k_gath(
    const u16* __restrict__ hg, const int* __restrict__ ei,
    const int* __restrict__ iptr, const int* __restrict__ eid,
    const float* __restrict__ L,      // holds w[e][h] (from k_mden)
    const float* __restrict__ cw,     // [NN][4][10]
    const u16* __restrict__ We16, const float* __restrict__ cb,
    u16* __restrict__ lio)
{
  __shared__ u16  sWe[10*HID];   // 20 KB
  __shared__ float scb[HID];     // 4 KB
  int tid = threadIdx.x;
  for (int i=tid;i<10*HID;i+=256) sWe[i] = We16[i];
  for (int i=tid;i<HID;i+=256) scb[i] = cb[i];
  __syncthreads();
  int h = tid >> 6;
  int f0 = tid*4;
  int d0 = blockIdx.x*NB, dend = min(NN, d0+NB);
  for (int d=d0; d<dend; d++){
    s16x4 a0 = *(const s16x4*)(lio + (long)d*HID + f0);
    float acc0=bf((u16)a0.x), acc1=bf((u16)a0.y), acc2=bf((u16)a0.z), acc3=bf((u16)a0.w);
    int b0 = iptr[d], en = iptr[d+1];
    for (int i=b0;i<en;i++){
      int e = eid[i], s_ = ei[e];
      float w = L[(long)e*4 + h];                       // wave-uniform broadcast
      s16x4 v = *(const s16x4*)(hg + (long)s_*HID + f0);
      acc0 += w*bf((u16)v.x); acc1 += w*bf((u16)v.y);
      acc2 += w*bf((u16)v.z); acc3 += w*bf((u16)v.w);
    }
    const float* cp = cw + (long)d*40 + h*10;
    float ew0=0.f, ew1=0.f, ew2=0.f, ew3=0.f;
    #pragma unroll
    for (int k=0;k<10;k++){
      float c = cp[k];
      s16x4 wv = *(const s16x4*)(sWe + k*HID + f0);
      ew0 += c*bf((u16)wv.x); ew1 += c*bf((u16)wv.y);
      ew2 += c*bf((u16)wv.z); ew3 += c*bf((u16)wv.w);
    }
    acc0 += ew0; acc1 += ew1; acc2 += ew2; acc3 += ew3;
    u16 o[4];
    o[0] = fb(fmaxf(acc0 + scb[f0  ], 0.f));
    o[1] = fb(fmaxf(acc1 + scb[f0+1], 0.f));
    o[2] = fb(fmaxf(acc2 + scb[f0+2], 0.f));
    o[3] = fb(fmaxf(acc3 + scb[f0+3], 0.f));
    *(s16x4*)(lio + (long)d*HID + f0) = *(const s16x4*)o;
  }
}

// ---------------- layer 3 ----------------
__global__ void k_c4init(const float* __restrict__ lb, float* __restrict__ c4){
  if (threadIdx.x==0 && blockIdx.x==0){ c4[0]=0.f; c4[1]=0.f; c4[2]=lb[0]; c4[3]=lb[1]; }
}

// fold BN scale into interleaved weights W4[k][4] = {Wg0,Wg1,lw0,lw1}*sc; shift -> c4
__global__ __launch_bounds__(256) void k_fold3(const float* __restrict__ Wg, const float* __restrict__ lw,
                        const float* __restrict__ scale, const float* __restrict__ shift,
                        float* __restrict__ W4, float* __restrict__ c4){
  int k = blockIdx.x*256 + threadIdx.x;   // grid 4, covers HID exactly
  float sc = scale[k], sh = shift[k];
  float w0=Wg[k*2], w1=Wg[k*2+1], l0=lw[k*2], l1=lw[k*2+1];
  float4 o = {w0*sc, w1*sc, l0*sc, l1*sc};
  *(float4*)(W4 + (long)k*4) = o;
  __shared__ float red[256][4];
  int tid = threadIdx.x;
  red[tid][0]=sh*w0; red[tid][1]=sh*w1; red[tid][2]=sh*l0; red[tid][3]=sh*l1;
  __syncthreads();
  for (int o2=128;o2>0;o2>>=1){
    if (tid<o2){
      #pragma unroll
      for (int j=0;j<4;j++) red[tid][j]+=red[tid+o2][j];
    }
    __syncthreads();
  }
  if (tid==0){
    #pragma unroll
    for (int j=0;j<4;j++) atomicAdd(&c4[j], red[0][j]);
  }
}

// wave-per-node GEMV: x-rows and W4 staged in LDS, shuffle reduce, no post-stage barriers
__global__ __launch_bounds__(256) void k_n3(const u16* __restrict__ in,
    const float* __restrict__ W4, const float* __restrict__ c4,
    const float* __restrict__ attn,
    float* __restrict__ hg3, float* __restrict__ lin3,
    float* __restrict__ ssrc, float* __restrict__ sdst)
{
  __shared__ float sW[HID*4];   // 16 KB
  __shared__ float sx[4][HID];  // 16 KB
  int tid = threadIdx.x;
  int n0 = blockIdx.x*4;        // grid 5000 exact
  for (int i=tid; i<HID; i+=256) *(float4*)&sW[i*4] = *(const float4*)(W4 + (long)i*4);
  for (int idx=tid; idx<512; idx+=256){
    int rr = idx>>7, ch = idx&127;
    bf16x8 v = *(const bf16x8*)(in + (long)(n0+rr)*HID + ch*8);
    #pragma unroll
    for (int j=0;j<8;j++) sx[rr][ch*8+j] = bf((u16)v[j]);
  }
  __syncthreads();
  int w = tid>>6, lane = tid&63;
  float p0=0.f,p1=0.f,p2=0.f,p3=0.f;
  #pragma unroll
  for (int g=0; g<16; g++){
    int k = g*64 + lane;                      // lanes consecutive -> conflict-free
    float x = sx[w][k];
    float4 wv = *(const float4*)&sW[k*4];
    p0 += x*wv.x; p1 += x*wv.y; p2 += x*wv.z; p3 += x*wv.w;
  }
  #pragma unroll
  for (int off=32; off>0; off>>=1){
    p0 += __shfl_down(p0, off);
    p1 += __shfl_down(p1, off);
    p2 += __shfl_down(p2, off);
    p3 += __shfl_down(p3, off);
  }
  if (lane==0){
    int n = n0 + w;
    float r0=p0+c4[0], r1=p1+c4[1], r2=p2+c4[2], r3=p3+c4[3];
    hg3[n*2]=r0; hg3[n*2+1]=r1;
    lin3[n*2]=r2; lin3[n*2+1]=r3;
    ssrc[n]=r0*attn[0]+r1*attn[1];
    sdst[n]=r0*attn[2]+r1*attn[3];
  }
}

__global__ void k_logits3(const int* __restrict__ ei, const float* __restrict__ ea,
                          const float* __restrict__ We, const float* __restrict__ attn,
                          const float* __restrict__ at, const float* __restrict__ ssrc,
                          const float* __restrict__ sdst, float* __restrict__ L){
  int e = blockIdx.x*256 + threadIdx.x;
  if (e >= EE) return;
  int s = ei[e], d = ei[EE+e];
  float e0=0.f, e1=0.f;
  #pragma unroll
  for (int k=0;k<10;k++){
    float c = ea[e*12+1+k];
    e0 += c*We[k*2]; e1 += c*We[k*2+1];
  }
  float se = e0*attn[4] + e1*attn[5];
  float v = ssrc[s] + sdst[d] + se + ea[e*12]*at[0];
  L[e] = (v>0.f)? v : 0.2f*v;
}

// layer-3 softmax finalize: w in place + cw3[n][k]
__global__ void k_mden3(const int* __restrict__ iptr, const int* __restrict__ eid,
                        const float* __restrict__ ea, float* __restrict__ L,
                        float* __restrict__ cw){
  int n = blockIdx.x*256 + threadIdx.x;
  if (n >= NN) return;
  int b = iptr[n], e1 = iptr[n+1];
  float mx = -INFINITY;
  for (int i=b;i<e1;i++) mx = fmaxf(mx, L[eid[i]]);
  if (b == e1) mx = 0.f;
  float s = 0.f;
  for (int i=b;i<e1;i++) s += expf(L[eid[i]] - mx);
  float dv = 1.f/(s+1e-16f);
  float c[10] = {0.f,0.f,0.f,0.f,0.f,0.f,0.f,0.f,0.f,0.f};
  for (int i=b;i<e1;i++){
    int e = eid[i];
    float w = expf(L[e]-mx)*dv;
    L[e] = w;
    #pragma unroll
    for (int k=0;k<10;k++) c[k] += w*ea[e*12+1+k];
  }
  float* cp = cw + (long)n*10;
  #pragma unroll
  for (int k=0;k<10;k++) cp[k] = c[k];
}

__global__ void k_gather3(const int* __restrict__ ei,
                          const int* __restrict__ iptr, const int* __restrict__ eid,
                          const float* __restrict__ L,      // holds w[e]
                          const float* __restrict__ cw,     // [NN][10]
                          const float* __restrict__ hg3,
                          const float* __restrict__ We, const float* __restrict__ lin3,
                          const float* __restrict__ cb, float* __restrict__ out){
  int n = blockIdx.x*256 + threadIdx.x;
  if (n >= NN) return;
  int b = iptr[n], en = iptr[n+1];
  const float* cp = cw + (long)n*10;
  float e0f=0.f, e1f=0.f;
  #pragma unroll
  for (int k=0;k<10;k++){ e0f += cp[k]*We[k*2]; e1f += cp[k]*We[k*2+1]; }
  float a0=0.f, a1=0.f;
  for (int i=b;i<en;i++){
    int e = eid[i], s_ = ei[e];
    float w = L[e];
    a0 += w*hg3[s_*2];
    a1 += w*hg3[s_*2+1];
  }
  out[n*2]   = fmaxf(lin3[n*2]  +a0+e0f+cb[0], 0.f);
  out[n*2+1] = fmaxf(lin3[n*2+1]+a1+e1f+cb[1], 0.f);
}

extern "C" void kernel_launch(void* const* d_in, const int* in_sizes, int n_in,
                              void* d_out, int out_size, void* d_ws, size_t ws_size,
                              hipStream_t stream){
  const int* ei = (const int*)d_in[1];

  long long sz[64];
  {
    const long long* s64 = (const long long*)(const void*)in_sizes;
    bool is64 = (n_in >= 2) && (in_sizes[0] == 3340000) && (in_sizes[1] == 0)
                && (s64[1] == 200000);
    for (int i=0;i<n_in && i<64;i++) sz[i] = is64 ? s64[i] : (long long)in_sizes[i];
  }

  int IWg[3], IWe[3], IAttn[3], IAt[3], ICb[3], ILw[3], ILb[3], IG[3], IB[3];
  if (n_in > 8 && sz[8] == (long long)HID*HID){ // setup_inputs() dict order
    for (int l=0;l<3;l++){
      IWg[l]=3+l*5; IWe[l]=4+l*5; IAttn[l]=5+l*5; IAt[l]=6+l*5; ICb[l]=7+l*5;
      ILw[l]=18+l*4; ILb[l]=19+l*4; IG[l]=20+l*4; IB[l]=21+l*4;
    }
  } else {
    int idx=3;
    for (int l=0;l<3;l++){
      IWg[l]=idx++; IWe[l]=idx++; IAttn[l]=idx++; IAt[l]=idx++; ICb[l]=idx++;
      ILw[l]=idx++; ILb[l]=idx++; IG[l]=idx++; IB[l]=idx++;
    }
  }
  #define FP(i) ((const float*)d_in[(i)])

  char* ws = (char*)d_ws;
  size_t off = 0;
  auto alloc = [&](size_t bytes)->void*{ void* p = ws + off; off += (bytes + 255) & ~(size_t)255; return p; };
  auto G = [](long n){ return (int)((n+255)/256); };

  u16*   buf0 = (u16*)  alloc((size_t)NN*HID*2);   // hg (bf16)
  u16*   bufA = (u16*)  alloc((size_t)NN*HID*2);   // layer-1 lin/result
  u16*   bufB = (u16*)  alloc((size_t)NN*HID*2);   // layer-2 lin/result
  u16*   xbf  = (u16*)  alloc((size_t)NN*KP1*2);   // layer-1 A (bf16, padded)
  u16*   Wt   = (u16*)  alloc((size_t)2*HID*HID*2);// fused folded weights [2048][K] K-major
  u16*   We16 = (u16*)  alloc((size_t)10*HID*2);
  float* cst  = (float*)alloc(2*HID*4);
  float* L    = (float*)alloc((size_t)EE*4*4);
  float* ssrc = (float*)alloc((size_t)NN*4*4);
  float* sdst = (float*)alloc((size_t)NN*4*4);
  int*   iptr = (int*)  alloc((size_t)(NN+4)*4);
  int*   cnts = (int*)  alloc((size_t)NN*4);
  int*   eid  = (int*)  alloc((size_t)EE*4);
  float* stats= (float*)alloc(2*HID*4);
  float* scale= (float*)alloc(HID*4);
  float* shift= (float*)alloc(HID*4);
  float* qbuf = (float*)alloc(64*4);
  float* hg3  = (float*)alloc((size_t)NN*2*4);
  float* lin3 = (float*)alloc((size_t)NN*2*4);
  float* cw   = (float*)alloc((size_t)NN*40*4);    // factored edge-feature weights
  float* W4   = (float*)alloc((size_t)HID*4*4);    // layer-3 folded interleaved weights
  float* c4   = (float*)alloc(4*4);
  float* part = (float*)alloc((size_t)256*2048*4); // bnstats8 partials (2 MB)

  // ---- CSR by dst ----
  hipMemsetAsync(cnts, 0, NN*sizeof(int), stream);
  k_count<<<G(EE),256,0,stream>>>(ei, cnts);
  k_scan<<<1,256,0,stream>>>(cnts, iptr);
  hipMemsetAsync(cnts, 0, NN*sizeof(int), stream);
  k_fill<<<G(EE),256,0,stream>>>(ei, iptr, cnts, eid);

  int gg = 1264;   // 79 row-tiles (256 rows) x 16 col-tiles (128 cols), XCD-swizzled in-kernel
  int gsd = (NN*4+3)/4;   // k_sdot: one wave per (n,h)

  // ---- layer 1 (A = bf16(x), Kp=256) ----
  {
    hipMemsetAsync(stats, 0, 2*FIN*sizeof(float), stream);
    dim3 bg(200, 1);
    k_bnstats<float><<<bg,256,0,stream>>>(FP(0), stats, FIN);
    k_bnfin<<<1,256,0,stream>>>(stats, FP(IG[0]), FP(IB[0]), scale, shift, FIN);
    k_cast<<<G((long)NN*KP1),256,0,stream>>>(FP(0), xbf);
    dim3 ft(KP1/32, 64);
    k_foldT<<<ft,256,0,stream>>>(FP(IWg[0]), FP(ILw[0]), scale, Wt, FIN, KP1);
    k_cinit<<<8,256,0,stream>>>(FP(ILb[0]), cst);
    dim3 cg(32, (FIN+127)/128);
    k_const<<<cg,256,0,stream>>>(FP(IWg[0]), FP(ILw[0]), shift, cst, FIN);
    k_we16<<<40,256,0,stream>>>(FP(IWe[0]), We16);
    k_gemm<<<gg,512,0,stream>>>(xbf, KP1, Wt, cst, buf0, bufA);
    k_sdot<<<gsd,256,0,stream>>>(buf0, FP(IAttn[0]), ssrc, sdst);
    k_q<<<1,64,0,stream>>>(FP(IWe[0]), FP(IAttn[0]), qbuf);
    k_logits<<<G(EE),256,0,stream>>>(ei, FP(2), qbuf, FP(IAt[0]), ssrc, sdst, L);
    k_mden<<<G(NN),256,0,stream>>>(iptr, eid, FP(2), L, cw);
    k_gath<<<(NN+NB-1)/NB,256,0,stream>>>(buf0, ei, iptr, eid, L, cw,
                                          We16, FP(ICb[0]), bufA);
  }
  // ---- layer 2 (A = bufA, K=1024) ----
  {
    k_bnstats8<<<256,256,0,stream>>>(bufA, part);
    k_pred<<<8,256,0,stream>>>(part, stats);
    k_bnfin<<<4,256,0,stream>>>(stats, FP(IG[1]), FP(IB[1]), scale, shift, HID);
    dim3 ft(HID/32, 64);
    k_foldT<<<ft,256,0,stream>>>(FP(IWg[1]), FP(ILw[1]), scale, Wt, HID, HID);
    k_cinit<<<8,256,0,stream>>>(FP(ILb[1]), cst);
    dim3 cg(32, HID/128);
    k_const<<<cg,256,0,stream>>>(FP(IWg[1]), FP(ILw[1]), shift, cst, HID);
    k_we16<<<40,256,0,stream>>>(FP(IWe[1]), We16);
    k_gemm<<<gg,512,0,stream>>>(bufA, HID, Wt, cst, buf0, bufB);
    k_sdot<<<gsd,256,0,stream>>>(buf0, FP(IAttn[1]), ssrc, sdst);
    k_q<<<1,64,0,stream>>>(FP(IWe[1]), FP(IAttn[1]), qbuf);
    k_logits<<<G(EE),256,0,stream>>>(ei, FP(2), qbuf, FP(IAt[1]), ssrc, sdst, L);
    k_mden<<<G(NN),256,0,stream>>>(iptr, eid, FP(2), L, cw);
    k_gath<<<(NN+NB-1)/NB,256,0,stream>>>(buf0, ei, iptr, eid, L, cw,
                                          We16, FP(ICb[1]), bufB);
  }

  // ---- layer 3 (input = bufB) ----
  k_bnstats8<<<256,256,0,stream>>>(bufB, part);
  k_pred<<<8,256,0,stream>>>(part, stats);
  k_bnfin<<<4,256,0,stream>>>(stats, FP(IG[2]), FP(IB[2]), scale, shift, HID);
  k_c4init<<<1,64,0,stream>>>(FP(ILb[2]), c4);
  k_fold3<<<HID/256,256,0,stream>>>(FP(IWg[2]), FP(ILw[2]), scale, shift, W4, c4);
  k_n3<<<NN/4,256,0,stream>>>(bufB, W4, c4, FP(IAttn[2]), hg3, lin3, ssrc, sdst);
  k_logits3<<<G(EE),256,0,stream>>>(ei, FP(2), FP(IWe[2]), FP(IAttn[2]), FP(IAt[2]), ssrc, sdst, L);
  k_mden3<<<G(NN),256,0,stream>>>(iptr, eid, FP(2), L, cw);
  k_gather3<<<G(NN),256,0,stream>>>(ei, iptr, eid, L, cw, hg3,
                                    FP(IWe[2]), lin3, FP(ICb[2]), (float*)d_out);
}

// Round 9
// 815.298 us; speedup vs baseline: 1.5339x; 1.0929x over previous
//
#include <hip/hip_runtime.h>
#include <math.h>

#define NN 20000
#define EE 100000
#define FIN 167
#define KP1 256    // layer-1 K padded to mult of 64
#define HID 1024   // H*O = 4*256
#define OO 256
#define NB 8       // nodes per k_gath block (2500 blocks -> 6 resident/CU, LDS-capped)

typedef unsigned short u16;
typedef short bf16x8 __attribute__((ext_vector_type(8)));
typedef short s16x4  __attribute__((ext_vector_type(4)));
typedef float f32x4  __attribute__((ext_vector_type(4)));

__device__ __forceinline__ float bf(u16 u){ return __uint_as_float(((unsigned)u)<<16); }
__device__ __forceinline__ u16 fb(float v){            // f32 -> bf16 RNE
  unsigned u = __float_as_uint(v);
  return (u16)((u + 0x7FFFu + ((u>>16)&1u)) >> 16);
}
__device__ __forceinline__ float ldv(const float* p, long i){ return p[i]; }
__device__ __forceinline__ float ldv(const u16*   p, long i){ return bf(p[i]); }

// ---------------- CSR build ----------------
__global__ void k_count(const int* __restrict__ ei, int* __restrict__ counts){
  int e = blockIdx.x*256 + threadIdx.x;
  if (e < EE) atomicAdd(&counts[ei[EE+e]], 1);
}

// two-level scan (replaces 79-round single-block serial scan, ~60us -> ~8us)
__global__ __launch_bounds__(256) void k_scanA(const int* __restrict__ counts,
                                               int* __restrict__ iptr, int* __restrict__ bsum){
  __shared__ int sd[256];
  int b = blockIdx.x, tid = threadIdx.x;
  int i = b*256 + tid;
  int v = (i<NN)? counts[i] : 0;
  sd[tid]=v; __syncthreads();
  for (int off=1; off<256; off<<=1){
    int t = (tid>=off)? sd[tid-off] : 0;
    __syncthreads();
    sd[tid] += t;
    __syncthreads();
  }
  if (i<NN) iptr[i] = sd[tid]-v;     // block-local exclusive
  if (tid==255) bsum[b]=sd[255];
}
__global__ __launch_bounds__(128) void k_scanB(const int* __restrict__ bsum,
                                               int* __restrict__ boff, int* __restrict__ iptrN,
                                               int nb){
  __shared__ int sd[128];
  int tid=threadIdx.x;
  int v=(tid<nb)? bsum[tid]:0;
  sd[tid]=v; __syncthreads();
  for (int off=1; off<128; off<<=1){
    int t=(tid>=off)?sd[tid-off]:0;
    __syncthreads();
    sd[tid]+=t;
    __syncthreads();
  }
  if (tid<nb) boff[tid]=sd[tid]-v;
  if (tid==127) *iptrN = sd[127];
}
__global__ void k_scanC(const int* __restrict__ boff, int* __restrict__ iptr){
  int i = blockIdx.x*256+threadIdx.x;
  if (i<NN) iptr[i] += boff[blockIdx.x];
}

__global__ void k_fill(const int* __restrict__ ei, const int* __restrict__ iptr,
                       int* __restrict__ cursor, int* __restrict__ eid){
  int e = blockIdx.x*256 + threadIdx.x;
  if (e < EE){
    int d = ei[EE+e];
    int pos = atomicAdd(&cursor[d],1);
    eid[iptr[d]+pos] = e;
  }
}

// ---------------- BatchNorm stats ----------------
// layer-1 (float input, F=167): original coalesced version (never hot; 67K atomics OK)
template<typename T>
__global__ void k_bnstats(const T* __restrict__ X, float* __restrict__ sums, int F){
  int f = blockIdx.y*256 + threadIdx.x;
  if (f >= F) return;
  int r0 = blockIdx.x*100, r1 = r0+100;
  float s=0.f, s2=0.f;
  for (int r=r0;r<r1;r++){ float v = ldv(X,(long)r*F+f); s += v; s2 += v*v; }
  atomicAdd(&sums[f], s);
  atomicAdd(&sums[F+f], s2);
}

// layers 2/3 (bf16, F=HID) stage A: zero-atomic partials (round-7 lesson: atomics storm)
__global__ __launch_bounds__(256) void k_bnstats8(const u16* __restrict__ X, float* __restrict__ part){
  int tid = threadIdx.x;
  int f8 = (tid & 127)*8;
  int r0 = blockIdx.x*79, r1 = min(NN, r0+79);     // grid 256
  float s[8]={0,0,0,0,0,0,0,0}, s2[8]={0,0,0,0,0,0,0,0};
  for (int r=r0 + (tid>>7); r<r1; r+=2){
    bf16x8 v = *(const bf16x8*)(X + (long)r*HID + f8);
    #pragma unroll
    for (int j=0;j<8;j++){ float x=bf((u16)v[j]); s[j]+=x; s2[j]+=x*x; }
  }
  __shared__ float red[256][8];
  float* pb = part + (long)blockIdx.x*2048;
  #pragma unroll
  for (int j=0;j<8;j++) red[tid][j]=s[j];
  __syncthreads();
  if (tid<128){
    #pragma unroll
    for (int j=0;j<8;j++) pb[f8+j] = red[tid][j]+red[tid+128][j];
  }
  __syncthreads();
  #pragma unroll
  for (int j=0;j<8;j++) red[tid][j]=s2[j];
  __syncthreads();
  if (tid<128){
    #pragma unroll
    for (int j=0;j<8;j++) pb[1024+f8+j] = red[tid][j]+red[tid+128][j];
  }
}

// stage B: reduce 256 partials -> sums[2048]; consecutive threads = consecutive addrs
__global__ __launch_bounds__(256) void k_pred(const float* __restrict__ part, float* __restrict__ sums){
  int idx = blockIdx.x*256 + threadIdx.x;   // grid 8 -> 2048 threads
  float s = 0.f;
  #pragma unroll 8
  for (int b=0;b<256;b++) s += part[(long)b*2048 + idx];
  sums[idx] = s;
}

__global__ void k_bnfin(const float* __restrict__ sums, const float* __restrict__ g,
                        const float* __restrict__ b, float* __restrict__ scale,
                        float* __restrict__ shift, int F){
  int f = blockIdx.x*256 + threadIdx.x;
  if (f >= F) return;
  float mu  = sums[f]   * (1.f/NN);
  float var = sums[F+f] * (1.f/NN) - mu*mu;
  float sc  = rsqrtf(var + 1e-5f) * g[f];
  scale[f] = sc;
  shift[f] = b[f] - mu*sc;
}

// ---------------- BN-folded fused weight prep ----------------
__global__ __launch_bounds__(256) void k_foldT(const float* __restrict__ Wg, const float* __restrict__ Wl,
                        const float* __restrict__ scale,
                        u16* __restrict__ Wt, int K, int Kp){
  __shared__ float t[32][33];
  int k0 = blockIdx.x*32, c0 = blockIdx.y*32;
  int tx = threadIdx.x & 31, ty = threadIdx.x >> 5;
  bool second = (c0 >= HID);
  const float* W = second ? Wl : Wg;
  int cc0 = second ? c0 - HID : c0;
  #pragma unroll
  for (int i=0;i<4;i++){
    int k = k0 + ty + i*8;
    t[ty+i*8][tx] = (k < K) ? W[(long)k*HID + cc0 + tx] * scale[k] : 0.f;
  }
  __syncthreads();
  #pragma unroll
  for (int i=0;i<4;i++){
    int c = c0 + ty + i*8;
    Wt[(long)c*Kp + k0 + tx] = fb(t[tx][ty+i*8]);
  }
}

// cst init: lb for lin half, 0 for hg half
__global__ void k_cinit(const float* __restrict__ lb, float* __restrict__ cst){
  int c = blockIdx.x*256 + threadIdx.x;
  if (c < 2*HID) cst[c] = (c >= HID) ? lb[c-HID] : 0.f;
}

// cst[c] += sum_k shift[k]*W[k][c]  — parallel reduction, coalesced
__global__ __launch_bounds__(256) void k_const(const float* __restrict__ Wg, const float* __restrict__ Wl,
                        const float* __restrict__ shift, float* __restrict__ cst, int K){
  int tx = threadIdx.x & 63, ty = threadIdx.x >> 6;
  int c = blockIdx.x*64 + tx;
  bool second = c >= HID;
  const float* W = second ? Wl : Wg;
  int cc = second ? c-HID : c;
  int k0 = blockIdx.y*128;
  int k1 = min(K, k0+128);
  float s = 0.f;
  for (int k=k0+ty; k<k1; k+=4) s += shift[k]*W[(long)k*HID+cc];
  __shared__ float red[256];
  red[threadIdx.x] = s;
  __syncthreads();
  if (ty == 0){
    float tot = red[tx] + red[tx+64] + red[tx+128] + red[tx+192];
    atomicAdd(&cst[c], tot);
  }
}

__global__ void k_cast(const float* __restrict__ x, u16* __restrict__ xb){
  long idx = (long)blockIdx.x*256 + threadIdx.x;
  if (idx >= (long)NN*KP1) return;
  int n = (int)(idx / KP1), k = (int)(idx % KP1);
  xb[idx] = (k<FIN)? fb(x[(long)n*FIN+k]) : (u16)0;
}

__global__ void k_we16(const float* __restrict__ We, u16* __restrict__ We16){
  int i = blockIdx.x*256 + threadIdx.x;
  if (i < 10*HID) We16[i] = fb(We[i]);
}

// ---------------- MFMA GEMM (round-4 verified, FROZEN) ----------------
#define MF(a_,b_,c_) __builtin_amdgcn_mfma_f32_16x16x32_bf16(a_,b_,c_,0,0,0)
#define FENCE asm volatile("" ::: "memory")
#define BAR do { FENCE; __builtin_amdgcn_s_barrier(); FENCE; } while(0)

__global__ __launch_bounds__(512,2) void k_gemm(const u16* __restrict__ A, int K,
                     const u16* __restrict__ Wt, const float* __restrict__ cst,
                     u16* __restrict__ Chg, u16* __restrict__ Clin){
  __shared__ u16 lds[2][24576];   // [buf][Ak0|Ak1|Bk0|Bk1] = 16K+16K+8K+8K bytes, total 96 KB
  int b = blockIdx.x;
  int wg = (b & 7)*158 + (b >> 3);          // 1264 % 8 == 0 -> bijective XCD swizzle
  int row0 = (wg >> 4)*256, col0 = (wg & 15)*128;
  int tid = threadIdx.x;
  int wave = tid >> 6, lane = tid & 63, quad = lane >> 4, lo = lane & 15;
  int wm = wave >> 1, wn = wave & 1;        // 4 M-waves x 2 N-waves, 64x64 out each
  const u16* Apt[2];
  #pragma unroll
  for (int i=0;i<2;i++){
    int s = i*512 + tid, srow = s>>2;
    int gr = row0 + srow; if (gr >= NN) gr = NN-1;      // clamp: garbage rows never stored
    Apt[i] = A + (long)gr*K + (((s&3)^(srow&3))*8);
  }
  int brow = tid>>2;
  const u16* Bpt = Wt + (long)(col0 + brow)*K + ((((tid&3)^(brow&3)))*8);
  const char* ldsc = (const char*)&lds[0][0];
  int axor = lo & 3;
  int aoff = (wm*64 + lo)*64 + ((quad^axor)*16);
  int boff = 32768 + (wn*64 + lo)*64 + ((quad^axor)*16);
  int NT = K >> 6;
  f32x4 acc[4][4] = {};
  {
    u16* d = (u16*)&lds[0][0];
    __builtin_amdgcn_global_load_lds(Apt[0],      d +          tid*8, 16, 0, 0);
    __builtin_amdgcn_global_load_lds(Apt[1],      d +  4096 +  tid*8, 16, 0, 0);
    __builtin_amdgcn_global_load_lds(Bpt,         d + 16384 +  tid*8, 16, 0, 0);
    __builtin_amdgcn_global_load_lds(Apt[0] + 32, d +  8192 +  tid*8, 16, 0, 0);
    __builtin_amdgcn_global_load_lds(Apt[1] + 32, d + 12288 +  tid*8, 16, 0, 0);
    __builtin_amdgcn_global_load_lds(Bpt    + 32, d + 20480 +  tid*8, 16, 0, 0);
    asm volatile("s_waitcnt vmcnt(3)" ::: "memory");
    BAR;
  }
  for (int t=0; t<NT; t++){
    const char* Lb = ldsc + (t&1)*49152;
    u16* Sb = (u16*)&lds[0][0] + ((t&1)^1)*24576;
    int k0n = (t+1) << 6;
    int nx = (t+1 < NT);
    bf16x8 af[4], bfr[4];
    #pragma unroll
    for (int i=0;i<4;i++) af[i]  = *(const bf16x8*)(Lb + aoff + i*1024);
    #pragma unroll
    for (int n=0;n<4;n++) bfr[n] = *(const bf16x8*)(Lb + boff + n*1024);
    if (nx){
      __builtin_amdgcn_global_load_lds(Apt[0] + k0n, Sb +          tid*8, 16, 0, 0);
      __builtin_amdgcn_global_load_lds(Apt[1] + k0n, Sb +  4096 +  tid*8, 16, 0, 0);
      __builtin_amdgcn_global_load_lds(Bpt    + k0n, Sb + 16384 +  tid*8, 16, 0, 0);
    }
    #pragma unroll
    for (int i=0;i<4;i++)
      #pragma unroll
      for (int n=0;n<4;n++)
        acc[i][n] = MF(af[i], bfr[n], acc[i][n]);
    if (nx) asm volatile("s_waitcnt vmcnt(3)" ::: "memory");
    else    asm volatile("s_waitcnt vmcnt(0)" ::: "memory");
    BAR;
    #pragma unroll
    for (int i=0;i<4;i++) af[i]  = *(const bf16x8*)(Lb + 16384 + aoff + i*1024);
    #pragma unroll
    for (int n=0;n<4;n++) bfr[n] = *(const bf16x8*)(Lb +  8192 + boff + n*1024);
    if (nx){
      __builtin_amdgcn_global_load_lds(Apt[0] + k0n + 32, Sb +  8192 +  tid*8, 16, 0, 0);
      __builtin_amdgcn_global_load_lds(Apt[1] + k0n + 32, Sb + 12288 +  tid*8, 16, 0, 0);
      __builtin_amdgcn_global_load_lds(Bpt    + k0n + 32, Sb + 20480 +  tid*8, 16, 0, 0);
    }
    #pragma unroll
    for (int i=0;i<4;i++)
      #pragma unroll
      for (int n=0;n<4;n++)
        acc[i][n] = MF(af[i], bfr[n], acc[i][n]);
    if (nx) asm volatile("s_waitcnt vmcnt(3)" ::: "memory");
    BAR;
  }
  #pragma unroll
  for (int i=0;i<4;i++){
    #pragma unroll
    for (int n=0;n<4;n++){
      int col = col0 + wn*64 + n*16 + lo;
      float cs = cst[col];
      #pragma unroll
      for (int r=0;r<4;r++){
        int row = row0 + wm*64 + i*16 + quad*4 + r;   // C/D: col=lane&15, row=quad*4+reg
        if (row < NN){
          u16 o = fb(acc[i][n][r] + cs);
          if (col < HID) Chg[(long)row*HID + col] = o;
          else           Clin[(long)row*HID + col - HID] = o;
        }
      }
    }
  }
}
#undef MF
#undef BAR
#undef FENCE

// ---------------- per-(node,head) attention dots: wave-parallel, coalesced ----------------
__global__ __launch_bounds__(256) void k_sdot(const u16* __restrict__ hg, const float* __restrict__ attn,
                       float* __restrict__ ssrc, float* __restrict__ sdst){
  int unit = blockIdx.x*4 + (threadIdx.x >> 6);   // one wave per (n,h)
  if (unit >= NN*4) return;
  int lane = threadIdx.x & 63;
  int n = unit >> 2, h = unit & 3;
  const u16* hp = hg + (long)n*HID + h*OO + lane*4;
  s16x4 v = *(const s16x4*)hp;
  float4 x0 = *(const float4*)(attn + h*OO + lane*4);
  float4 x1 = *(const float4*)(attn + HID + h*OO + lane*4);
  float f0 = bf((u16)v.x), f1 = bf((u16)v.y), f2 = bf((u16)v.z), f3 = bf((u16)v.w);
  float ss = f0*x0.x + f1*x0.y + f2*x0.z + f3*x0.w;
  float sd = f0*x1.x + f1*x1.y + f2*x1.z + f3*x1.w;
  #pragma unroll
  for (int off=32; off>0; off>>=1){
    ss += __shfl_down(ss, off);
    sd += __shfl_down(sd, off);
  }
  if (lane==0){ ssrc[unit]=ss; sdst[unit]=sd; }
}

__global__ void k_q(const float* __restrict__ We, const float* __restrict__ attn,
                    float* __restrict__ q){
  int t = threadIdx.x;
  if (t >= 40) return;
  int k = t >> 2, h = t & 3;
  float s = 0.f;
  for (int d=0; d<OO; d++) s += We[(long)k*HID + h*OO + d] * attn[2*HID + h*OO + d];
  q[k*4+h] = s;
}

// per-EDGE logits: ea read once, all 4 heads computed, float4 write
__global__ void k_logits(const int* __restrict__ ei, const float* __restrict__ ea,
                         const float* __restrict__ q, const float* __restrict__ at,
                         const float* __restrict__ ssrc, const float* __restrict__ sdst,
                         float* __restrict__ L){
  int e = blockIdx.x*256 + threadIdx.x;
  if (e >= EE) return;
  int s = ei[e], dd = ei[EE+e];
  float4 a0 = *(const float4*)(ea + (long)e*12);
  float4 a1 = *(const float4*)(ea + (long)e*12 + 4);
  float4 a2 = *(const float4*)(ea + (long)e*12 + 8);
  float t = a0.x;
  float cc[10] = {a0.y,a0.z,a0.w, a1.x,a1.y,a1.z,a1.w, a2.x,a2.y,a2.z};
  float4 ss = *(const float4*)(ssrc + (long)s*4);
  float4 sd = *(const float4*)(sdst + (long)dd*4);
  float sv[4] = {ss.x+sd.x, ss.y+sd.y, ss.z+sd.z, ss.w+sd.w};
  float4 out;
  #pragma unroll
  for (int h=0;h<4;h++){
    float se = 0.f;
    #pragma unroll
    for (int k=0;k<10;k++) se += cc[k]*q[k*4+h];
    float v = sv[h] + se + t*at[h];
    ((float*)&out)[h] = (v>0.f)? v : 0.2f*v;
  }
  *(float4*)(L + (long)e*4) = out;
}

// per-NODE softmax finalize: writes w = exp(L-m)*dinv IN PLACE into L (float4),
// accumulates cw[n][4][10] with ea read ONCE per edge
__global__ void k_mden(const int* __restrict__ iptr, const int* __restrict__ eid,
                       const float* __restrict__ ea, float* __restrict__ L,
                       float* __restrict__ cw){
  int n = blockIdx.x*256 + threadIdx.x;
  if (n >= NN) return;
  int b = iptr[n], e1 = iptr[n+1];
  float m0=-INFINITY, m1=-INFINITY, m2=-INFINITY, m3=-INFINITY;
  for (int i=b;i<e1;i++){
    float4 l = *(const float4*)(L + (long)eid[i]*4);
    m0=fmaxf(m0,l.x); m1=fmaxf(m1,l.y); m2=fmaxf(m2,l.z); m3=fmaxf(m3,l.w);
  }
  if (b==e1){ m0=m1=m2=m3=0.f; }
  float s0=0.f,s1=0.f,s2=0.f,s3=0.f;
  for (int i=b;i<e1;i++){
    float4 l = *(const float4*)(L + (long)eid[i]*4);
    s0+=expf(l.x-m0); s1+=expf(l.y-m1); s2+=expf(l.z-m2); s3+=expf(l.w-m3);
  }
  float d0=1.f/(s0+1e-16f), d1=1.f/(s1+1e-16f), d2=1.f/(s2+1e-16f), d3=1.f/(s3+1e-16f);
  float c[4][10] = {};
  for (int i=b;i<e1;i++){
    int e = eid[i];
    float4 l = *(const float4*)(L + (long)e*4);
    float4 w = { expf(l.x-m0)*d0, expf(l.y-m1)*d1, expf(l.z-m2)*d2, expf(l.w-m3)*d3 };
    *(float4*)(L + (long)e*4) = w;
    float4 a0 = *(const float4*)(ea + (long)e*12);
    float4 a1 = *(const float4*)(ea + (long)e*12 + 4);
    float4 a2 = *(const float4*)(ea + (long)e*12 + 8);
    float cc[10] = {a0.y,a0.z,a0.w, a1.x,a1.y,a1.z,a1.w, a2.x,a2.y,a2.z};
    #pragma unroll
    for (int k=0;k<10;k++){
      c[0][k] += w.x*cc[k]; c[1][k] += w.y*cc[k];
      c[2][k] += w.z*cc[k]; c[3][k] += w.w*cc[k];
    }
  }
  float* cp = cw + (long)n*40;
  #pragma unroll
  for (int h=0;h<4;h++)
    #pragma unroll
    for (int k=0;k<10;k++) cp[h*10+k] = c[h][k];
}

// ---------------- edge gather v4: 8B/lane + 2-deep software prefetch ----------------
// thread t owns features [4t,4t+4) (head h=t>>6): one broadcast weight + one s16x4/edge.
// Prefetch issues edge i+1's (w,v) loads BEFORE edge i's FMAs -> latency hides (G7).
// Accumulation order unchanged -> bit-identical.
__global__ __launch_bounds__(256) void k_gath(
    const u16* __restrict__ hg, const int* __restrict__ ei,
    const int* __restrict__ iptr, const int* __restrict__ eid,
    const float* __restrict__ L,      // holds w[e][h] (from k_mden)
    const float* __restrict__ cw,     // [NN][4][10]
    const u16* __restrict__ We16, const float* __restrict__ cb,
    u16* __restrict__ lio)
{
  __shared__ u16  sWe[10*HID];   // 20 KB
  __shared__ float scb[HID];     // 4 KB
  int tid = threadIdx.x;
  for (int i=tid;i<10*HID;i+=256) sWe[i] = We16[i];
  for (int i=tid;i<HID;i+=256) scb[i] = cb[i];
  __syncthreads();
  int h = tid >> 6;
  int f0 = tid*4;
  int d0 = blockIdx.x*NB, dend = min(NN, d0+NB);
  for (int d=d0; d<dend; d++){
    s16x4 a0 = *(const s16x4*)(lio + (long)d*HID + f0);
    float acc0=bf((u16)a0.x), acc1=bf((u16)a0.y), acc2=bf((u16)a0.z), acc3=bf((u16)a0.w);
    int b0 = iptr[d], en = iptr[d+1];
    float wN = 0.f; s16x4 vN = {};
    if (b0 < en){
      int e = eid[b0], s_ = ei[e];
      wN = L[(long)e*4 + h];
      vN = *(const s16x4*)(hg + (long)s_*HID + f0);
    }
    for (int i=b0;i<en;i++){
      float w = wN; s16x4 v = vN;
      if (i+1 < en){
        int e2 = eid[i+1], s2 = ei[e2];
        wN = L[(long)e2*4 + h];
        vN = *(const s16x4*)(hg + (long)s2*HID + f0);
      }
      acc0 += w*bf((u16)v.x); acc1 += w*bf((u16)v.y);
      acc2 += w*bf((u16)v.z); acc3 += w*bf((u16)v.w);
    }
    const float* cp = cw + (long)d*40 + h*10;
    float ew0=0.f, ew1=0.f, ew2=0.f, ew3=0.f;
    #pragma unroll
    for (int k=0;k<10;k++){
      float c = cp[k];
      s16x4 wv = *(const s16x4*)(sWe + k*HID + f0);
      ew0 += c*bf((u16)wv.x); ew1 += c*bf((u16)wv.y);
      ew2 += c*bf((u16)wv.z); ew3 += c*bf((u16)wv.w);
    }
    acc0 += ew0; acc1 += ew1; acc2 += ew2; acc3 += ew3;
    u16 o[4];
    o[0] = fb(fmaxf(acc0 + scb[f0  ], 0.f));
    o[1] = fb(fmaxf(acc1 + scb[f0+1], 0.f));
    o[2] = fb(fmaxf(acc2 + scb[f0+2], 0.f));
    o[3] = fb(fmaxf(acc3 + scb[f0+3], 0.f));
    *(s16x4*)(lio + (long)d*HID + f0) = *(const s16x4*)o;
  }
}

// ---------------- layer 3 ----------------
__global__ void k_c4init(const float* __restrict__ lb, float* __restrict__ c4){
  if (threadIdx.x==0 && blockIdx.x==0){ c4[0]=0.f; c4[1]=0.f; c4[2]=lb[0]; c4[3]=lb[1]; }
}

// fold BN scale into interleaved weights W4[k][4] = {Wg0,Wg1,lw0,lw1}*sc; shift -> c4
__global__ __launch_bounds__(256) void k_fold3(const float* __restrict__ Wg, const float* __restrict__ lw,
                        const float* __restrict__ scale, const float* __restrict__ shift,
                        float* __restrict__ W4, float* __restrict__ c4){
  int k = blockIdx.x*256 + threadIdx.x;   // grid 4, covers HID exactly
  float sc = scale[k], sh = shift[k];
  float w0=Wg[k*2], w1=Wg[k*2+1], l0=lw[k*2], l1=lw[k*2+1];
  float4 o = {w0*sc, w1*sc, l0*sc, l1*sc};
  *(float4*)(W4 + (long)k*4) = o;
  __shared__ float red[256][4];
  int tid = threadIdx.x;
  red[tid][0]=sh*w0; red[tid][1]=sh*w1; red[tid][2]=sh*l0; red[tid][3]=sh*l1;
  __syncthreads();
  for (int o2=128;o2>0;o2>>=1){
    if (tid<o2){
      #pragma unroll
      for (int j=0;j<4;j++) red[tid][j]+=red[tid+o2][j];
    }
    __syncthreads();
  }
  if (tid==0){
    #pragma unroll
    for (int j=0;j<4;j++) atomicAdd(&c4[j], red[0][j]);
  }
}

// wave-per-node GEMV: x-rows and W4 staged in LDS, shuffle reduce, no post-stage barriers
__global__ __launch_bounds__(256) void k_n3(const u16* __restrict__ in,
    const float* __restrict__ W4, const float* __restrict__ c4,
    const float* __restrict__ attn,
    float* __restrict__ hg3, float* __restrict__ lin3,
    float* __restrict__ ssrc, float* __restrict__ sdst)
{
  __shared__ float sW[HID*4];   // 16 KB
  __shared__ float sx[4][HID];  // 16 KB
  int tid = threadIdx.x;
  int n0 = blockIdx.x*4;        // grid 5000 exact
  for (int i=tid; i<HID; i+=256) *(float4*)&sW[i*4] = *(const float4*)(W4 + (long)i*4);
  for (int idx=tid; idx<512; idx+=256){
    int rr = idx>>7, ch = idx&127;
    bf16x8 v = *(const bf16x8*)(in + (long)(n0+rr)*HID + ch*8);
    #pragma unroll
    for (int j=0;j<8;j++) sx[rr][ch*8+j] = bf((u16)v[j]);
  }
  __syncthreads();
  int w = tid>>6, lane = tid&63;
  float p0=0.f,p1=0.f,p2=0.f,p3=0.f;
  #pragma unroll
  for (int g=0; g<16; g++){
    int k = g*64 + lane;                      // lanes consecutive -> conflict-free
    float x = sx[w][k];
    float4 wv = *(const float4*)&sW[k*4];
    p0 += x*wv.x; p1 += x*wv.y; p2 += x*wv.z; p3 += x*wv.w;
  }
  #pragma unroll
  for (int off=32; off>0; off>>=1){
    p0 += __shfl_down(p0, off);
    p1 += __shfl_down(p1, off);
    p2 += __shfl_down(p2, off);
    p3 += __shfl_down(p3, off);
  }
  if (lane==0){
    int n = n0 + w;
    float r0=p0+c4[0], r1=p1+c4[1], r2=p2+c4[2], r3=p3+c4[3];
    hg3[n*2]=r0; hg3[n*2+1]=r1;
    lin3[n*2]=r2; lin3[n*2+1]=r3;
    ssrc[n]=r0*attn[0]+r1*attn[1];
    sdst[n]=r0*attn[2]+r1*attn[3];
  }
}

__global__ void k_logits3(const int* __restrict__ ei, const float* __restrict__ ea,
                          const float* __restrict__ We, const float* __restrict__ attn,
                          const float* __restrict__ at, const float* __restrict__ ssrc,
                          const float* __restrict__ sdst, float* __restrict__ L){
  int e = blockIdx.x*256 + threadIdx.x;
  if (e >= EE) return;
  int s = ei[e], d = ei[EE+e];
  float e0=0.f, e1=0.f;
  #pragma unroll
  for (int k=0;k<10;k++){
    float c = ea[e*12+1+k];
    e0 += c*We[k*2]; e1 += c*We[k*2+1];
  }
  float se = e0*attn[4] + e1*attn[5];
  float v = ssrc[s] + sdst[d] + se + ea[e*12]*at[0];
  L[e] = (v>0.f)? v : 0.2f*v;
}

// layer-3 softmax finalize: w in place + cw3[n][k]
__global__ void k_mden3(const int* __restrict__ iptr, const int* __restrict__ eid,
                        const float* __restrict__ ea, float* __restrict__ L,
                        float* __restrict__ cw){
  int n = blockIdx.x*256 + threadIdx.x;
  if (n >= NN) return;
  int b = iptr[n], e1 = iptr[n+1];
  float mx = -INFINITY;
  for (int i=b;i<e1;i++) mx = fmaxf(mx, L[eid[i]]);
  if (b == e1) mx = 0.f;
  float s = 0.f;
  for (int i=b;i<e1;i++) s += expf(L[eid[i]] - mx);
  float dv = 1.f/(s+1e-16f);
  float c[10] = {0.f,0.f,0.f,0.f,0.f,0.f,0.f,0.f,0.f,0.f};
  for (int i=b;i<e1;i++){
    int e = eid[i];
    float w = expf(L[e]-mx)*dv;
    L[e] = w;
    #pragma unroll
    for (int k=0;k<10;k++) c[k] += w*ea[e*12+1+k];
  }
  float* cp = cw + (long)n*10;
  #pragma unroll
  for (int k=0;k<10;k++) cp[k] = c[k];
}

__global__ void k_gather3(const int* __restrict__ ei,
                          const int* __restrict__ iptr, const int* __restrict__ eid,
                          const float* __restrict__ L,      // holds w[e]
                          const float* __restrict__ cw,     // [NN][10]
                          const float* __restrict__ hg3,
                          const float* __restrict__ We, const float* __restrict__ lin3,
                          const float* __restrict__ cb, float* __restrict__ out){
  int n = blockIdx.x*256 + threadIdx.x;
  if (n >= NN) return;
  int b = iptr[n], en = iptr[n+1];
  const float* cp = cw + (long)n*10;
  float e0f=0.f, e1f=0.f;
  #pragma unroll
  for (int k=0;k<10;k++){ e0f += cp[k]*We[k*2]; e1f += cp[k]*We[k*2+1]; }
  float a0=0.f, a1=0.f;
  for (int i=b;i<en;i++){
    int e = eid[i], s_ = ei[e];
    float w = L[e];
    a0 += w*hg3[s_*2];
    a1 += w*hg3[s_*2+1];
  }
  out[n*2]   = fmaxf(lin3[n*2]  +a0+e0f+cb[0], 0.f);
  out[n*2+1] = fmaxf(lin3[n*2+1]+a1+e1f+cb[1], 0.f);
}

extern "C" void kernel_launch(void* const* d_in, const int* in_sizes, int n_in,
                              void* d_out, int out_size, void* d_ws, size_t ws_size,
                              hipStream_t stream){
  const int* ei = (const int*)d_in[1];

  long long sz[64];
  {
    const long long* s64 = (const long long*)(const void*)in_sizes;
    bool is64 = (n_in >= 2) && (in_sizes[0] == 3340000) && (in_sizes[1] == 0)
                && (s64[1] == 200000);
    for (int i=0;i<n_in && i<64;i++) sz[i] = is64 ? s64[i] : (long long)in_sizes[i];
  }

  int IWg[3], IWe[3], IAttn[3], IAt[3], ICb[3], ILw[3], ILb[3], IG[3], IB[3];
  if (n_in > 8 && sz[8] == (long long)HID*HID){ // setup_inputs() dict order
    for (int l=0;l<3;l++){
      IWg[l]=3+l*5; IWe[l]=4+l*5; IAttn[l]=5+l*5; IAt[l]=6+l*5; ICb[l]=7+l*5;
      ILw[l]=18+l*4; ILb[l]=19+l*4; IG[l]=20+l*4; IB[l]=21+l*4;
    }
  } else {
    int idx=3;
    for (int l=0;l<3;l++){
      IWg[l]=idx++; IWe[l]=idx++; IAttn[l]=idx++; IAt[l]=idx++; ICb[l]=idx++;
      ILw[l]=idx++; ILb[l]=idx++; IG[l]=idx++; IB[l]=idx++;
    }
  }
  #define FP(i) ((const float*)d_in[(i)])

  char* ws = (char*)d_ws;
  size_t off = 0;
  auto alloc = [&](size_t bytes)->void*{ void* p = ws + off; off += (bytes + 255) & ~(size_t)255; return p; };
  auto G = [](long n){ return (int)((n+255)/256); };

  u16*   buf0 = (u16*)  alloc((size_t)NN*HID*2);   // hg (bf16)
  u16*   bufA = (u16*)  alloc((size_t)NN*HID*2);   // layer-1 lin/result
  u16*   bufB = (u16*)  alloc((size_t)NN*HID*2);   // layer-2 lin/result
  u16*   xbf  = (u16*)  alloc((size_t)NN*KP1*2);   // layer-1 A (bf16, padded)
  u16*   Wt   = (u16*)  alloc((size_t)2*HID*HID*2);// fused folded weights [2048][K] K-major
  u16*   We16 = (u16*)  alloc((size_t)10*HID*2);
  float* cst  = (float*)alloc(2*HID*4);
  float* L    = (float*)alloc((size_t)EE*4*4);
  float* ssrc = (float*)alloc((size_t)NN*4*4);
  float* sdst = (float*)alloc((size_t)NN*4*4);
  int*   iptr = (int*)  alloc((size_t)(NN+4)*4);
  int*   cnts = (int*)  alloc((size_t)NN*4);
  int*   eid  = (int*)  alloc((size_t)EE*4);
  int*   bsum = (int*)  alloc(256*4);
  int*   boff = (int*)  alloc(256*4);
  float* stats= (float*)alloc(2*HID*4);
  float* scale= (float*)alloc(HID*4);
  float* shift= (float*)alloc(HID*4);
  float* qbuf = (float*)alloc(64*4);
  float* hg3  = (float*)alloc((size_t)NN*2*4);
  float* lin3 = (float*)alloc((size_t)NN*2*4);
  float* cw   = (float*)alloc((size_t)NN*40*4);    // factored edge-feature weights
  float* W4   = (float*)alloc((size_t)HID*4*4);    // layer-3 folded interleaved weights
  float* c4   = (float*)alloc(4*4);
  float* part = (float*)alloc((size_t)256*2048*4); // bnstats8 partials (2 MB)

  // ---- CSR by dst (two-level scan) ----
  int nsb = G(NN);   // 79 scan blocks
  hipMemsetAsync(cnts, 0, NN*sizeof(int), stream);
  k_count<<<G(EE),256,0,stream>>>(ei, cnts);
  k_scanA<<<nsb,256,0,stream>>>(cnts, iptr, bsum);
  k_scanB<<<1,128,0,stream>>>(bsum, boff, iptr+NN, nsb);
  k_scanC<<<nsb,256,0,stream>>>(boff, iptr);
  hipMemsetAsync(cnts, 0, NN*sizeof(int), stream);
  k_fill<<<G(EE),256,0,stream>>>(ei, iptr, cnts, eid);

  int gg = 1264;   // 79 row-tiles (256 rows) x 16 col-tiles (128 cols), XCD-swizzled in-kernel
  int gsd = (NN*4+3)/4;   // k_sdot: one wave per (n,h)

  // ---- layer 1 (A = bf16(x), Kp=256) ----
  {
    hipMemsetAsync(stats, 0, 2*FIN*sizeof(float), stream);
    dim3 bg(200, 1);
    k_bnstats<float><<<bg,256,0,stream>>>(FP(0), stats, FIN);
    k_bnfin<<<1,256,0,stream>>>(stats, FP(IG[0]), FP(IB[0]), scale, shift, FIN);
    k_cast<<<G((long)NN*KP1),256,0,stream>>>(FP(0), xbf);
    dim3 ft(KP1/32, 64);
    k_foldT<<<ft,256,0,stream>>>(FP(IWg[0]), FP(ILw[0]), scale, Wt, FIN, KP1);
    k_cinit<<<8,256,0,stream>>>(FP(ILb[0]), cst);
    dim3 cg(32, (FIN+127)/128);
    k_const<<<cg,256,0,stream>>>(FP(IWg[0]), FP(ILw[0]), shift, cst, FIN);
    k_we16<<<40,256,0,stream>>>(FP(IWe[0]), We16);
    k_gemm<<<gg,512,0,stream>>>(xbf, KP1, Wt, cst, buf0, bufA);
    k_sdot<<<gsd,256,0,stream>>>(buf0, FP(IAttn[0]), ssrc, sdst);
    k_q<<<1,64,0,stream>>>(FP(IWe[0]), FP(IAttn[0]), qbuf);
    k_logits<<<G(EE),256,0,stream>>>(ei, FP(2), qbuf, FP(IAt[0]), ssrc, sdst, L);
    k_mden<<<G(NN),256,0,stream>>>(iptr, eid, FP(2), L, cw);
    k_gath<<<(NN+NB-1)/NB,256,0,stream>>>(buf0, ei, iptr, eid, L, cw,
                                          We16, FP(ICb[0]), bufA);
  }
  // ---- layer 2 (A = bufA, K=1024) ----
  {
    k_bnstats8<<<256,256,0,stream>>>(bufA, part);
    k_pred<<<8,256,0,stream>>>(part, stats);
    k_bnfin<<<4,256,0,stream>>>(stats, FP(IG[1]), FP(IB[1]), scale, shift, HID);
    dim3 ft(HID/32, 64);
    k_foldT<<<ft,256,0,stream>>>(FP(IWg[1]), FP(ILw[1]), scale, Wt, HID, HID);
    k_cinit<<<8,256,0,stream>>>(FP(ILb[1]), cst);
    dim3 cg(32, HID/128);
    k_const<<<cg,256,0,stream>>>(FP(IWg[1]), FP(ILw[1]), shift, cst, HID);
    k_we16<<<40,256,0,stream>>>(FP(IWe[1]), We16);
    k_gemm<<<gg,512,0,stream>>>(bufA, HID, Wt, cst, buf0, bufB);
    k_sdot<<<gsd,256,0,stream>>>(buf0, FP(IAttn[1]), ssrc, sdst);
    k_q<<<1,64,0,stream>>>(FP(IWe[1]), FP(IAttn[1]), qbuf);
    k_logits<<<G(EE),256,0,stream>>>(ei, FP(2), qbuf, FP(IAt[1]), ssrc, sdst, L);
    k_mden<<<G(NN),256,0,stream>>>(iptr, eid, FP(2), L, cw);
    k_gath<<<(NN+NB-1)/NB,256,0,stream>>>(buf0, ei, iptr, eid, L, cw,
                                          We16, FP(ICb[1]), bufB);
  }

  // ---- layer 3 (input = bufB) ----
  k_bnstats8<<<256,256,0,stream>>>(bufB, part);
  k_pred<<<8,256,0,stream>>>(part, stats);
  k_bnfin<<<4,256,0,stream>>>(stats, FP(IG[2]), FP(IB[2]), scale, shift, HID);
  k_c4init<<<1,64,0,stream>>>(FP(ILb[2]), c4);
  k_fold3<<<HID/256,256,0,stream>>>(FP(IWg[2]), FP(ILw[2]), scale, shift, W4, c4);
  k_n3<<<NN/4,256,0,stream>>>(bufB, W4, c4, FP(IAttn[2]), hg3, lin3, ssrc, sdst);
  k_logits3<<<G(EE),256,0,stream>>>(ei, FP(2), FP(IWe[2]), FP(IAttn[2]), FP(IAt[2]), ssrc, sdst, L);
  k_mden3<<<G(NN),256,0,stream>>>(iptr, eid, FP(2), L, cw);
  k_gather3<<<G(NN),256,0,stream>>>(ei, iptr, eid, L, cw, hg3,
                                    FP(IWe[2]), lin3, FP(ICb[2]), (float*)d_out);
}

// Round 10
// 765.386 us; speedup vs baseline: 1.6339x; 1.0652x over previous
//
#include <hip/hip_runtime.h>
#include <math.h>

#define NN 20000
#define EE 100000
#define FIN 167
#define KP1 256    // layer-1 K padded to mult of 64
#define HID 1024   // H*O = 4*256
#define OO 256
#define NB 8       // nodes per k_gath block

typedef unsigned short u16;
typedef short bf16x8 __attribute__((ext_vector_type(8)));
typedef short s16x4  __attribute__((ext_vector_type(4)));
typedef float f32x4  __attribute__((ext_vector_type(4)));

__device__ __forceinline__ float bf(u16 u){ return __uint_as_float(((unsigned)u)<<16); }
__device__ __forceinline__ u16 fb(float v){            // f32 -> bf16 RNE
  unsigned u = __float_as_uint(v);
  return (u16)((u + 0x7FFFu + ((u>>16)&1u)) >> 16);
}
__device__ __forceinline__ float ldv(const float* p, long i){ return p[i]; }
__device__ __forceinline__ float ldv(const u16*   p, long i){ return bf(p[i]); }

// ---------------- CSR build ----------------
__global__ void k_count(const int* __restrict__ ei, int* __restrict__ counts){
  int e = blockIdx.x*256 + threadIdx.x;
  if (e < EE) atomicAdd(&counts[ei[EE+e]], 1);
}

// two-level scan
__global__ __launch_bounds__(256) void k_scanA(const int* __restrict__ counts,
                                               int* __restrict__ iptr, int* __restrict__ bsum){
  __shared__ int sd[256];
  int b = blockIdx.x, tid = threadIdx.x;
  int i = b*256 + tid;
  int v = (i<NN)? counts[i] : 0;
  sd[tid]=v; __syncthreads();
  for (int off=1; off<256; off<<=1){
    int t = (tid>=off)? sd[tid-off] : 0;
    __syncthreads();
    sd[tid] += t;
    __syncthreads();
  }
  if (i<NN) iptr[i] = sd[tid]-v;     // block-local exclusive
  if (tid==255) bsum[b]=sd[255];
}
__global__ __launch_bounds__(128) void k_scanB(const int* __restrict__ bsum,
                                               int* __restrict__ boff, int* __restrict__ iptrN,
                                               int nb){
  __shared__ int sd[128];
  int tid=threadIdx.x;
  int v=(tid<nb)? bsum[tid]:0;
  sd[tid]=v; __syncthreads();
  for (int off=1; off<128; off<<=1){
    int t=(tid>=off)?sd[tid-off]:0;
    __syncthreads();
    sd[tid]+=t;
    __syncthreads();
  }
  if (tid<nb) boff[tid]=sd[tid]-v;
  if (tid==127) *iptrN = sd[127];
}
__global__ void k_scanC(const int* __restrict__ boff, int* __restrict__ iptr){
  int i = blockIdx.x*256+threadIdx.x;
  if (i<NN) iptr[i] += boff[blockIdx.x];
}

__global__ void k_fill(const int* __restrict__ ei, const int* __restrict__ iptr,
                       int* __restrict__ cursor, int* __restrict__ eid){
  int e = blockIdx.x*256 + threadIdx.x;
  if (e < EE){
    int d = ei[EE+e];
    int pos = atomicAdd(&cursor[d],1);
    eid[iptr[d]+pos] = e;
  }
}

// ---------------- BatchNorm stats ----------------
// layer-1 (float input, F=167): original coalesced version (never hot; 67K atomics OK)
template<typename T>
__global__ void k_bnstats(const T* __restrict__ X, float* __restrict__ sums, int F){
  int f = blockIdx.y*256 + threadIdx.x;
  if (f >= F) return;
  int r0 = blockIdx.x*100, r1 = r0+100;
  float s=0.f, s2=0.f;
  for (int r=r0;r<r1;r++){ float v = ldv(X,(long)r*F+f); s += v; s2 += v*v; }
  atomicAdd(&sums[f], s);
  atomicAdd(&sums[F+f], s2);
}

// layers 2/3 (bf16, F=HID) stage A: zero-atomic partials (round-7 lesson: atomics storm)
__global__ __launch_bounds__(256) void k_bnstats8(const u16* __restrict__ X, float* __restrict__ part){
  int tid = threadIdx.x;
  int f8 = (tid & 127)*8;
  int r0 = blockIdx.x*79, r1 = min(NN, r0+79);     // grid 256
  float s[8]={0,0,0,0,0,0,0,0}, s2[8]={0,0,0,0,0,0,0,0};
  for (int r=r0 + (tid>>7); r<r1; r+=2){
    bf16x8 v = *(const bf16x8*)(X + (long)r*HID + f8);
    #pragma unroll
    for (int j=0;j<8;j++){ float x=bf((u16)v[j]); s[j]+=x; s2[j]+=x*x; }
  }
  __shared__ float red[256][8];
  float* pb = part + (long)blockIdx.x*2048;
  #pragma unroll
  for (int j=0;j<8;j++) red[tid][j]=s[j];
  __syncthreads();
  if (tid<128){
    #pragma unroll
    for (int j=0;j<8;j++) pb[f8+j] = red[tid][j]+red[tid+128][j];
  }
  __syncthreads();
  #pragma unroll
  for (int j=0;j<8;j++) red[tid][j]=s2[j];
  __syncthreads();
  if (tid<128){
    #pragma unroll
    for (int j=0;j<8;j++) pb[1024+f8+j] = red[tid][j]+red[tid+128][j];
  }
}

// stage B: reduce 256 partials -> sums[2048]; consecutive threads = consecutive addrs
__global__ __launch_bounds__(256) void k_pred(const float* __restrict__ part, float* __restrict__ sums){
  int idx = blockIdx.x*256 + threadIdx.x;   // grid 8 -> 2048 threads
  float s = 0.f;
  #pragma unroll 8
  for (int b=0;b<256;b++) s += part[(long)b*2048 + idx];
  sums[idx] = s;
}

__global__ void k_bnfin(const float* __restrict__ sums, const float* __restrict__ g,
                        const float* __restrict__ b, float* __restrict__ scale,
                        float* __restrict__ shift, int F){
  int f = blockIdx.x*256 + threadIdx.x;
  if (f >= F) return;
  float mu  = sums[f]   * (1.f/NN);
  float var = sums[F+f] * (1.f/NN) - mu*mu;
  float sc  = rsqrtf(var + 1e-5f) * g[f];
  scale[f] = sc;
  shift[f] = b[f] - mu*sc;
}

// ---------------- BN-folded fused weight prep ----------------
__global__ __launch_bounds__(256) void k_foldT(const float* __restrict__ Wg, const float* __restrict__ Wl,
                        const float* __restrict__ scale,
                        u16* __restrict__ Wt, int K, int Kp){
  __shared__ float t[32][33];
  int k0 = blockIdx.x*32, c0 = blockIdx.y*32;
  int tx = threadIdx.x & 31, ty = threadIdx.x >> 5;
  bool second = (c0 >= HID);
  const float* W = second ? Wl : Wg;
  int cc0 = second ? c0 - HID : c0;
  #pragma unroll
  for (int i=0;i<4;i++){
    int k = k0 + ty + i*8;
    t[ty+i*8][tx] = (k < K) ? W[(long)k*HID + cc0 + tx] * scale[k] : 0.f;
  }
  __syncthreads();
  #pragma unroll
  for (int i=0;i<4;i++){
    int c = c0 + ty + i*8;
    Wt[(long)c*Kp + k0 + tx] = fb(t[tx][ty+i*8]);
  }
}

// cst init: lb for lin half, 0 for hg half
__global__ void k_cinit(const float* __restrict__ lb, float* __restrict__ cst){
  int c = blockIdx.x*256 + threadIdx.x;
  if (c < 2*HID) cst[c] = (c >= HID) ? lb[c-HID] : 0.f;
}

// cst[c] += sum_k shift[k]*W[k][c]  — parallel reduction, coalesced
__global__ __launch_bounds__(256) void k_const(const float* __restrict__ Wg, const float* __restrict__ Wl,
                        const float* __restrict__ shift, float* __restrict__ cst, int K){
  int tx = threadIdx.x & 63, ty = threadIdx.x >> 6;
  int c = blockIdx.x*64 + tx;
  bool second = c >= HID;
  const float* W = second ? Wl : Wg;
  int cc = second ? c-HID : c;
  int k0 = blockIdx.y*128;
  int k1 = min(K, k0+128);
  float s = 0.f;
  for (int k=k0+ty; k<k1; k+=4) s += shift[k]*W[(long)k*HID+cc];
  __shared__ float red[256];
  red[threadIdx.x] = s;
  __syncthreads();
  if (ty == 0){
    float tot = red[tx] + red[tx+64] + red[tx+128] + red[tx+192];
    atomicAdd(&cst[c], tot);
  }
}

__global__ void k_cast(const float* __restrict__ x, u16* __restrict__ xb){
  long idx = (long)blockIdx.x*256 + threadIdx.x;
  if (idx >= (long)NN*KP1) return;
  int n = (int)(idx / KP1), k = (int)(idx % KP1);
  xb[idx] = (k<FIN)? fb(x[(long)n*FIN+k]) : (u16)0;
}

__global__ void k_we16(const float* __restrict__ We, u16* __restrict__ We16){
  int i = blockIdx.x*256 + threadIdx.x;
  if (i < 10*HID) We16[i] = fb(We[i]);
}

// ---------------- MFMA GEMM v5: 256x128 tile, BK=32, 3-buffer / 2-tile-deep counted-vmcnt ----------------
// The untested combination: counted waits (r4) x multi-block residency (r0/m114).
//   3 LDS buffers of 24 KB (A 16K | B 8K) = 72 KB -> 2 blocks/CU (16 waves/CU).
//   Stage tile t+2 during tile t -> panels in flight 2 tiles (~500-700 cyc, covers L2 lat)
//   before their counted vmcnt(3). vmcnt(0) only once at the tail.
// Per-tile body = r4's proven phase: {8x ds_read_b128 ; 3x global_load_lds ; 16 MFMA ;
//   vmcnt(3) ; BAR}. Swizzle/addressing byte-identical to r4 (verified).
// Ledger: prologue stages t0,t1 (6) -> vmcnt(3) = t0 landed. Steady: enter t with 3
//   outstanding (t+1), +3 for t+2 = 6 -> vmcnt(3) retires exactly t+1's slice per wave.
#define MF(a_,b_,c_) __builtin_amdgcn_mfma_f32_16x16x32_bf16(a_,b_,c_,0,0,0)
#define FENCE asm volatile("" ::: "memory")
#define BAR do { FENCE; __builtin_amdgcn_s_barrier(); FENCE; } while(0)

__global__ __launch_bounds__(512,2) void k_gemm(const u16* __restrict__ A, int K,
                     const u16* __restrict__ Wt, const float* __restrict__ cst,
                     u16* __restrict__ Chg, u16* __restrict__ Clin){
  __shared__ u16 lds[3][12288];   // 3 x (A 8192 u16 | B 4096 u16) = 72 KB
  int b = blockIdx.x;
  int wg = (b & 7)*158 + (b >> 3);          // 1264 % 8 == 0 -> bijective XCD swizzle
  int row0 = (wg >> 4)*256, col0 = (wg & 15)*128;
  int tid = threadIdx.x;
  int wave = tid >> 6, lane = tid & 63, quad = lane >> 4, lo = lane & 15;
  int wm = wave >> 1, wn = wave & 1;        // 4 M-waves x 2 N-waves, 64x64 out each
  const u16* Apt[2];
  #pragma unroll
  for (int i=0;i<2;i++){
    int s = i*512 + tid, srow = s>>2;
    int gr = row0 + srow; if (gr >= NN) gr = NN-1;      // clamp: garbage rows never stored
    Apt[i] = A + (long)gr*K + (((s&3)^(srow&3))*8);
  }
  int brow = tid>>2;
  const u16* Bpt = Wt + (long)(col0 + brow)*K + ((((tid&3)^(brow&3)))*8);
  const char* ldsc = (const char*)&lds[0][0];
  int axor = lo & 3;
  int aoff = (wm*64 + lo)*64 + ((quad^axor)*16);            // A frag i at +i*1024 B
  int boff = 16384 + (wn*64 + lo)*64 + ((quad^axor)*16);    // B frag n at +n*1024 B
  int NT = K >> 5;
  f32x4 acc[4][4] = {};
  // ---- prologue: stage tiles 0,1 into buffers 0,1 ----
  {
    u16* d0 = (u16*)&lds[0][0];
    u16* d1 = (u16*)&lds[1][0];
    __builtin_amdgcn_global_load_lds(Apt[0],      d0 +         tid*8, 16, 0, 0);
    __builtin_amdgcn_global_load_lds(Apt[1],      d0 + 4096 +  tid*8, 16, 0, 0);
    __builtin_amdgcn_global_load_lds(Bpt,         d0 + 8192 +  tid*8, 16, 0, 0);
    __builtin_amdgcn_global_load_lds(Apt[0] + 32, d1 +         tid*8, 16, 0, 0);
    __builtin_amdgcn_global_load_lds(Apt[1] + 32, d1 + 4096 +  tid*8, 16, 0, 0);
    __builtin_amdgcn_global_load_lds(Bpt    + 32, d1 + 8192 +  tid*8, 16, 0, 0);
    asm volatile("s_waitcnt vmcnt(3)" ::: "memory");   // tile-0 panels landed
    BAR;
  }
  int cb = 0;
  for (int t=0; t<NT; t++){
    const char* Lb = ldsc + cb*24576;
    bf16x8 af[4], bfr[4];
    #pragma unroll
    for (int i=0;i<4;i++) af[i]  = *(const bf16x8*)(Lb + aoff + i*1024);
    #pragma unroll
    for (int n=0;n<4;n++) bfr[n] = *(const bf16x8*)(Lb + boff + n*1024);
    int nx2 = (t+2 < NT);
    if (nx2){
      int sb = cb+2; if (sb>=3) sb-=3;       // buffer holding tile t-1 (consumed, barrier-safe)
      u16* Sd = (u16*)&lds[0][0] + sb*12288;
      int ko = (t+2) << 5;
      __builtin_amdgcn_global_load_lds(Apt[0] + ko, Sd +         tid*8, 16, 0, 0);
      __builtin_amdgcn_global_load_lds(Apt[1] + ko, Sd + 4096 +  tid*8, 16, 0, 0);
      __builtin_amdgcn_global_load_lds(Bpt    + ko, Sd + 8192 +  tid*8, 16, 0, 0);
    }
    #pragma unroll
    for (int i=0;i<4;i++)
      #pragma unroll
      for (int n=0;n<4;n++)
        acc[i][n] = MF(af[i], bfr[n], acc[i][n]);
    if (t+1 < NT){
      if (nx2) asm volatile("s_waitcnt vmcnt(3)" ::: "memory");  // tile t+1 landed
      else     asm volatile("s_waitcnt vmcnt(0)" ::: "memory");  // tail (once)
      BAR;
    }
    cb++; if (cb>=3) cb=0;
  }
  // ---- epilogue (verified mapping, unchanged) ----
  #pragma unroll
  for (int i=0;i<4;i++){
    #pragma unroll
    for (int n=0;n<4;n++){
      int col = col0 + wn*64 + n*16 + lo;
      float cs = cst[col];
      #pragma unroll
      for (int r=0;r<4;r++){
        int row = row0 + wm*64 + i*16 + quad*4 + r;   // C/D: col=lane&15, row=quad*4+reg
        if (row < NN){
          u16 o = fb(acc[i][n][r] + cs);
          if (col < HID) Chg[(long)row*HID + col] = o;
          else           Clin[(long)row*HID + col - HID] = o;
        }
      }
    }
  }
}
#undef MF
#undef BAR
#undef FENCE

// ---------------- per-(node,head) attention dots: wave-parallel, coalesced ----------------
__global__ __launch_bounds__(256) void k_sdot(const u16* __restrict__ hg, const float* __restrict__ attn,
                       float* __restrict__ ssrc, float* __restrict__ sdst){
  int unit = blockIdx.x*4 + (threadIdx.x >> 6);   // one wave per (n,h)
  if (unit >= NN*4) return;
  int lane = threadIdx.x & 63;
  int n = unit >> 2, h = unit & 3;
  const u16* hp = hg + (long)n*HID + h*OO + lane*4;
  s16x4 v = *(const s16x4*)hp;
  float4 x0 = *(const float4*)(attn + h*OO + lane*4);
  float4 x1 = *(const float4*)(attn + HID + h*OO + lane*4);
  float f0 = bf((u16)v.x), f1 = bf((u16)v.y), f2 = bf((u16)v.z), f3 = bf((u16)v.w);
  float ss = f0*x0.x + f1*x0.y + f2*x0.z + f3*x0.w;
  float sd = f0*x1.x + f1*x1.y + f2*x1.z + f3*x1.w;
  #pragma unroll
  for (int off=32; off>0; off>>=1){
    ss += __shfl_down(ss, off);
    sd += __shfl_down(sd, off);
  }
  if (lane==0){ ssrc[unit]=ss; sdst[unit]=sd; }
}

__global__ void k_q(const float* __restrict__ We, const float* __restrict__ attn,
                    float* __restrict__ q){
  int t = threadIdx.x;
  if (t >= 40) return;
  int k = t >> 2, h = t & 3;
  float s = 0.f;
  for (int d=0; d<OO; d++) s += We[(long)k*HID + h*OO + d] * attn[2*HID + h*OO + d];
  q[k*4+h] = s;
}

// per-EDGE logits: ea read once, all 4 heads computed, float4 write
__global__ void k_logits(const int* __restrict__ ei, const float* __restrict__ ea,
                         const float* __restrict__ q, const float* __restrict__ at,
                         const float* __restrict__ ssrc, const float* __restrict__ sdst,
                         float* __restrict__ L){
  int e = blockIdx.x*256 + threadIdx.x;
  if (e >= EE) return;
  int s = ei[e], dd = ei[EE+e];
  float4 a0 = *(const float4*)(ea + (long)e*12);
  float4 a1 = *(const float4*)(ea + (long)e*12 + 4);
  float4 a2 = *(const float4*)(ea + (long)e*12 + 8);
  float t = a0.x;
  float cc[10] = {a0.y,a0.z,a0.w, a1.x,a1.y,a1.z,a1.w, a2.x,a2.y,a2.z};
  float4 ss = *(const float4*)(ssrc + (long)s*4);
  float4 sd = *(const float4*)(sdst + (long)dd*4);
  float sv[4] = {ss.x+sd.x, ss.y+sd.y, ss.z+sd.z, ss.w+sd.w};
  float4 out;
  #pragma unroll
  for (int h=0;h<4;h++){
    float se = 0.f;
    #pragma unroll
    for (int k=0;k<10;k++) se += cc[k]*q[k*4+h];
    float v = sv[h] + se + t*at[h];
    ((float*)&out)[h] = (v>0.f)? v : 0.2f*v;
  }
  *(float4*)(L + (long)e*4) = out;
}

// per-NODE softmax finalize: writes w = exp(L-m)*dinv IN PLACE into L (float4),
// accumulates cw[n][4][10] with ea read ONCE per edge
__global__ void k_mden(const int* __restrict__ iptr, const int* __restrict__ eid,
                       const float* __restrict__ ea, float* __restrict__ L,
                       float* __restrict__ cw){
  int n = blockIdx.x*256 + threadIdx.x;
  if (n >= NN) return;
  int b = iptr[n], e1 = iptr[n+1];
  float m0=-INFINITY, m1=-INFINITY, m2=-INFINITY, m3=-INFINITY;
  for (int i=b;i<e1;i++){
    float4 l = *(const float4*)(L + (long)eid[i]*4);
    m0=fmaxf(m0,l.x); m1=fmaxf(m1,l.y); m2=fmaxf(m2,l.z); m3=fmaxf(m3,l.w);
  }
  if (b==e1){ m0=m1=m2=m3=0.f; }
  float s0=0.f,s1=0.f,s2=0.f,s3=0.f;
  for (int i=b;i<e1;i++){
    float4 l = *(const float4*)(L + (long)eid[i]*4);
    s0+=expf(l.x-m0); s1+=expf(l.y-m1); s2+=expf(l.z-m2); s3+=expf(l.w-m3);
  }
  float d0=1.f/(s0+1e-16f), d1=1.f/(s1+1e-16f), d2=1.f/(s2+1e-16f), d3=1.f/(s3+1e-16f);
  float c[4][10] = {};
  for (int i=b;i<e1;i++){
    int e = eid[i];
    float4 l = *(const float4*)(L + (long)e*4);
    float4 w = { expf(l.x-m0)*d0, expf(l.y-m1)*d1, expf(l.z-m2)*d2, expf(l.w-m3)*d3 };
    *(float4*)(L + (long)e*4) = w;
    float4 a0 = *(const float4*)(ea + (long)e*12);
    float4 a1 = *(const float4*)(ea + (long)e*12 + 4);
    float4 a2 = *(const float4*)(ea + (long)e*12 + 8);
    float cc[10] = {a0.y,a0.z,a0.w, a1.x,a1.y,a1.z,a1.w, a2.x,a2.y,a2.z};
    #pragma unroll
    for (int k=0;k<10;k++){
      c[0][k] += w.x*cc[k]; c[1][k] += w.y*cc[k];
      c[2][k] += w.z*cc[k]; c[3][k] += w.w*cc[k];
    }
  }
  float* cp = cw + (long)n*40;
  #pragma unroll
  for (int h=0;h<4;h++)
    #pragma unroll
    for (int k=0;k<10;k++) cp[h*10+k] = c[h][k];
}

// ---------------- edge gather: 8B/lane + 2-deep software prefetch ----------------
__global__ __launch_bounds__(256) void k_gath(
    const u16* __restrict__ hg, const int* __restrict__ ei,
    const int* __restrict__ iptr, const int* __restrict__ eid,
    const float* __restrict__ L,      // holds w[e][h] (from k_mden)
    const float* __restrict__ cw,     // [NN][4][10]
    const u16* __restrict__ We16, const float* __restrict__ cb,
    u16* __restrict__ lio)
{
  __shared__ u16  sWe[10*HID];   // 20 KB
  __shared__ float scb[HID];     // 4 KB
  int tid = threadIdx.x;
  for (int i=tid;i<10*HID;i+=256) sWe[i] = We16[i];
  for (int i=tid;i<HID;i+=256) scb[i] = cb[i];
  __syncthreads();
  int h = tid >> 6;
  int f0 = tid*4;
  int d0 = blockIdx.x*NB, dend = min(NN, d0+NB);
  for (int d=d0; d<dend; d++){
    s16x4 a0 = *(const s16x4*)(lio + (long)d*HID + f0);
    float acc0=bf((u16)a0.x), acc1=bf((u16)a0.y), acc2=bf((u16)a0.z), acc3=bf((u16)a0.w);
    int b0 = iptr[d], en = iptr[d+1];
    float wN = 0.f; s16x4 vN = {};
    if (b0 < en){
      int e = eid[b0], s_ = ei[e];
      wN = L[(long)e*4 + h];
      vN = *(const s16x4*)(hg + (long)s_*HID + f0);
    }
    for (int i=b0;i<en;i++){
      float w = wN; s16x4 v = vN;
      if (i+1 < en){
        int e2 = eid[i+1], s2 = ei[e2];
        wN = L[(long)e2*4 + h];
        vN = *(const s16x4*)(hg + (long)s2*HID + f0);
      }
      acc0 += w*bf((u16)v.x); acc1 += w*bf((u16)v.y);
      acc2 += w*bf((u16)v.z); acc3 += w*bf((u16)v.w);
    }
    const float* cp = cw + (long)d*40 + h*10;
    float ew0=0.f, ew1=0.f, ew2=0.f, ew3=0.f;
    #pragma unroll
    for (int k=0;k<10;k++){
      float c = cp[k];
      s16x4 wv = *(const s16x4*)(sWe + k*HID + f0);
      ew0 += c*bf((u16)wv.x); ew1 += c*bf((u16)wv.y);
      ew2 += c*bf((u16)wv.z); ew3 += c*bf((u16)wv.w);
    }
    acc0 += ew0; acc1 += ew1; acc2 += ew2; acc3 += ew3;
    u16 o[4];
    o[0] = fb(fmaxf(acc0 + scb[f0  ], 0.f));
    o[1] = fb(fmaxf(acc1 + scb[f0+1], 0.f));
    o[2] = fb(fmaxf(acc2 + scb[f0+2], 0.f));
    o[3] = fb(fmaxf(acc3 + scb[f0+3], 0.f));
    *(s16x4*)(lio + (long)d*HID + f0) = *(const s16x4*)o;
  }
}

// ---------------- layer 3 ----------------
__global__ void k_c4init(const float* __restrict__ lb, float* __restrict__ c4){
  if (threadIdx.x==0 && blockIdx.x==0){ c4[0]=0.f; c4[1]=0.f; c4[2]=lb[0]; c4[3]=lb[1]; }
}

// fold BN scale into interleaved weights W4[k][4] = {Wg0,Wg1,lw0,lw1}*sc; shift -> c4
__global__ __launch_bounds__(256) void k_fold3(const float* __restrict__ Wg, const float* __restrict__ lw,
                        const float* __restrict__ scale, const float* __restrict__ shift,
                        float* __restrict__ W4, float* __restrict__ c4){
  int k = blockIdx.x*256 + threadIdx.x;   // grid 4, covers HID exactly
  float sc = scale[k], sh = shift[k];
  float w0=Wg[k*2], w1=Wg[k*2+1], l0=lw[k*2], l1=lw[k*2+1];
  float4 o = {w0*sc, w1*sc, l0*sc, l1*sc};
  *(float4*)(W4 + (long)k*4) = o;
  __shared__ float red[256][4];
  int tid = threadIdx.x;
  red[tid][0]=sh*w0; red[tid][1]=sh*w1; red[tid][2]=sh*l0; red[tid][3]=sh*l1;
  __syncthreads();
  for (int o2=128;o2>0;o2>>=1){
    if (tid<o2){
      #pragma unroll
      for (int j=0;j<4;j++) red[tid][j]+=red[tid+o2][j];
    }
    __syncthreads();
  }
  if (tid==0){
    #pragma unroll
    for (int j=0;j<4;j++) atomicAdd(&c4[j], red[0][j]);
  }
}

// wave-per-node GEMV: x-rows and W4 staged in LDS, shuffle reduce, no post-stage barriers
__global__ __launch_bounds__(256) void k_n3(const u16* __restrict__ in,
    const float* __restrict__ W4, const float* __restrict__ c4,
    const float* __restrict__ attn,
    float* __restrict__ hg3, float* __restrict__ lin3,
    float* __restrict__ ssrc, float* __restrict__ sdst)
{
  __shared__ float sW[HID*4];   // 16 KB
  __shared__ float sx[4][HID];  // 16 KB
  int tid = threadIdx.x;
  int n0 = blockIdx.x*4;        // grid 5000 exact
  for (int i=tid; i<HID; i+=256) *(float4*)&sW[i*4] = *(const float4*)(W4 + (long)i*4);
  for (int idx=tid; idx<512; idx+=256){
    int rr = idx>>7, ch = idx&127;
    bf16x8 v = *(const bf16x8*)(in + (long)(n0+rr)*HID + ch*8);
    #pragma unroll
    for (int j=0;j<8;j++) sx[rr][ch*8+j] = bf((u16)v[j]);
  }
  __syncthreads();
  int w = tid>>6, lane = tid&63;
  float p0=0.f,p1=0.f,p2=0.f,p3=0.f;
  #pragma unroll
  for (int g=0; g<16; g++){
    int k = g*64 + lane;                      // lanes consecutive -> conflict-free
    float x = sx[w][k];
    float4 wv = *(const float4*)&sW[k*4];
    p0 += x*wv.x; p1 += x*wv.y; p2 += x*wv.z; p3 += x*wv.w;
  }
  #pragma unroll
  for (int off=32; off>0; off>>=1){
    p0 += __shfl_down(p0, off);
    p1 += __shfl_down(p1, off);
    p2 += __shfl_down(p2, off);
    p3 += __shfl_down(p3, off);
  }
  if (lane==0){
    int n = n0 + w;
    float r0=p0+c4[0], r1=p1+c4[1], r2=p2+c4[2], r3=p3+c4[3];
    hg3[n*2]=r0; hg3[n*2+1]=r1;
    lin3[n*2]=r2; lin3[n*2+1]=r3;
    ssrc[n]=r0*attn[0]+r1*attn[1];
    sdst[n]=r0*attn[2]+r1*attn[3];
  }
}

__global__ void k_logits3(const int* __restrict__ ei, const float* __restrict__ ea,
                          const float* __restrict__ We, const float* __restrict__ attn,
                          const float* __restrict__ at, const float* __restrict__ ssrc,
                          const float* __restrict__ sdst, float* __restrict__ L){
  int e = blockIdx.x*256 + threadIdx.x;
  if (e >= EE) return;
  int s = ei[e], d = ei[EE+e];
  float e0=0.f, e1=0.f;
  #pragma unroll
  for (int k=0;k<10;k++){
    float c = ea[e*12+1+k];
    e0 += c*We[k*2]; e1 += c*We[k*2+1];
  }
  float se = e0*attn[4] + e1*attn[5];
  float v = ssrc[s] + sdst[d] + se + ea[e*12]*at[0];
  L[e] = (v>0.f)? v : 0.2f*v;
}

// layer-3 softmax finalize: w in place + cw3[n][k]
__global__ void k_mden3(const int* __restrict__ iptr, const int* __restrict__ eid,
                        const float* __restrict__ ea, float* __restrict__ L,
                        float* __restrict__ cw){
  int n = blockIdx.x*256 + threadIdx.x;
  if (n >= NN) return;
  int b = iptr[n], e1 = iptr[n+1];
  float mx = -INFINITY;
  for (int i=b;i<e1;i++) mx = fmaxf(mx, L[eid[i]]);
  if (b == e1) mx = 0.f;
  float s = 0.f;
  for (int i=b;i<e1;i++) s += expf(L[eid[i]] - mx);
  float dv = 1.f/(s+1e-16f);
  float c[10] = {0.f,0.f,0.f,0.f,0.f,0.f,0.f,0.f,0.f,0.f};
  for (int i=b;i<e1;i++){
    int e = eid[i];
    float w = expf(L[e]-mx)*dv;
    L[e] = w;
    #pragma unroll
    for (int k=0;k<10;k++) c[k] += w*ea[e*12+1+k];
  }
  float* cp = cw + (long)n*10;
  #pragma unroll
  for (int k=0;k<10;k++) cp[k] = c[k];
}

__global__ void k_gather3(const int* __restrict__ ei,
                          const int* __restrict__ iptr, const int* __restrict__ eid,
                          const float* __restrict__ L,      // holds w[e]
                          const float* __restrict__ cw,     // [NN][10]
                          const float* __restrict__ hg3,
                          const float* __restrict__ We, const float* __restrict__ lin3,
                          const float* __restrict__ cb, float* __restrict__ out){
  int n = blockIdx.x*256 + threadIdx.x;
  if (n >= NN) return;
  int b = iptr[n], en = iptr[n+1];
  const float* cp = cw + (long)n*10;
  float e0f=0.f, e1f=0.f;
  #pragma unroll
  for (int k=0;k<10;k++){ e0f += cp[k]*We[k*2]; e1f += cp[k]*We[k*2+1]; }
  float a0=0.f, a1=0.f;
  for (int i=b;i<en;i++){
    int e = eid[i], s_ = ei[e];
    float w = L[e];
    a0 += w*hg3[s_*2];
    a1 += w*hg3[s_*2+1];
  }
  out[n*2]   = fmaxf(lin3[n*2]  +a0+e0f+cb[0], 0.f);
  out[n*2+1] = fmaxf(lin3[n*2+1]+a1+e1f+cb[1], 0.f);
}

extern "C" void kernel_launch(void* const* d_in, const int* in_sizes, int n_in,
                              void* d_out, int out_size, void* d_ws, size_t ws_size,
                              hipStream_t stream){
  const int* ei = (const int*)d_in[1];

  long long sz[64];
  {
    const long long* s64 = (const long long*)(const void*)in_sizes;
    bool is64 = (n_in >= 2) && (in_sizes[0] == 3340000) && (in_sizes[1] == 0)
                && (s64[1] == 200000);
    for (int i=0;i<n_in && i<64;i++) sz[i] = is64 ? s64[i] : (long long)in_sizes[i];
  }

  int IWg[3], IWe[3], IAttn[3], IAt[3], ICb[3], ILw[3], ILb[3], IG[3], IB[3];
  if (n_in > 8 && sz[8] == (long long)HID*HID){ // setup_inputs() dict order
    for (int l=0;l<3;l++){
      IWg[l]=3+l*5; IWe[l]=4+l*5; IAttn[l]=5+l*5; IAt[l]=6+l*5; ICb[l]=7+l*5;
      ILw[l]=18+l*4; ILb[l]=19+l*4; IG[l]=20+l*4; IB[l]=21+l*4;
    }
  } else {
    int idx=3;
    for (int l=0;l<3;l++){
      IWg[l]=idx++; IWe[l]=idx++; IAttn[l]=idx++; IAt[l]=idx++; ICb[l]=idx++;
      ILw[l]=idx++; ILb[l]=idx++; IG[l]=idx++; IB[l]=idx++;
    }
  }
  #define FP(i) ((const float*)d_in[(i)])

  char* ws = (char*)d_ws;
  size_t off = 0;
  auto alloc = [&](size_t bytes)->void*{ void* p = ws + off; off += (bytes + 255) & ~(size_t)255; return p; };
  auto G = [](long n){ return (int)((n+255)/256); };

  u16*   buf0 = (u16*)  alloc((size_t)NN*HID*2);   // hg (bf16)
  u16*   bufA = (u16*)  alloc((size_t)NN*HID*2);   // layer-1 lin/result
  u16*   bufB = (u16*)  alloc((size_t)NN*HID*2);   // layer-2 lin/result
  u16*   xbf  = (u16*)  alloc((size_t)NN*KP1*2);   // layer-1 A (bf16, padded)
  u16*   Wt   = (u16*)  alloc((size_t)2*HID*HID*2);// fused folded weights [2048][K] K-major
  u16*   We16 = (u16*)  alloc((size_t)10*HID*2);
  float* cst  = (float*)alloc(2*HID*4);
  float* L    = (float*)alloc((size_t)EE*4*4);
  float* ssrc = (float*)alloc((size_t)NN*4*4);
  float* sdst = (float*)alloc((size_t)NN*4*4);
  int*   iptr = (int*)  alloc((size_t)(NN+4)*4);
  int*   cnts = (int*)  alloc((size_t)NN*4);
  int*   eid  = (int*)  alloc((size_t)EE*4);
  int*   bsum = (int*)  alloc(256*4);
  int*   boff = (int*)  alloc(256*4);
  float* stats= (float*)alloc(2*HID*4);
  float* scale= (float*)alloc(HID*4);
  float* shift= (float*)alloc(HID*4);
  float* qbuf = (float*)alloc(64*4);
  float* hg3  = (float*)alloc((size_t)NN*2*4);
  float* lin3 = (float*)alloc((size_t)NN*2*4);
  float* cw   = (float*)alloc((size_t)NN*40*4);    // factored edge-feature weights
  float* W4   = (float*)alloc((size_t)HID*4*4);    // layer-3 folded interleaved weights
  float* c4   = (float*)alloc(4*4);
  float* part = (float*)alloc((size_t)256*2048*4); // bnstats8 partials (2 MB)

  // ---- CSR by dst (two-level scan) ----
  int nsb = G(NN);   // 79 scan blocks
  hipMemsetAsync(cnts, 0, NN*sizeof(int), stream);
  k_count<<<G(EE),256,0,stream>>>(ei, cnts);
  k_scanA<<<nsb,256,0,stream>>>(cnts, iptr, bsum);
  k_scanB<<<1,128,0,stream>>>(bsum, boff, iptr+NN, nsb);
  k_scanC<<<nsb,256,0,stream>>>(boff, iptr);
  hipMemsetAsync(cnts, 0, NN*sizeof(int), stream);
  k_fill<<<G(EE),256,0,stream>>>(ei, iptr, cnts, eid);

  int gg = 1264;   // 79 row-tiles (256 rows) x 16 col-tiles (128 cols), XCD-swizzled in-kernel
  int gsd = (NN*4+3)/4;   // k_sdot: one wave per (n,h)

  // ---- layer 1 (A = bf16(x), Kp=256) ----
  {
    hipMemsetAsync(stats, 0, 2*FIN*sizeof(float), stream);
    dim3 bg(200, 1);
    k_bnstats<float><<<bg,256,0,stream>>>(FP(0), stats, FIN);
    k_bnfin<<<1,256,0,stream>>>(stats, FP(IG[0]), FP(IB[0]), scale, shift, FIN);
    k_cast<<<G((long)NN*KP1),256,0,stream>>>(FP(0), xbf);
    dim3 ft(KP1/32, 64);
    k_foldT<<<ft,256,0,stream>>>(FP(IWg[0]), FP(ILw[0]), scale, Wt, FIN, KP1);
    k_cinit<<<8,256,0,stream>>>(FP(ILb[0]), cst);
    dim3 cg(32, (FIN+127)/128);
    k_const<<<cg,256,0,stream>>>(FP(IWg[0]), FP(ILw[0]), shift, cst, FIN);
    k_we16<<<40,256,0,stream>>>(FP(IWe[0]), We16);
    k_gemm<<<gg,512,0,stream>>>(xbf, KP1, Wt, cst, buf0, bufA);
    k_sdot<<<gsd,256,0,stream>>>(buf0, FP(IAttn[0]), ssrc, sdst);
    k_q<<<1,64,0,stream>>>(FP(IWe[0]), FP(IAttn[0]), qbuf);
    k_logits<<<G(EE),256,0,stream>>>(ei, FP(2), qbuf, FP(IAt[0]), ssrc, sdst, L);
    k_mden<<<G(NN),256,0,stream>>>(iptr, eid, FP(2), L, cw);
    k_gath<<<(NN+NB-1)/NB,256,0,stream>>>(buf0, ei, iptr, eid, L, cw,
                                          We16, FP(ICb[0]), bufA);
  }
  // ---- layer 2 (A = bufA, K=1024) ----
  {
    k_bnstats8<<<256,256,0,stream>>>(bufA, part);
    k_pred<<<8,256,0,stream>>>(part, stats);
    k_bnfin<<<4,256,0,stream>>>(stats, FP(IG[1]), FP(IB[1]), scale, shift, HID);
    dim3 ft(HID/32, 64);
    k_foldT<<<ft,256,0,stream>>>(FP(IWg[1]), FP(ILw[1]), scale, Wt, HID, HID);
    k_cinit<<<8,256,0,stream>>>(FP(ILb[1]), cst);
    dim3 cg(32, HID/128);
    k_const<<<cg,256,0,stream>>>(FP(IWg[1]), FP(ILw[1]), shift, cst, HID);
    k_we16<<<40,256,0,stream>>>(FP(IWe[1]), We16);
    k_gemm<<<gg,512,0,stream>>>(bufA, HID, Wt, cst, buf0, bufB);
    k_sdot<<<gsd,256,0,stream>>>(buf0, FP(IAttn[1]), ssrc, sdst);
    k_q<<<1,64,0,stream>>>(FP(IWe[1]), FP(IAttn[1]), qbuf);
    k_logits<<<G(EE),256,0,stream>>>(ei, FP(2), qbuf, FP(IAt[1]), ssrc, sdst, L);
    k_mden<<<G(NN),256,0,stream>>>(iptr, eid, FP(2), L, cw);
    k_gath<<<(NN+NB-1)/NB,256,0,stream>>>(buf0, ei, iptr, eid, L, cw,
                                          We16, FP(ICb[1]), bufB);
  }

  // ---- layer 3 (input = bufB) ----
  k_bnstats8<<<256,256,0,stream>>>(bufB, part);
  k_pred<<<8,256,0,stream>>>(part, stats);
  k_bnfin<<<4,256,0,stream>>>(stats, FP(IG[2]), FP(IB[2]), scale, shift, HID);
  k_c4init<<<1,64,0,stream>>>(FP(ILb[2]), c4);
  k_fold3<<<HID/256,256,0,stream>>>(FP(IWg[2]), FP(ILw[2]), scale, shift, W4, c4);
  k_n3<<<NN/4,256,0,stream>>>(bufB, W4, c4, FP(IAttn[2]), hg3, lin3, ssrc, sdst);
  k_logits3<<<G(EE),256,0,stream>>>(ei, FP(2), FP(IWe[2]), FP(IAttn[2]), FP(IAt[2]), ssrc, sdst, L);
  k_mden3<<<G(NN),256,0,stream>>>(iptr, eid, FP(2), L, cw);
  k_gather3<<<G(NN),256,0,stream>>>(ei, iptr, eid, L, cw, hg3,
                                    FP(IWe[2]), lin3, FP(ICb[2]), (float*)d_out);
}

// Round 11
// 763.026 us; speedup vs baseline: 1.6390x; 1.0031x over previous
//
#include <hip/hip_runtime.h>
#include <math.h>

#define NN 20000
#define EE 100000
#define FIN 167
#define KP1 256    // layer-1 K padded to mult of 64
#define HID 1024   // H*O = 4*256
#define OO 256
#define NB 8       // nodes per k_gath block

typedef unsigned short u16;
typedef short bf16x8 __attribute__((ext_vector_type(8)));
typedef short s16x4  __attribute__((ext_vector_type(4)));
typedef float f32x4  __attribute__((ext_vector_type(4)));

__device__ __forceinline__ float bf(u16 u){ return __uint_as_float(((unsigned)u)<<16); }
__device__ __forceinline__ u16 fb(float v){            // f32 -> bf16 RNE
  unsigned u = __float_as_uint(v);
  return (u16)((u + 0x7FFFu + ((u>>16)&1u)) >> 16);
}
__device__ __forceinline__ float ldv(const float* p, long i){ return p[i]; }
__device__ __forceinline__ float ldv(const u16*   p, long i){ return bf(p[i]); }

// ---------------- CSR build ----------------
__global__ void k_count(const int* __restrict__ ei, int* __restrict__ counts){
  int e = blockIdx.x*256 + threadIdx.x;
  if (e < EE) atomicAdd(&counts[ei[EE+e]], 1);
}

// two-level scan
__global__ __launch_bounds__(256) void k_scanA(const int* __restrict__ counts,
                                               int* __restrict__ iptr, int* __restrict__ bsum){
  __shared__ int sd[256];
  int b = blockIdx.x, tid = threadIdx.x;
  int i = b*256 + tid;
  int v = (i<NN)? counts[i] : 0;
  sd[tid]=v; __syncthreads();
  for (int off=1; off<256; off<<=1){
    int t = (tid>=off)? sd[tid-off] : 0;
    __syncthreads();
    sd[tid] += t;
    __syncthreads();
  }
  if (i<NN) iptr[i] = sd[tid]-v;     // block-local exclusive
  if (tid==255) bsum[b]=sd[255];
}
__global__ __launch_bounds__(128) void k_scanB(const int* __restrict__ bsum,
                                               int* __restrict__ boff, int* __restrict__ iptrN,
                                               int nb){
  __shared__ int sd[128];
  int tid=threadIdx.x;
  int v=(tid<nb)? bsum[tid]:0;
  sd[tid]=v; __syncthreads();
  for (int off=1; off<128; off<<=1){
    int t=(tid>=off)?sd[tid-off]:0;
    __syncthreads();
    sd[tid]+=t;
    __syncthreads();
  }
  if (tid<nb) boff[tid]=sd[tid]-v;
  if (tid==127) *iptrN = sd[127];
}
__global__ void k_scanC(const int* __restrict__ boff, int* __restrict__ iptr){
  int i = blockIdx.x*256+threadIdx.x;
  if (i<NN) iptr[i] += boff[blockIdx.x];
}

__global__ void k_fill(const int* __restrict__ ei, const int* __restrict__ iptr,
                       int* __restrict__ cursor, int* __restrict__ eid){
  int e = blockIdx.x*256 + threadIdx.x;
  if (e < EE){
    int d = ei[EE+e];
    int pos = atomicAdd(&cursor[d],1);
    eid[iptr[d]+pos] = e;
  }
}

// ---------------- BatchNorm stats ----------------
// layer-1 (float input, F=167): original coalesced version (never hot; 67K atomics OK)
template<typename T>
__global__ void k_bnstats(const T* __restrict__ X, float* __restrict__ sums, int F){
  int f = blockIdx.y*256 + threadIdx.x;
  if (f >= F) return;
  int r0 = blockIdx.x*100, r1 = r0+100;
  float s=0.f, s2=0.f;
  for (int r=r0;r<r1;r++){ float v = ldv(X,(long)r*F+f); s += v; s2 += v*v; }
  atomicAdd(&sums[f], s);
  atomicAdd(&sums[F+f], s2);
}

// layers 2/3 (bf16, F=HID) stage A: zero-atomic partials (round-7 lesson: atomics storm)
__global__ __launch_bounds__(256) void k_bnstats8(const u16* __restrict__ X, float* __restrict__ part){
  int tid = threadIdx.x;
  int f8 = (tid & 127)*8;
  int r0 = blockIdx.x*79, r1 = min(NN, r0+79);     // grid 256
  float s[8]={0,0,0,0,0,0,0,0}, s2[8]={0,0,0,0,0,0,0,0};
  for (int r=r0 + (tid>>7); r<r1; r+=2){
    bf16x8 v = *(const bf16x8*)(X + (long)r*HID + f8);
    #pragma unroll
    for (int j=0;j<8;j++){ float x=bf((u16)v[j]); s[j]+=x; s2[j]+=x*x; }
  }
  __shared__ float red[256][8];
  float* pb = part + (long)blockIdx.x*2048;
  #pragma unroll
  for (int j=0;j<8;j++) red[tid][j]=s[j];
  __syncthreads();
  if (tid<128){
    #pragma unroll
    for (int j=0;j<8;j++) pb[f8+j] = red[tid][j]+red[tid+128][j];
  }
  __syncthreads();
  #pragma unroll
  for (int j=0;j<8;j++) red[tid][j]=s2[j];
  __syncthreads();
  if (tid<128){
    #pragma unroll
    for (int j=0;j<8;j++) pb[1024+f8+j] = red[tid][j]+red[tid+128][j];
  }
}

// stage B: reduce 256 partials -> sums[2048]; consecutive threads = consecutive addrs
__global__ __launch_bounds__(256) void k_pred(const float* __restrict__ part, float* __restrict__ sums){
  int idx = blockIdx.x*256 + threadIdx.x;   // grid 8 -> 2048 threads
  float s = 0.f;
  #pragma unroll 8
  for (int b=0;b<256;b++) s += part[(long)b*2048 + idx];
  sums[idx] = s;
}

__global__ void k_bnfin(const float* __restrict__ sums, const float* __restrict__ g,
                        const float* __restrict__ b, float* __restrict__ scale,
                        float* __restrict__ shift, int F){
  int f = blockIdx.x*256 + threadIdx.x;
  if (f >= F) return;
  float mu  = sums[f]   * (1.f/NN);
  float var = sums[F+f] * (1.f/NN) - mu*mu;
  float sc  = rsqrtf(var + 1e-5f) * g[f];
  scale[f] = sc;
  shift[f] = b[f] - mu*sc;
}

// ---------------- BN-folded fused weight prep ----------------
__global__ __launch_bounds__(256) void k_foldT(const float* __restrict__ Wg, const float* __restrict__ Wl,
                        const float* __restrict__ scale,
                        u16* __restrict__ Wt, int K, int Kp){
  __shared__ float t[32][33];
  int k0 = blockIdx.x*32, c0 = blockIdx.y*32;
  int tx = threadIdx.x & 31, ty = threadIdx.x >> 5;
  bool second = (c0 >= HID);
  const float* W = second ? Wl : Wg;
  int cc0 = second ? c0 - HID : c0;
  #pragma unroll
  for (int i=0;i<4;i++){
    int k = k0 + ty + i*8;
    t[ty+i*8][tx] = (k < K) ? W[(long)k*HID + cc0 + tx] * scale[k] : 0.f;
  }
  __syncthreads();
  #pragma unroll
  for (int i=0;i<4;i++){
    int c = c0 + ty + i*8;
    Wt[(long)c*Kp + k0 + tx] = fb(t[tx][ty+i*8]);
  }
}

// cst init: lb for lin half, 0 for hg half
__global__ void k_cinit(const float* __restrict__ lb, float* __restrict__ cst){
  int c = blockIdx.x*256 + threadIdx.x;
  if (c < 2*HID) cst[c] = (c >= HID) ? lb[c-HID] : 0.f;
}

// cst[c] += sum_k shift[k]*W[k][c]  — parallel reduction, coalesced
__global__ __launch_bounds__(256) void k_const(const float* __restrict__ Wg, const float* __restrict__ Wl,
                        const float* __restrict__ shift, float* __restrict__ cst, int K){
  int tx = threadIdx.x & 63, ty = threadIdx.x >> 6;
  int c = blockIdx.x*64 + tx;
  bool second = c >= HID;
  const float* W = second ? Wl : Wg;
  int cc = second ? c-HID : c;
  int k0 = blockIdx.y*128;
  int k1 = min(K, k0+128);
  float s = 0.f;
  for (int k=k0+ty; k<k1; k+=4) s += shift[k]*W[(long)k*HID+cc];
  __shared__ float red[256];
  red[threadIdx.x] = s;
  __syncthreads();
  if (ty == 0){
    float tot = red[tx] + red[tx+64] + red[tx+128] + red[tx+192];
    atomicAdd(&cst[c], tot);
  }
}

__global__ void k_cast(const float* __restrict__ x, u16* __restrict__ xb){
  long idx = (long)blockIdx.x*256 + threadIdx.x;
  if (idx >= (long)NN*KP1) return;
  int n = (int)(idx / KP1), k = (int)(idx % KP1);
  xb[idx] = (k<FIN)? fb(x[(long)n*FIN+k]) : (u16)0;
}

__global__ void k_we16(const float* __restrict__ We, u16* __restrict__ We16){
  int i = blockIdx.x*256 + threadIdx.x;
  if (i < 10*HID) We16[i] = fb(We[i]);
}

// ---------------- MFMA GEMM v6: v5 + conflict-free XOR ----------------
// v5 (256x128, BK=32, 3-buffer 2-tile-deep counted-vmcnt, 2 blocks/CU) measured
// 110us / 32% MfmaUtil with 1.035e7 bank conflicts (+4 cyc per ds_read_b128 = +33%
// LDS time, now co-critical with MFMA).  Root cause: chunk ^= (row&3) leaves lanes
// lo,lo+1 on colliding (parity x chunk) bank slots -> 4-way.  Fix: chunk ^= ((row>>1)&3):
// for fixed quad, lo=2m+b gives chunk_pos=quad^(m&3) -> each (parity,chunk) slot gets
// exactly 2 lanes = 2-way = free (m136).  Same involution on store (source addr) and
// read (ds addr) sides; panel-row bases are mult of 16 so (row>>1)&3 == (lo>>1)&3.
#define MF(a_,b_,c_) __builtin_amdgcn_mfma_f32_16x16x32_bf16(a_,b_,c_,0,0,0)
#define FENCE asm volatile("" ::: "memory")
#define BAR do { FENCE; __builtin_amdgcn_s_barrier(); FENCE; } while(0)

__global__ __launch_bounds__(512,2) void k_gemm(const u16* __restrict__ A, int K,
                     const u16* __restrict__ Wt, const float* __restrict__ cst,
                     u16* __restrict__ Chg, u16* __restrict__ Clin){
  __shared__ u16 lds[3][12288];   // 3 x (A 8192 u16 | B 4096 u16) = 72 KB
  int b = blockIdx.x;
  int wg = (b & 7)*158 + (b >> 3);          // 1264 % 8 == 0 -> bijective XCD swizzle
  int row0 = (wg >> 4)*256, col0 = (wg & 15)*128;
  int tid = threadIdx.x;
  int wave = tid >> 6, lane = tid & 63, quad = lane >> 4, lo = lane & 15;
  int wm = wave >> 1, wn = wave & 1;        // 4 M-waves x 2 N-waves, 64x64 out each
  const u16* Apt[2];
  #pragma unroll
  for (int i=0;i<2;i++){
    int s = i*512 + tid, srow = s>>2;
    int gr = row0 + srow; if (gr >= NN) gr = NN-1;      // clamp: garbage rows never stored
    Apt[i] = A + (long)gr*K + (((s&3)^((srow>>1)&3))*8);
  }
  int brow = tid>>2;
  const u16* Bpt = Wt + (long)(col0 + brow)*K + ((((tid&3)^((brow>>1)&3)))*8);
  const char* ldsc = (const char*)&lds[0][0];
  int axor = (lo>>1) & 3;
  int aoff = (wm*64 + lo)*64 + ((quad^axor)*16);            // A frag i at +i*1024 B
  int boff = 16384 + (wn*64 + lo)*64 + ((quad^axor)*16);    // B frag n at +n*1024 B
  int NT = K >> 5;
  f32x4 acc[4][4] = {};
  // ---- prologue: stage tiles 0,1 into buffers 0,1 ----
  {
    u16* d0 = (u16*)&lds[0][0];
    u16* d1 = (u16*)&lds[1][0];
    __builtin_amdgcn_global_load_lds(Apt[0],      d0 +         tid*8, 16, 0, 0);
    __builtin_amdgcn_global_load_lds(Apt[1],      d0 + 4096 +  tid*8, 16, 0, 0);
    __builtin_amdgcn_global_load_lds(Bpt,         d0 + 8192 +  tid*8, 16, 0, 0);
    __builtin_amdgcn_global_load_lds(Apt[0] + 32, d1 +         tid*8, 16, 0, 0);
    __builtin_amdgcn_global_load_lds(Apt[1] + 32, d1 + 4096 +  tid*8, 16, 0, 0);
    __builtin_amdgcn_global_load_lds(Bpt    + 32, d1 + 8192 +  tid*8, 16, 0, 0);
    asm volatile("s_waitcnt vmcnt(3)" ::: "memory");   // tile-0 panels landed
    BAR;
  }
  int cb = 0;
  for (int t=0; t<NT; t++){
    const char* Lb = ldsc + cb*24576;
    bf16x8 af[4], bfr[4];
    #pragma unroll
    for (int i=0;i<4;i++) af[i]  = *(const bf16x8*)(Lb + aoff + i*1024);
    #pragma unroll
    for (int n=0;n<4;n++) bfr[n] = *(const bf16x8*)(Lb + boff + n*1024);
    int nx2 = (t+2 < NT);
    if (nx2){
      int sb = cb+2; if (sb>=3) sb-=3;       // buffer holding tile t-1 (consumed, barrier-safe)
      u16* Sd = (u16*)&lds[0][0] + sb*12288;
      int ko = (t+2) << 5;
      __builtin_amdgcn_global_load_lds(Apt[0] + ko, Sd +         tid*8, 16, 0, 0);
      __builtin_amdgcn_global_load_lds(Apt[1] + ko, Sd + 4096 +  tid*8, 16, 0, 0);
      __builtin_amdgcn_global_load_lds(Bpt    + ko, Sd + 8192 +  tid*8, 16, 0, 0);
    }
    #pragma unroll
    for (int i=0;i<4;i++)
      #pragma unroll
      for (int n=0;n<4;n++)
        acc[i][n] = MF(af[i], bfr[n], acc[i][n]);
    if (t+1 < NT){
      if (nx2) asm volatile("s_waitcnt vmcnt(3)" ::: "memory");  // tile t+1 landed
      else     asm volatile("s_waitcnt vmcnt(0)" ::: "memory");  // tail (once)
      BAR;
    }
    cb++; if (cb>=3) cb=0;
  }
  // ---- epilogue (verified mapping, unchanged) ----
  #pragma unroll
  for (int i=0;i<4;i++){
    #pragma unroll
    for (int n=0;n<4;n++){
      int col = col0 + wn*64 + n*16 + lo;
      float cs = cst[col];
      #pragma unroll
      for (int r=0;r<4;r++){
        int row = row0 + wm*64 + i*16 + quad*4 + r;   // C/D: col=lane&15, row=quad*4+reg
        if (row < NN){
          u16 o = fb(acc[i][n][r] + cs);
          if (col < HID) Chg[(long)row*HID + col] = o;
          else           Clin[(long)row*HID + col - HID] = o;
        }
      }
    }
  }
}
#undef MF
#undef BAR
#undef FENCE

// ---------------- per-(node,head) attention dots: wave-parallel, coalesced ----------------
__global__ __launch_bounds__(256) void k_sdot(const u16* __restrict__ hg, const float* __restrict__ attn,
                       float* __restrict__ ssrc, float* __restrict__ sdst){
  int unit = blockIdx.x*4 + (threadIdx.x >> 6);   // one wave per (n,h)
  if (unit >= NN*4) return;
  int lane = threadIdx.x & 63;
  int n = unit >> 2, h = unit & 3;
  const u16* hp = hg + (long)n*HID + h*OO + lane*4;
  s16x4 v = *(const s16x4*)hp;
  float4 x0 = *(const float4*)(attn + h*OO + lane*4);
  float4 x1 = *(const float4*)(attn + HID + h*OO + lane*4);
  float f0 = bf((u16)v.x), f1 = bf((u16)v.y), f2 = bf((u16)v.z), f3 = bf((u16)v.w);
  float ss = f0*x0.x + f1*x0.y + f2*x0.z + f3*x0.w;
  float sd = f0*x1.x + f1*x1.y + f2*x1.z + f3*x1.w;
  #pragma unroll
  for (int off=32; off>0; off>>=1){
    ss += __shfl_down(ss, off);
    sd += __shfl_down(sd, off);
  }
  if (lane==0){ ssrc[unit]=ss; sdst[unit]=sd; }
}

__global__ void k_q(const float* __restrict__ We, const float* __restrict__ attn,
                    float* __restrict__ q){
  int t = threadIdx.x;
  if (t >= 40) return;
  int k = t >> 2, h = t & 3;
  float s = 0.f;
  for (int d=0; d<OO; d++) s += We[(long)k*HID + h*OO + d] * attn[2*HID + h*OO + d];
  q[k*4+h] = s;
}

// per-EDGE logits: ea read once, all 4 heads computed, float4 write
__global__ void k_logits(const int* __restrict__ ei, const float* __restrict__ ea,
                         const float* __restrict__ q, const float* __restrict__ at,
                         const float* __restrict__ ssrc, const float* __restrict__ sdst,
                         float* __restrict__ L){
  int e = blockIdx.x*256 + threadIdx.x;
  if (e >= EE) return;
  int s = ei[e], dd = ei[EE+e];
  float4 a0 = *(const float4*)(ea + (long)e*12);
  float4 a1 = *(const float4*)(ea + (long)e*12 + 4);
  float4 a2 = *(const float4*)(ea + (long)e*12 + 8);
  float t = a0.x;
  float cc[10] = {a0.y,a0.z,a0.w, a1.x,a1.y,a1.z,a1.w, a2.x,a2.y,a2.z};
  float4 ss = *(const float4*)(ssrc + (long)s*4);
  float4 sd = *(const float4*)(sdst + (long)dd*4);
  float sv[4] = {ss.x+sd.x, ss.y+sd.y, ss.z+sd.z, ss.w+sd.w};
  float4 out;
  #pragma unroll
  for (int h=0;h<4;h++){
    float se = 0.f;
    #pragma unroll
    for (int k=0;k<10;k++) se += cc[k]*q[k*4+h];
    float v = sv[h] + se + t*at[h];
    ((float*)&out)[h] = (v>0.f)? v : 0.2f*v;
  }
  *(float4*)(L + (long)e*4) = out;
}

// per-NODE softmax finalize: writes w = exp(L-m)*dinv IN PLACE into L (float4),
// accumulates cw[n][4][10] with ea read ONCE per edge
__global__ void k_mden(const int* __restrict__ iptr, const int* __restrict__ eid,
                       const float* __restrict__ ea, float* __restrict__ L,
                       float* __restrict__ cw){
  int n = blockIdx.x*256 + threadIdx.x;
  if (n >= NN) return;
  int b = iptr[n], e1 = iptr[n+1];
  float m0=-INFINITY, m1=-INFINITY, m2=-INFINITY, m3=-INFINITY;
  for (int i=b;i<e1;i++){
    float4 l = *(const float4*)(L + (long)eid[i]*4);
    m0=fmaxf(m0,l.x); m1=fmaxf(m1,l.y); m2=fmaxf(m2,l.z); m3=fmaxf(m3,l.w);
  }
  if (b==e1){ m0=m1=m2=m3=0.f; }
  float s0=0.f,s1=0.f,s2=0.f,s3=0.f;
  for (int i=b;i<e1;i++){
    float4 l = *(const float4*)(L + (long)eid[i]*4);
    s0+=expf(l.x-m0); s1+=expf(l.y-m1); s2+=expf(l.z-m2); s3+=expf(l.w-m3);
  }
  float d0=1.f/(s0+1e-16f), d1=1.f/(s1+1e-16f), d2=1.f/(s2+1e-16f), d3=1.f/(s3+1e-16f);
  float c[4][10] = {};
  for (int i=b;i<e1;i++){
    int e = eid[i];
    float4 l = *(const float4*)(L + (long)e*4);
    float4 w = { expf(l.x-m0)*d0, expf(l.y-m1)*d1, expf(l.z-m2)*d2, expf(l.w-m3)*d3 };
    *(float4*)(L + (long)e*4) = w;
    float4 a0 = *(const float4*)(ea + (long)e*12);
    float4 a1 = *(const float4*)(ea + (long)e*12 + 4);
    float4 a2 = *(const float4*)(ea + (long)e*12 + 8);
    float cc[10] = {a0.y,a0.z,a0.w, a1.x,a1.y,a1.z,a1.w, a2.x,a2.y,a2.z};
    #pragma unroll
    for (int k=0;k<10;k++){
      c[0][k] += w.x*cc[k]; c[1][k] += w.y*cc[k];
      c[2][k] += w.z*cc[k]; c[3][k] += w.w*cc[k];
    }
  }
  float* cp = cw + (long)n*40;
  #pragma unroll
  for (int h=0;h<4;h++)
    #pragma unroll
    for (int k=0;k<10;k++) cp[h*10+k] = c[h][k];
}

// ---------------- edge gather: 8B/lane + 2-deep software prefetch ----------------
__global__ __launch_bounds__(256) void k_gath(
    const u16* __restrict__ hg, const int* __restrict__ ei,
    const int* __restrict__ iptr, const int* __restrict__ eid,
    const float* __restrict__ L,      // holds w[e][h] (from k_mden)
    const float* __restrict__ cw,     // [NN][4][10]
    const u16* __restrict__ We16, const float* __restrict__ cb,
    u16* __restrict__ lio)
{
  __shared__ u16  sWe[10*HID];   // 20 KB
  __shared__ float scb[HID];     // 4 KB
  int tid = threadIdx.x;
  for (int i=tid;i<10*HID;i+=256) sWe[i] = We16[i];
  for (int i=tid;i<HID;i+=256) scb[i] = cb[i];
  __syncthreads();
  int h = tid >> 6;
  int f0 = tid*4;
  int d0 = blockIdx.x*NB, dend = min(NN, d0+NB);
  for (int d=d0; d<dend; d++){
    s16x4 a0 = *(const s16x4*)(lio + (long)d*HID + f0);
    float acc0=bf((u16)a0.x), acc1=bf((u16)a0.y), acc2=bf((u16)a0.z), acc3=bf((u16)a0.w);
    int b0 = iptr[d], en = iptr[d+1];
    float wN = 0.f; s16x4 vN = {};
    if (b0 < en){
      int e = eid[b0], s_ = ei[e];
      wN = L[(long)e*4 + h];
      vN = *(const s16x4*)(hg + (long)s_*HID + f0);
    }
    for (int i=b0;i<en;i++){
      float w = wN; s16x4 v = vN;
      if (i+1 < en){
        int e2 = eid[i+1], s2 = ei[e2];
        wN = L[(long)e2*4 + h];
        vN = *(const s16x4*)(hg + (long)s2*HID + f0);
      }
      acc0 += w*bf((u16)v.x); acc1 += w*bf((u16)v.y);
      acc2 += w*bf((u16)v.z); acc3 += w*bf((u16)v.w);
    }
    const float* cp = cw + (long)d*40 + h*10;
    float ew0=0.f, ew1=0.f, ew2=0.f, ew3=0.f;
    #pragma unroll
    for (int k=0;k<10;k++){
      float c = cp[k];
      s16x4 wv = *(const s16x4*)(sWe + k*HID + f0);
      ew0 += c*bf((u16)wv.x); ew1 += c*bf((u16)wv.y);
      ew2 += c*bf((u16)wv.z); ew3 += c*bf((u16)wv.w);
    }
    acc0 += ew0; acc1 += ew1; acc2 += ew2; acc3 += ew3;
    u16 o[4];
    o[0] = fb(fmaxf(acc0 + scb[f0  ], 0.f));
    o[1] = fb(fmaxf(acc1 + scb[f0+1], 0.f));
    o[2] = fb(fmaxf(acc2 + scb[f0+2], 0.f));
    o[3] = fb(fmaxf(acc3 + scb[f0+3], 0.f));
    *(s16x4*)(lio + (long)d*HID + f0) = *(const s16x4*)o;
  }
}

// ---------------- layer 3 ----------------
__global__ void k_c4init(const float* __restrict__ lb, float* __restrict__ c4){
  if (threadIdx.x==0 && blockIdx.x==0){ c4[0]=0.f; c4[1]=0.f; c4[2]=lb[0]; c4[3]=lb[1]; }
}

// fold BN scale into interleaved weights W4[k][4] = {Wg0,Wg1,lw0,lw1}*sc; shift -> c4
__global__ __launch_bounds__(256) void k_fold3(const float* __restrict__ Wg, const float* __restrict__ lw,
                        const float* __restrict__ scale, const float* __restrict__ shift,
                        float* __restrict__ W4, float* __restrict__ c4){
  int k = blockIdx.x*256 + threadIdx.x;   // grid 4, covers HID exactly
  float sc = scale[k], sh = shift[k];
  float w0=Wg[k*2], w1=Wg[k*2+1], l0=lw[k*2], l1=lw[k*2+1];
  float4 o = {w0*sc, w1*sc, l0*sc, l1*sc};
  *(float4*)(W4 + (long)k*4) = o;
  __shared__ float red[256][4];
  int tid = threadIdx.x;
  red[tid][0]=sh*w0; red[tid][1]=sh*w1; red[tid][2]=sh*l0; red[tid][3]=sh*l1;
  __syncthreads();
  for (int o2=128;o2>0;o2>>=1){
    if (tid<o2){
      #pragma unroll
      for (int j=0;j<4;j++) red[tid][j]+=red[tid+o2][j];
    }
    __syncthreads();
  }
  if (tid==0){
    #pragma unroll
    for (int j=0;j<4;j++) atomicAdd(&c4[j], red[0][j]);
  }
}

// wave-per-node GEMV: x-rows and W4 staged in LDS, shuffle reduce, no post-stage barriers
__global__ __launch_bounds__(256) void k_n3(const u16* __restrict__ in,
    const float* __restrict__ W4, const float* __restrict__ c4,
    const float* __restrict__ attn,
    float* __restrict__ hg3, float* __restrict__ lin3,
    float* __restrict__ ssrc, float* __restrict__ sdst)
{
  __shared__ float sW[HID*4];   // 16 KB
  __shared__ float sx[4][HID];  // 16 KB
  int tid = threadIdx.x;
  int n0 = blockIdx.x*4;        // grid 5000 exact
  for (int i=tid; i<HID; i+=256) *(float4*)&sW[i*4] = *(const float4*)(W4 + (long)i*4);
  for (int idx=tid; idx<512; idx+=256){
    int rr = idx>>7, ch = idx&127;
    bf16x8 v = *(const bf16x8*)(in + (long)(n0+rr)*HID + ch*8);
    #pragma unroll
    for (int j=0;j<8;j++) sx[rr][ch*8+j] = bf((u16)v[j]);
  }
  __syncthreads();
  int w = tid>>6, lane = tid&63;
  float p0=0.f,p1=0.f,p2=0.f,p3=0.f;
  #pragma unroll
  for (int g=0; g<16; g++){
    int k = g*64 + lane;                      // lanes consecutive -> conflict-free
    float x = sx[w][k];
    float4 wv = *(const float4*)&sW[k*4];
    p0 += x*wv.x; p1 += x*wv.y; p2 += x*wv.z; p3 += x*wv.w;
  }
  #pragma unroll
  for (int off=32; off>0; off>>=1){
    p0 += __shfl_down(p0, off);
    p1 += __shfl_down(p1, off);
    p2 += __shfl_down(p2, off);
    p3 += __shfl_down(p3, off);
  }
  if (lane==0){
    int n = n0 + w;
    float r0=p0+c4[0], r1=p1+c4[1], r2=p2+c4[2], r3=p3+c4[3];
    hg3[n*2]=r0; hg3[n*2+1]=r1;
    lin3[n*2]=r2; lin3[n*2+1]=r3;
    ssrc[n]=r0*attn[0]+r1*attn[1];
    sdst[n]=r0*attn[2]+r1*attn[3];
  }
}

__global__ void k_logits3(const int* __restrict__ ei, const float* __restrict__ ea,
                          const float* __restrict__ We, const float* __restrict__ attn,
                          const float* __restrict__ at, const float* __restrict__ ssrc,
                          const float* __restrict__ sdst, float* __restrict__ L){
  int e = blockIdx.x*256 + threadIdx.x;
  if (e >= EE) return;
  int s = ei[e], d = ei[EE+e];
  float e0=0.f, e1=0.f;
  #pragma unroll
  for (int k=0;k<10;k++){
    float c = ea[e*12+1+k];
    e0 += c*We[k*2]; e1 += c*We[k*2+1];
  }
  float se = e0*attn[4] + e1*attn[5];
  float v = ssrc[s] + sdst[d] + se + ea[e*12]*at[0];
  L[e] = (v>0.f)? v : 0.2f*v;
}

// layer-3 softmax finalize: w in place + cw3[n][k]
__global__ void k_mden3(const int* __restrict__ iptr, const int* __restrict__ eid,
                        const float* __restrict__ ea, float* __restrict__ L,
                        float* __restrict__ cw){
  int n = blockIdx.x*256 + threadIdx.x;
  if (n >= NN) return;
  int b = iptr[n], e1 = iptr[n+1];
  float mx = -INFINITY;
  for (int i=b;i<e1;i++) mx = fmaxf(mx, L[eid[i]]);
  if (b == e1) mx = 0.f;
  float s = 0.f;
  for (int i=b;i<e1;i++) s += expf(L[eid[i]] - mx);
  float dv = 1.f/(s+1e-16f);
  float c[10] = {0.f,0.f,0.f,0.f,0.f,0.f,0.f,0.f,0.f,0.f};
  for (int i=b;i<e1;i++){
    int e = eid[i];
    float w = expf(L[e]-mx)*dv;
    L[e] = w;
    #pragma unroll
    for (int k=0;k<10;k++) c[k] += w*ea[e*12+1+k];
  }
  float* cp = cw + (long)n*10;
  #pragma unroll
  for (int k=0;k<10;k++) cp[k] = c[k];
}

__global__ void k_gather3(const int* __restrict__ ei,
                          const int* __restrict__ iptr, const int* __restrict__ eid,
                          const float* __restrict__ L,      // holds w[e]
                          const float* __restrict__ cw,     // [NN][10]
                          const float* __restrict__ hg3,
                          const float* __restrict__ We, const float* __restrict__ lin3,
                          const float* __restrict__ cb, float* __restrict__ out){
  int n = blockIdx.x*256 + threadIdx.x;
  if (n >= NN) return;
  int b = iptr[n], en = iptr[n+1];
  const float* cp = cw + (long)n*10;
  float e0f=0.f, e1f=0.f;
  #pragma unroll
  for (int k=0;k<10;k++){ e0f += cp[k]*We[k*2]; e1f += cp[k]*We[k*2+1]; }
  float a0=0.f, a1=0.f;
  for (int i=b;i<en;i++){
    int e = eid[i], s_ = ei[e];
    float w = L[e];
    a0 += w*hg3[s_*2];
    a1 += w*hg3[s_*2+1];
  }
  out[n*2]   = fmaxf(lin3[n*2]  +a0+e0f+cb[0], 0.f);
  out[n*2+1] = fmaxf(lin3[n*2+1]+a1+e1f+cb[1], 0.f);
}

extern "C" void kernel_launch(void* const* d_in, const int* in_sizes, int n_in,
                              void* d_out, int out_size, void* d_ws, size_t ws_size,
                              hipStream_t stream){
  const int* ei = (const int*)d_in[1];

  long long sz[64];
  {
    const long long* s64 = (const long long*)(const void*)in_sizes;
    bool is64 = (n_in >= 2) && (in_sizes[0] == 3340000) && (in_sizes[1] == 0)
                && (s64[1] == 200000);
    for (int i=0;i<n_in && i<64;i++) sz[i] = is64 ? s64[i] : (long long)in_sizes[i];
  }

  int IWg[3], IWe[3], IAttn[3], IAt[3], ICb[3], ILw[3], ILb[3], IG[3], IB[3];
  if (n_in > 8 && sz[8] == (long long)HID*HID){ // setup_inputs() dict order
    for (int l=0;l<3;l++){
      IWg[l]=3+l*5; IWe[l]=4+l*5; IAttn[l]=5+l*5; IAt[l]=6+l*5; ICb[l]=7+l*5;
      ILw[l]=18+l*4; ILb[l]=19+l*4; IG[l]=20+l*4; IB[l]=21+l*4;
    }
  } else {
    int idx=3;
    for (int l=0;l<3;l++){
      IWg[l]=idx++; IWe[l]=idx++; IAttn[l]=idx++; IAt[l]=idx++; ICb[l]=idx++;
      ILw[l]=idx++; ILb[l]=idx++; IG[l]=idx++; IB[l]=idx++;
    }
  }
  #define FP(i) ((const float*)d_in[(i)])

  char* ws = (char*)d_ws;
  size_t off = 0;
  auto alloc = [&](size_t bytes)->void*{ void* p = ws + off; off += (bytes + 255) & ~(size_t)255; return p; };
  auto G = [](long n){ return (int)((n+255)/256); };

  u16*   buf0 = (u16*)  alloc((size_t)NN*HID*2);   // hg (bf16)
  u16*   bufA = (u16*)  alloc((size_t)NN*HID*2);   // layer-1 lin/result
  u16*   bufB = (u16*)  alloc((size_t)NN*HID*2);   // layer-2 lin/result
  u16*   xbf  = (u16*)  alloc((size_t)NN*KP1*2);   // layer-1 A (bf16, padded)
  u16*   Wt   = (u16*)  alloc((size_t)2*HID*HID*2);// fused folded weights [2048][K] K-major
  u16*   We16 = (u16*)  alloc((size_t)10*HID*2);
  float* cst  = (float*)alloc(2*HID*4);
  float* L    = (float*)alloc((size_t)EE*4*4);
  float* ssrc = (float*)alloc((size_t)NN*4*4);
  float* sdst = (float*)alloc((size_t)NN*4*4);
  int*   iptr = (int*)  alloc((size_t)(NN+4)*4);
  int*   cnts = (int*)  alloc((size_t)NN*4);
  int*   eid  = (int*)  alloc((size_t)EE*4);
  int*   bsum = (int*)  alloc(256*4);
  int*   boff = (int*)  alloc(256*4);
  float* stats= (float*)alloc(2*HID*4);
  float* scale= (float*)alloc(HID*4);
  float* shift= (float*)alloc(HID*4);
  float* qbuf = (float*)alloc(64*4);
  float* hg3  = (float*)alloc((size_t)NN*2*4);
  float* lin3 = (float*)alloc((size_t)NN*2*4);
  float* cw   = (float*)alloc((size_t)NN*40*4);    // factored edge-feature weights
  float* W4   = (float*)alloc((size_t)HID*4*4);    // layer-3 folded interleaved weights
  float* c4   = (float*)alloc(4*4);
  float* part = (float*)alloc((size_t)256*2048*4); // bnstats8 partials (2 MB)

  // ---- CSR by dst (two-level scan) ----
  int nsb = G(NN);   // 79 scan blocks
  hipMemsetAsync(cnts, 0, NN*sizeof(int), stream);
  k_count<<<G(EE),256,0,stream>>>(ei, cnts);
  k_scanA<<<nsb,256,0,stream>>>(cnts, iptr, bsum);
  k_scanB<<<1,128,0,stream>>>(bsum, boff, iptr+NN, nsb);
  k_scanC<<<nsb,256,0,stream>>>(boff, iptr);
  hipMemsetAsync(cnts, 0, NN*sizeof(int), stream);
  k_fill<<<G(EE),256,0,stream>>>(ei, iptr, cnts, eid);

  int gg = 1264;   // 79 row-tiles (256 rows) x 16 col-tiles (128 cols), XCD-swizzled in-kernel
  int gsd = (NN*4+3)/4;   // k_sdot: one wave per (n,h)

  // ---- layer 1 (A = bf16(x), Kp=256) ----
  {
    hipMemsetAsync(stats, 0, 2*FIN*sizeof(float), stream);
    dim3 bg(200, 1);
    k_bnstats<float><<<bg,256,0,stream>>>(FP(0), stats, FIN);
    k_bnfin<<<1,256,0,stream>>>(stats, FP(IG[0]), FP(IB[0]), scale, shift, FIN);
    k_cast<<<G((long)NN*KP1),256,0,stream>>>(FP(0), xbf);
    dim3 ft(KP1/32, 64);
    k_foldT<<<ft,256,0,stream>>>(FP(IWg[0]), FP(ILw[0]), scale, Wt, FIN, KP1);
    k_cinit<<<8,256,0,stream>>>(FP(ILb[0]), cst);
    dim3 cg(32, (FIN+127)/128);
    k_const<<<cg,256,0,stream>>>(FP(IWg[0]), FP(ILw[0]), shift, cst, FIN);
    k_we16<<<40,256,0,stream>>>(FP(IWe[0]), We16);
    k_gemm<<<gg,512,0,stream>>>(xbf, KP1, Wt, cst, buf0, bufA);
    k_sdot<<<gsd,256,0,stream>>>(buf0, FP(IAttn[0]), ssrc, sdst);
    k_q<<<1,64,0,stream>>>(FP(IWe[0]), FP(IAttn[0]), qbuf);
    k_logits<<<G(EE),256,0,stream>>>(ei, FP(2), qbuf, FP(IAt[0]), ssrc, sdst, L);
    k_mden<<<G(NN),256,0,stream>>>(iptr, eid, FP(2), L, cw);
    k_gath<<<(NN+NB-1)/NB,256,0,stream>>>(buf0, ei, iptr, eid, L, cw,
                                          We16, FP(ICb[0]), bufA);
  }
  // ---- layer 2 (A = bufA, K=1024) ----
  {
    k_bnstats8<<<256,256,0,stream>>>(bufA, part);
    k_pred<<<8,256,0,stream>>>(part, stats);
    k_bnfin<<<4,256,0,stream>>>(stats, FP(IG[1]), FP(IB[1]), scale, shift, HID);
    dim3 ft(HID/32, 64);
    k_foldT<<<ft,256,0,stream>>>(FP(IWg[1]), FP(ILw[1]), scale, Wt, HID, HID);
    k_cinit<<<8,256,0,stream>>>(FP(ILb[1]), cst);
    dim3 cg(32, HID/128);
    k_const<<<cg,256,0,stream>>>(FP(IWg[1]), FP(ILw[1]), shift, cst, HID);
    k_we16<<<40,256,0,stream>>>(FP(IWe[1]), We16);
    k_gemm<<<gg,512,0,stream>>>(bufA, HID, Wt, cst, buf0, bufB);
    k_sdot<<<gsd,256,0,stream>>>(buf0, FP(IAttn[1]), ssrc, sdst);
    k_q<<<1,64,0,stream>>>(FP(IWe[1]), FP(IAttn[1]), qbuf);
    k_logits<<<G(EE),256,0,stream>>>(ei, FP(2), qbuf, FP(IAt[1]), ssrc, sdst, L);
    k_mden<<<G(NN),256,0,stream>>>(iptr, eid, FP(2), L, cw);
    k_gath<<<(NN+NB-1)/NB,256,0,stream>>>(buf0, ei, iptr, eid, L, cw,
                                          We16, FP(ICb[1]), bufB);
  }

  // ---- layer 3 (input = bufB) ----
  k_bnstats8<<<256,256,0,stream>>>(bufB, part);
  k_pred<<<8,256,0,stream>>>(part, stats);
  k_bnfin<<<4,256,0,stream>>>(stats, FP(IG[2]), FP(IB[2]), scale, shift, HID);
  k_c4init<<<1,64,0,stream>>>(FP(ILb[2]), c4);
  k_fold3<<<HID/256,256,0,stream>>>(FP(IWg[2]), FP(ILw[2]), scale, shift, W4, c4);
  k_n3<<<NN/4,256,0,stream>>>(bufB, W4, c4, FP(IAttn[2]), hg3, lin3, ssrc, sdst);
  k_logits3<<<G(EE),256,0,stream>>>(ei, FP(2), FP(IWe[2]), FP(IAttn[2]), FP(IAt[2]), ssrc, sdst, L);
  k_mden3<<<G(NN),256,0,stream>>>(iptr, eid, FP(2), L, cw);
  k_gather3<<<G(NN),256,0,stream>>>(ei, iptr, eid, L, cw, hg3,
                                    FP(IWe[2]), lin3, FP(ICb[2]), (float*)d_out);
}

// Round 12
// 759.771 us; speedup vs baseline: 1.6460x; 1.0043x over previous
//
#include <hip/hip_runtime.h>
#include <math.h>

#define NN 20000
#define EE 100000
#define FIN 167
#define KP1 192    // layer-1 K padded to mult of 64 (was 256: 53% zero-K; 192 = minimal)
#define HID 1024   // H*O = 4*256
#define OO 256
#define NB 8       // nodes per k_gath block

typedef unsigned short u16;
typedef short bf16x8 __attribute__((ext_vector_type(8)));
typedef short s16x4  __attribute__((ext_vector_type(4)));
typedef float f32x4  __attribute__((ext_vector_type(4)));

__device__ __forceinline__ float bf(u16 u){ return __uint_as_float(((unsigned)u)<<16); }
__device__ __forceinline__ u16 fb(float v){            // f32 -> bf16 RNE
  unsigned u = __float_as_uint(v);
  return (u16)((u + 0x7FFFu + ((u>>16)&1u)) >> 16);
}
__device__ __forceinline__ float ldv(const float* p, long i){ return p[i]; }
__device__ __forceinline__ float ldv(const u16*   p, long i){ return bf(p[i]); }

// ---------------- CSR build ----------------
__global__ void k_count(const int* __restrict__ ei, int* __restrict__ counts){
  int e = blockIdx.x*256 + threadIdx.x;
  if (e < EE) atomicAdd(&counts[ei[EE+e]], 1);
}

// two-level scan
__global__ __launch_bounds__(256) void k_scanA(const int* __restrict__ counts,
                                               int* __restrict__ iptr, int* __restrict__ bsum){
  __shared__ int sd[256];
  int b = blockIdx.x, tid = threadIdx.x;
  int i = b*256 + tid;
  int v = (i<NN)? counts[i] : 0;
  sd[tid]=v; __syncthreads();
  for (int off=1; off<256; off<<=1){
    int t = (tid>=off)? sd[tid-off] : 0;
    __syncthreads();
    sd[tid] += t;
    __syncthreads();
  }
  if (i<NN) iptr[i] = sd[tid]-v;     // block-local exclusive
  if (tid==255) bsum[b]=sd[255];
}
__global__ __launch_bounds__(128) void k_scanB(const int* __restrict__ bsum,
                                               int* __restrict__ boff, int* __restrict__ iptrN,
                                               int nb){
  __shared__ int sd[128];
  int tid=threadIdx.x;
  int v=(tid<nb)? bsum[tid]:0;
  sd[tid]=v; __syncthreads();
  for (int off=1; off<128; off<<=1){
    int t=(tid>=off)?sd[tid-off]:0;
    __syncthreads();
    sd[tid]+=t;
    __syncthreads();
  }
  if (tid<nb) boff[tid]=sd[tid]-v;
  if (tid==127) *iptrN = sd[127];
}
__global__ void k_scanC(const int* __restrict__ boff, int* __restrict__ iptr){
  int i = blockIdx.x*256+threadIdx.x;
  if (i<NN) iptr[i] += boff[blockIdx.x];
}

__global__ void k_fill(const int* __restrict__ ei, const int* __restrict__ iptr,
                       int* __restrict__ cursor, int* __restrict__ eid){
  int e = blockIdx.x*256 + threadIdx.x;
  if (e < EE){
    int d = ei[EE+e];
    int pos = atomicAdd(&cursor[d],1);
    eid[iptr[d]+pos] = e;
  }
}

// ---------------- BatchNorm stats ----------------
// layer-1 (float input, F=167): original coalesced version (never hot; 67K atomics OK)
template<typename T>
__global__ void k_bnstats(const T* __restrict__ X, float* __restrict__ sums, int F){
  int f = blockIdx.y*256 + threadIdx.x;
  if (f >= F) return;
  int r0 = blockIdx.x*100, r1 = r0+100;
  float s=0.f, s2=0.f;
  for (int r=r0;r<r1;r++){ float v = ldv(X,(long)r*F+f); s += v; s2 += v*v; }
  atomicAdd(&sums[f], s);
  atomicAdd(&sums[F+f], s2);
}

// layers 2/3 (bf16, F=HID) stage A: zero-atomic partials (round-7 lesson: atomics storm)
__global__ __launch_bounds__(256) void k_bnstats8(const u16* __restrict__ X, float* __restrict__ part){
  int tid = threadIdx.x;
  int f8 = (tid & 127)*8;
  int r0 = blockIdx.x*79, r1 = min(NN, r0+79);     // grid 256
  float s[8]={0,0,0,0,0,0,0,0}, s2[8]={0,0,0,0,0,0,0,0};
  for (int r=r0 + (tid>>7); r<r1; r+=2){
    bf16x8 v = *(const bf16x8*)(X + (long)r*HID + f8);
    #pragma unroll
    for (int j=0;j<8;j++){ float x=bf((u16)v[j]); s[j]+=x; s2[j]+=x*x; }
  }
  __shared__ float red[256][8];
  float* pb = part + (long)blockIdx.x*2048;
  #pragma unroll
  for (int j=0;j<8;j++) red[tid][j]=s[j];
  __syncthreads();
  if (tid<128){
    #pragma unroll
    for (int j=0;j<8;j++) pb[f8+j] = red[tid][j]+red[tid+128][j];
  }
  __syncthreads();
  #pragma unroll
  for (int j=0;j<8;j++) red[tid][j]=s2[j];
  __syncthreads();
  if (tid<128){
    #pragma unroll
    for (int j=0;j<8;j++) pb[1024+f8+j] = red[tid][j]+red[tid+128][j];
  }
}

// stage B: reduce 256 partials -> sums[2048]; consecutive threads = consecutive addrs
__global__ __launch_bounds__(256) void k_pred(const float* __restrict__ part, float* __restrict__ sums){
  int idx = blockIdx.x*256 + threadIdx.x;   // grid 8 -> 2048 threads
  float s = 0.f;
  #pragma unroll 8
  for (int b=0;b<256;b++) s += part[(long)b*2048 + idx];
  sums[idx] = s;
}

__global__ void k_bnfin(const float* __restrict__ sums, const float* __restrict__ g,
                        const float* __restrict__ b, float* __restrict__ scale,
                        float* __restrict__ shift, int F){
  int f = blockIdx.x*256 + threadIdx.x;
  if (f >= F) return;
  float mu  = sums[f]   * (1.f/NN);
  float var = sums[F+f] * (1.f/NN) - mu*mu;
  float sc  = rsqrtf(var + 1e-5f) * g[f];
  scale[f] = sc;
  shift[f] = b[f] - mu*sc;
}

// ---------------- BN-folded fused weight prep ----------------
__global__ __launch_bounds__(256) void k_foldT(const float* __restrict__ Wg, const float* __restrict__ Wl,
                        const float* __restrict__ scale,
                        u16* __restrict__ Wt, int K, int Kp){
  __shared__ float t[32][33];
  int k0 = blockIdx.x*32, c0 = blockIdx.y*32;
  int tx = threadIdx.x & 31, ty = threadIdx.x >> 5;
  bool second = (c0 >= HID);
  const float* W = second ? Wl : Wg;
  int cc0 = second ? c0 - HID : c0;
  #pragma unroll
  for (int i=0;i<4;i++){
    int k = k0 + ty + i*8;
    t[ty+i*8][tx] = (k < K) ? W[(long)k*HID + cc0 + tx] * scale[k] : 0.f;
  }
  __syncthreads();
  #pragma unroll
  for (int i=0;i<4;i++){
    int c = c0 + ty + i*8;
    Wt[(long)c*Kp + k0 + tx] = fb(t[tx][ty+i*8]);
  }
}

// cst init: lb for lin half, 0 for hg half
__global__ void k_cinit(const float* __restrict__ lb, float* __restrict__ cst){
  int c = blockIdx.x*256 + threadIdx.x;
  if (c < 2*HID) cst[c] = (c >= HID) ? lb[c-HID] : 0.f;
}

// cst[c] += sum_k shift[k]*W[k][c]  — parallel reduction, coalesced
__global__ __launch_bounds__(256) void k_const(const float* __restrict__ Wg, const float* __restrict__ Wl,
                        const float* __restrict__ shift, float* __restrict__ cst, int K){
  int tx = threadIdx.x & 63, ty = threadIdx.x >> 6;
  int c = blockIdx.x*64 + tx;
  bool second = c >= HID;
  const float* W = second ? Wl : Wg;
  int cc = second ? c-HID : c;
  int k0 = blockIdx.y*128;
  int k1 = min(K, k0+128);
  float s = 0.f;
  for (int k=k0+ty; k<k1; k+=4) s += shift[k]*W[(long)k*HID+cc];
  __shared__ float red[256];
  red[threadIdx.x] = s;
  __syncthreads();
  if (ty == 0){
    float tot = red[tx] + red[tx+64] + red[tx+128] + red[tx+192];
    atomicAdd(&cst[c], tot);
  }
}

__global__ void k_cast(const float* __restrict__ x, u16* __restrict__ xb){
  long idx = (long)blockIdx.x*256 + threadIdx.x;
  if (idx >= (long)NN*KP1) return;
  int n = (int)(idx / KP1), k = (int)(idx % KP1);
  xb[idx] = (k<FIN)? fb(x[(long)n*FIN+k]) : (u16)0;
}

__global__ void k_we16(const float* __restrict__ We, u16* __restrict__ We16){
  int i = blockIdx.x*256 + threadIdx.x;
  if (i < 10*HID) We16[i] = fb(We[i]);
}

// ---------------- MFMA GEMM v7: v6 + T5 setprio ----------------
// v6 measured 110us / 33% MfmaUtil / 0 bank conflicts (conflict fix was temporally null:
// LDS not critical; kept as insurance). v7 adds s_setprio(1) around the MFMA cluster —
// regime check: 2 co-resident blocks/CU at different phase positions = the role
// diversity T5 needs (unlike r1-r4 lockstep nulls). Pre-commit: positive -> confirmed,
// null -> keep (free).
#define MF(a_,b_,c_) __builtin_amdgcn_mfma_f32_16x16x32_bf16(a_,b_,c_,0,0,0)
#define FENCE asm volatile("" ::: "memory")
#define BAR do { FENCE; __builtin_amdgcn_s_barrier(); FENCE; } while(0)

__global__ __launch_bounds__(512,2) void k_gemm(const u16* __restrict__ A, int K,
                     const u16* __restrict__ Wt, const float* __restrict__ cst,
                     u16* __restrict__ Chg, u16* __restrict__ Clin){
  __shared__ u16 lds[3][12288];   // 3 x (A 8192 u16 | B 4096 u16) = 72 KB -> 2 blocks/CU
  int b = blockIdx.x;
  int wg = (b & 7)*158 + (b >> 3);          // 1264 % 8 == 0 -> bijective XCD swizzle
  int row0 = (wg >> 4)*256, col0 = (wg & 15)*128;
  int tid = threadIdx.x;
  int wave = tid >> 6, lane = tid & 63, quad = lane >> 4, lo = lane & 15;
  int wm = wave >> 1, wn = wave & 1;        // 4 M-waves x 2 N-waves, 64x64 out each
  const u16* Apt[2];
  #pragma unroll
  for (int i=0;i<2;i++){
    int s = i*512 + tid, srow = s>>2;
    int gr = row0 + srow; if (gr >= NN) gr = NN-1;      // clamp: garbage rows never stored
    Apt[i] = A + (long)gr*K + (((s&3)^((srow>>1)&3))*8);
  }
  int brow = tid>>2;
  const u16* Bpt = Wt + (long)(col0 + brow)*K + ((((tid&3)^((brow>>1)&3)))*8);
  const char* ldsc = (const char*)&lds[0][0];
  int axor = (lo>>1) & 3;
  int aoff = (wm*64 + lo)*64 + ((quad^axor)*16);            // A frag i at +i*1024 B
  int boff = 16384 + (wn*64 + lo)*64 + ((quad^axor)*16);    // B frag n at +n*1024 B
  int NT = K >> 5;
  f32x4 acc[4][4] = {};
  // ---- prologue: stage tiles 0,1 into buffers 0,1 ----
  {
    u16* d0 = (u16*)&lds[0][0];
    u16* d1 = (u16*)&lds[1][0];
    __builtin_amdgcn_global_load_lds(Apt[0],      d0 +         tid*8, 16, 0, 0);
    __builtin_amdgcn_global_load_lds(Apt[1],      d0 + 4096 +  tid*8, 16, 0, 0);
    __builtin_amdgcn_global_load_lds(Bpt,         d0 + 8192 +  tid*8, 16, 0, 0);
    __builtin_amdgcn_global_load_lds(Apt[0] + 32, d1 +         tid*8, 16, 0, 0);
    __builtin_amdgcn_global_load_lds(Apt[1] + 32, d1 + 4096 +  tid*8, 16, 0, 0);
    __builtin_amdgcn_global_load_lds(Bpt    + 32, d1 + 8192 +  tid*8, 16, 0, 0);
    asm volatile("s_waitcnt vmcnt(3)" ::: "memory");   // tile-0 panels landed
    BAR;
  }
  int cb = 0;
  for (int t=0; t<NT; t++){
    const char* Lb = ldsc + cb*24576;
    bf16x8 af[4], bfr[4];
    #pragma unroll
    for (int i=0;i<4;i++) af[i]  = *(const bf16x8*)(Lb + aoff + i*1024);
    #pragma unroll
    for (int n=0;n<4;n++) bfr[n] = *(const bf16x8*)(Lb + boff + n*1024);
    int nx2 = (t+2 < NT);
    if (nx2){
      int sb = cb+2; if (sb>=3) sb-=3;       // buffer holding tile t-1 (consumed, barrier-safe)
      u16* Sd = (u16*)&lds[0][0] + sb*12288;
      int ko = (t+2) << 5;
      __builtin_amdgcn_global_load_lds(Apt[0] + ko, Sd +         tid*8, 16, 0, 0);
      __builtin_amdgcn_global_load_lds(Apt[1] + ko, Sd + 4096 +  tid*8, 16, 0, 0);
      __builtin_amdgcn_global_load_lds(Bpt    + ko, Sd + 8192 +  tid*8, 16, 0, 0);
    }
    __builtin_amdgcn_s_setprio(1);
    #pragma unroll
    for (int i=0;i<4;i++)
      #pragma unroll
      for (int n=0;n<4;n++)
        acc[i][n] = MF(af[i], bfr[n], acc[i][n]);
    __builtin_amdgcn_s_setprio(0);
    if (t+1 < NT){
      if (nx2) asm volatile("s_waitcnt vmcnt(3)" ::: "memory");  // tile t+1 landed
      else     asm volatile("s_waitcnt vmcnt(0)" ::: "memory");  // tail (once)
      BAR;
    }
    cb++; if (cb>=3) cb=0;
  }
  // ---- epilogue (verified mapping, unchanged) ----
  #pragma unroll
  for (int i=0;i<4;i++){
    #pragma unroll
    for (int n=0;n<4;n++){
      int col = col0 + wn*64 + n*16 + lo;
      float cs = cst[col];
      #pragma unroll
      for (int r=0;r<4;r++){
        int row = row0 + wm*64 + i*16 + quad*4 + r;   // C/D: col=lane&15, row=quad*4+reg
        if (row < NN){
          u16 o = fb(acc[i][n][r] + cs);
          if (col < HID) Chg[(long)row*HID + col] = o;
          else           Clin[(long)row*HID + col - HID] = o;
        }
      }
    }
  }
}
#undef MF
#undef BAR
#undef FENCE

// ---------------- per-(node,head) attention dots: wave-parallel, coalesced ----------------
__global__ __launch_bounds__(256) void k_sdot(const u16* __restrict__ hg, const float* __restrict__ attn,
                       float* __restrict__ ssrc, float* __restrict__ sdst){
  int unit = blockIdx.x*4 + (threadIdx.x >> 6);   // one wave per (n,h)
  if (unit >= NN*4) return;
  int lane = threadIdx.x & 63;
  int n = unit >> 2, h = unit & 3;
  const u16* hp = hg + (long)n*HID + h*OO + lane*4;
  s16x4 v = *(const s16x4*)hp;
  float4 x0 = *(const float4*)(attn + h*OO + lane*4);
  float4 x1 = *(const float4*)(attn + HID + h*OO + lane*4);
  float f0 = bf((u16)v.x), f1 = bf((u16)v.y), f2 = bf((u16)v.z), f3 = bf((u16)v.w);
  float ss = f0*x0.x + f1*x0.y + f2*x0.z + f3*x0.w;
  float sd = f0*x1.x + f1*x1.y + f2*x1.z + f3*x1.w;
  #pragma unroll
  for (int off=32; off>0; off>>=1){
    ss += __shfl_down(ss, off);
    sd += __shfl_down(sd, off);
  }
  if (lane==0){ ssrc[unit]=ss; sdst[unit]=sd; }
}

__global__ void k_q(const float* __restrict__ We, const float* __restrict__ attn,
                    float* __restrict__ q){
  int t = threadIdx.x;
  if (t >= 40) return;
  int k = t >> 2, h = t & 3;
  float s = 0.f;
  for (int d=0; d<OO; d++) s += We[(long)k*HID + h*OO + d] * attn[2*HID + h*OO + d];
  q[k*4+h] = s;
}

// per-EDGE logits: ea read once, all 4 heads computed, float4 write
__global__ void k_logits(const int* __restrict__ ei, const float* __restrict__ ea,
                         const float* __restrict__ q, const float* __restrict__ at,
                         const float* __restrict__ ssrc, const float* __restrict__ sdst,
                         float* __restrict__ L){
  int e = blockIdx.x*256 + threadIdx.x;
  if (e >= EE) return;
  int s = ei[e], dd = ei[EE+e];
  float4 a0 = *(const float4*)(ea + (long)e*12);
  float4 a1 = *(const float4*)(ea + (long)e*12 + 4);
  float4 a2 = *(const float4*)(ea + (long)e*12 + 8);
  float t = a0.x;
  float cc[10] = {a0.y,a0.z,a0.w, a1.x,a1.y,a1.z,a1.w, a2.x,a2.y,a2.z};
  float4 ss = *(const float4*)(ssrc + (long)s*4);
  float4 sd = *(const float4*)(sdst + (long)dd*4);
  float sv[4] = {ss.x+sd.x, ss.y+sd.y, ss.z+sd.z, ss.w+sd.w};
  float4 out;
  #pragma unroll
  for (int h=0;h<4;h++){
    float se = 0.f;
    #pragma unroll
    for (int k=0;k<10;k++) se += cc[k]*q[k*4+h];
    float v = sv[h] + se + t*at[h];
    ((float*)&out)[h] = (v>0.f)? v : 0.2f*v;
  }
  *(float4*)(L + (long)e*4) = out;
}

// per-NODE softmax finalize: writes w = exp(L-m)*dinv IN PLACE into L (float4),
// accumulates cw[n][4][10] with ea read ONCE per edge
__global__ void k_mden(const int* __restrict__ iptr, const int* __restrict__ eid,
                       const float* __restrict__ ea, float* __restrict__ L,
                       float* __restrict__ cw){
  int n = blockIdx.x*256 + threadIdx.x;
  if (n >= NN) return;
  int b = iptr[n], e1 = iptr[n+1];
  float m0=-INFINITY, m1=-INFINITY, m2=-INFINITY, m3=-INFINITY;
  for (int i=b;i<e1;i++){
    float4 l = *(const float4*)(L + (long)eid[i]*4);
    m0=fmaxf(m0,l.x); m1=fmaxf(m1,l.y); m2=fmaxf(m2,l.z); m3=fmaxf(m3,l.w);
  }
  if (b==e1){ m0=m1=m2=m3=0.f; }
  float s0=0.f,s1=0.f,s2=0.f,s3=0.f;
  for (int i=b;i<e1;i++){
    float4 l = *(const float4*)(L + (long)eid[i]*4);
    s0+=expf(l.x-m0); s1+=expf(l.y-m1); s2+=expf(l.z-m2); s3+=expf(l.w-m3);
  }
  float d0=1.f/(s0+1e-16f), d1=1.f/(s1+1e-16f), d2=1.f/(s2+1e-16f), d3=1.f/(s3+1e-16f);
  float c[4][10] = {};
  for (int i=b;i<e1;i++){
    int e = eid[i];
    float4 l = *(const float4*)(L + (long)e*4);
    float4 w = { expf(l.x-m0)*d0, expf(l.y-m1)*d1, expf(l.z-m2)*d2, expf(l.w-m3)*d3 };
    *(float4*)(L + (long)e*4) = w;
    float4 a0 = *(const float4*)(ea + (long)e*12);
    float4 a1 = *(const float4*)(ea + (long)e*12 + 4);
    float4 a2 = *(const float4*)(ea + (long)e*12 + 8);
    float cc[10] = {a0.y,a0.z,a0.w, a1.x,a1.y,a1.z,a1.w, a2.x,a2.y,a2.z};
    #pragma unroll
    for (int k=0;k<10;k++){
      c[0][k] += w.x*cc[k]; c[1][k] += w.y*cc[k];
      c[2][k] += w.z*cc[k]; c[3][k] += w.w*cc[k];
    }
  }
  float* cp = cw + (long)n*40;
  #pragma unroll
  for (int h=0;h<4;h++)
    #pragma unroll
    for (int k=0;k<10;k++) cp[h*10+k] = c[h][k];
}

// ---------------- edge gather: 8B/lane + 2-deep software prefetch ----------------
__global__ __launch_bounds__(256) void k_gath(
    const u16* __restrict__ hg, const int* __restrict__ ei,
    const int* __restrict__ iptr, const int* __restrict__ eid,
    const float* __restrict__ L,      // holds w[e][h] (from k_mden)
    const float* __restrict__ cw,     // [NN][4][10]
    const u16* __restrict__ We16, const float* __restrict__ cb,
    u16* __restrict__ lio)
{
  __shared__ u16  sWe[10*HID];   // 20 KB
  __shared__ float scb[HID];     // 4 KB
  int tid = threadIdx.x;
  for (int i=tid;i<10*HID;i+=256) sWe[i] = We16[i];
  for (int i=tid;i<HID;i+=256) scb[i] = cb[i];
  __syncthreads();
  int h = tid >> 6;
  int f0 = tid*4;
  int d0 = blockIdx.x*NB, dend = min(NN, d0+NB);
  for (int d=d0; d<dend; d++){
    s16x4 a0 = *(const s16x4*)(lio + (long)d*HID + f0);
    float acc0=bf((u16)a0.x), acc1=bf((u16)a0.y), acc2=bf((u16)a0.z), acc3=bf((u16)a0.w);
    int b0 = iptr[d], en = iptr[d+1];
    float wN = 0.f; s16x4 vN = {};
    if (b0 < en){
      int e = eid[b0], s_ = ei[e];
      wN = L[(long)e*4 + h];
      vN = *(const s16x4*)(hg + (long)s_*HID + f0);
    }
    for (int i=b0;i<en;i++){
      float w = wN; s16x4 v = vN;
      if (i+1 < en){
        int e2 = eid[i+1], s2 = ei[e2];
        wN = L[(long)e2*4 + h];
        vN = *(const s16x4*)(hg + (long)s2*HID + f0);
      }
      acc0 += w*bf((u16)v.x); acc1 += w*bf((u16)v.y);
      acc2 += w*bf((u16)v.z); acc3 += w*bf((u16)v.w);
    }
    const float* cp = cw + (long)d*40 + h*10;
    float ew0=0.f, ew1=0.f, ew2=0.f, ew3=0.f;
    #pragma unroll
    for (int k=0;k<10;k++){
      float c = cp[k];
      s16x4 wv = *(const s16x4*)(sWe + k*HID + f0);
      ew0 += c*bf((u16)wv.x); ew1 += c*bf((u16)wv.y);
      ew2 += c*bf((u16)wv.z); ew3 += c*bf((u16)wv.w);
    }
    acc0 += ew0; acc1 += ew1; acc2 += ew2; acc3 += ew3;
    u16 o[4];
    o[0] = fb(fmaxf(acc0 + scb[f0  ], 0.f));
    o[1] = fb(fmaxf(acc1 + scb[f0+1], 0.f));
    o[2] = fb(fmaxf(acc2 + scb[f0+2], 0.f));
    o[3] = fb(fmaxf(acc3 + scb[f0+3], 0.f));
    *(s16x4*)(lio + (long)d*HID + f0) = *(const s16x4*)o;
  }
}

// ---------------- layer 3 ----------------
__global__ void k_c4init(const float* __restrict__ lb, float* __restrict__ c4){
  if (threadIdx.x==0 && blockIdx.x==0){ c4[0]=0.f; c4[1]=0.f; c4[2]=lb[0]; c4[3]=lb[1]; }
}

// fold BN scale into interleaved weights W4[k][4] = {Wg0,Wg1,lw0,lw1}*sc; shift -> c4
__global__ __launch_bounds__(256) void k_fold3(const float* __restrict__ Wg, const float* __restrict__ lw,
                        const float* __restrict__ scale, const float* __restrict__ shift,
                        float* __restrict__ W4, float* __restrict__ c4){
  int k = blockIdx.x*256 + threadIdx.x;   // grid 4, covers HID exactly
  float sc = scale[k], sh = shift[k];
  float w0=Wg[k*2], w1=Wg[k*2+1], l0=lw[k*2], l1=lw[k*2+1];
  float4 o = {w0*sc, w1*sc, l0*sc, l1*sc};
  *(float4*)(W4 + (long)k*4) = o;
  __shared__ float red[256][4];
  int tid = threadIdx.x;
  red[tid][0]=sh*w0; red[tid][1]=sh*w1; red[tid][2]=sh*l0; red[tid][3]=sh*l1;
  __syncthreads();
  for (int o2=128;o2>0;o2>>=1){
    if (tid<o2){
      #pragma unroll
      for (int j=0;j<4;j++) red[tid][j]+=red[tid+o2][j];
    }
    __syncthreads();
  }
  if (tid==0){
    #pragma unroll
    for (int j=0;j<4;j++) atomicAdd(&c4[j], red[0][j]);
  }
}

// wave-per-node GEMV: x-rows and W4 staged in LDS, shuffle reduce, no post-stage barriers
__global__ __launch_bounds__(256) void k_n3(const u16* __restrict__ in,
    const float* __restrict__ W4, const float* __restrict__ c4,
    const float* __restrict__ attn,
    float* __restrict__ hg3, float* __restrict__ lin3,
    float* __restrict__ ssrc, float* __restrict__ sdst)
{
  __shared__ float sW[HID*4];   // 16 KB
  __shared__ float sx[4][HID];  // 16 KB
  int tid = threadIdx.x;
  int n0 = blockIdx.x*4;        // grid 5000 exact
  for (int i=tid; i<HID; i+=256) *(float4*)&sW[i*4] = *(const float4*)(W4 + (long)i*4);
  for (int idx=tid; idx<512; idx+=256){
    int rr = idx>>7, ch = idx&127;
    bf16x8 v = *(const bf16x8*)(in + (long)(n0+rr)*HID + ch*8);
    #pragma unroll
    for (int j=0;j<8;j++) sx[rr][ch*8+j] = bf((u16)v[j]);
  }
  __syncthreads();
  int w = tid>>6, lane = tid&63;
  float p0=0.f,p1=0.f,p2=0.f,p3=0.f;
  #pragma unroll
  for (int g=0; g<16; g++){
    int k = g*64 + lane;                      // lanes consecutive -> conflict-free
    float x = sx[w][k];
    float4 wv = *(const float4*)&sW[k*4];
    p0 += x*wv.x; p1 += x*wv.y; p2 += x*wv.z; p3 += x*wv.w;
  }
  #pragma unroll
  for (int off=32; off>0; off>>=1){
    p0 += __shfl_down(p0, off);
    p1 += __shfl_down(p1, off);
    p2 += __shfl_down(p2, off);
    p3 += __shfl_down(p3, off);
  }
  if (lane==0){
    int n = n0 + w;
    float r0=p0+c4[0], r1=p1+c4[1], r2=p2+c4[2], r3=p3+c4[3];
    hg3[n*2]=r0; hg3[n*2+1]=r1;
    lin3[n*2]=r2; lin3[n*2+1]=r3;
    ssrc[n]=r0*attn[0]+r1*attn[1];
    sdst[n]=r0*attn[2]+r1*attn[3];
  }
}

__global__ void k_logits3(const int* __restrict__ ei, const float* __restrict__ ea,
                          const float* __restrict__ We, const float* __restrict__ attn,
                          const float* __restrict__ at, const float* __restrict__ ssrc,
                          const float* __restrict__ sdst, float* __restrict__ L){
  int e = blockIdx.x*256 + threadIdx.x;
  if (e >= EE) return;
  int s = ei[e], d = ei[EE+e];
  float e0=0.f, e1=0.f;
  #pragma unroll
  for (int k=0;k<10;k++){
    float c = ea[e*12+1+k];
    e0 += c*We[k*2]; e1 += c*We[k*2+1];
  }
  float se = e0*attn[4] + e1*attn[5];
  float v = ssrc[s] + sdst[d] + se + ea[e*12]*at[0];
  L[e] = (v>0.f)? v : 0.2f*v;
}

// layer-3 softmax finalize: w in place + cw3[n][k]
__global__ void k_mden3(const int* __restrict__ iptr, const int* __restrict__ eid,
                        const float* __restrict__ ea, float* __restrict__ L,
                        float* __restrict__ cw){
  int n = blockIdx.x*256 + threadIdx.x;
  if (n >= NN) return;
  int b = iptr[n], e1 = iptr[n+1];
  float mx = -INFINITY;
  for (int i=b;i<e1;i++) mx = fmaxf(mx, L[eid[i]]);
  if (b == e1) mx = 0.f;
  float s = 0.f;
  for (int i=b;i<e1;i++) s += expf(L[eid[i]] - mx);
  float dv = 1.f/(s+1e-16f);
  float c[10] = {0.f,0.f,0.f,0.f,0.f,0.f,0.f,0.f,0.f,0.f};
  for (int i=b;i<e1;i++){
    int e = eid[i];
    float w = expf(L[e]-mx)*dv;
    L[e] = w;
    #pragma unroll
    for (int k=0;k<10;k++) c[k] += w*ea[e*12+1+k];
  }
  float* cp = cw + (long)n*10;
  #pragma unroll
  for (int k=0;k<10;k++) cp[k] = c[k];
}

__global__ void k_gather3(const int* __restrict__ ei,
                          const int* __restrict__ iptr, const int* __restrict__ eid,
                          const float* __restrict__ L,      // holds w[e]
                          const float* __restrict__ cw,     // [NN][10]
                          const float* __restrict__ hg3,
                          const float* __restrict__ We, const float* __restrict__ lin3,
                          const float* __restrict__ cb, float* __restrict__ out){
  int n = blockIdx.x*256 + threadIdx.x;
  if (n >= NN) return;
  int b = iptr[n], en = iptr[n+1];
  const float* cp = cw + (long)n*10;
  float e0f=0.f, e1f=0.f;
  #pragma unroll
  for (int k=0;k<10;k++){ e0f += cp[k]*We[k*2]; e1f += cp[k]*We[k*2+1]; }
  float a0=0.f, a1=0.f;
  for (int i=b;i<en;i++){
    int e = eid[i], s_ = ei[e];
    float w = L[e];
    a0 += w*hg3[s_*2];
    a1 += w*hg3[s_*2+1];
  }
  out[n*2]   = fmaxf(lin3[n*2]  +a0+e0f+cb[0], 0.f);
  out[n*2+1] = fmaxf(lin3[n*2+1]+a1+e1f+cb[1], 0.f);
}

extern "C" void kernel_launch(void* const* d_in, const int* in_sizes, int n_in,
                              void* d_out, int out_size, void* d_ws, size_t ws_size,
                              hipStream_t stream){
  const int* ei = (const int*)d_in[1];

  long long sz[64];
  {
    const long long* s64 = (const long long*)(const void*)in_sizes;
    bool is64 = (n_in >= 2) && (in_sizes[0] == 3340000) && (in_sizes[1] == 0)
                && (s64[1] == 200000);
    for (int i=0;i<n_in && i<64;i++) sz[i] = is64 ? s64[i] : (long long)in_sizes[i];
  }

  int IWg[3], IWe[3], IAttn[3], IAt[3], ICb[3], ILw[3], ILb[3], IG[3], IB[3];
  if (n_in > 8 && sz[8] == (long long)HID*HID){ // setup_inputs() dict order
    for (int l=0;l<3;l++){
      IWg[l]=3+l*5; IWe[l]=4+l*5; IAttn[l]=5+l*5; IAt[l]=6+l*5; ICb[l]=7+l*5;
      ILw[l]=18+l*4; ILb[l]=19+l*4; IG[l]=20+l*4; IB[l]=21+l*4;
    }
  } else {
    int idx=3;
    for (int l=0;l<3;l++){
      IWg[l]=idx++; IWe[l]=idx++; IAttn[l]=idx++; IAt[l]=idx++; ICb[l]=idx++;
      ILw[l]=idx++; ILb[l]=idx++; IG[l]=idx++; IB[l]=idx++;
    }
  }
  #define FP(i) ((const float*)d_in[(i)])

  char* ws = (char*)d_ws;
  size_t off = 0;
  auto alloc = [&](size_t bytes)->void*{ void* p = ws + off; off += (bytes + 255) & ~(size_t)255; return p; };
  auto G = [](long n){ return (int)((n+255)/256); };

  u16*   buf0 = (u16*)  alloc((size_t)NN*HID*2);   // hg (bf16)
  u16*   bufA = (u16*)  alloc((size_t)NN*HID*2);   // layer-1 lin/result
  u16*   bufB = (u16*)  alloc((size_t)NN*HID*2);   // layer-2 lin/result
  u16*   xbf  = (u16*)  alloc((size_t)NN*KP1*2);   // layer-1 A (bf16, padded)
  u16*   Wt   = (u16*)  alloc((size_t)2*HID*HID*2);// fused folded weights [2048][K] K-major
  u16*   We16 = (u16*)  alloc((size_t)10*HID*2);
  float* cst  = (float*)alloc(2*HID*4);
  float* L    = (float*)alloc((size_t)EE*4*4);
  float* ssrc = (float*)alloc((size_t)NN*4*4);
  float* sdst = (float*)alloc((size_t)NN*4*4);
  int*   iptr = (int*)  alloc((size_t)(NN+4)*4);
  int*   cnts = (int*)  alloc((size_t)NN*4);
  int*   eid  = (int*)  alloc((size_t)EE*4);
  int*   bsum = (int*)  alloc(256*4);
  int*   boff = (int*)  alloc(256*4);
  float* stats= (float*)alloc(2*HID*4);
  float* scale= (float*)alloc(HID*4);
  float* shift= (float*)alloc(HID*4);
  float* qbuf = (float*)alloc(64*4);
  float* hg3  = (float*)alloc((size_t)NN*2*4);
  float* lin3 = (float*)alloc((size_t)NN*2*4);
  float* cw   = (float*)alloc((size_t)NN*40*4);    // factored edge-feature weights
  float* W4   = (float*)alloc((size_t)HID*4*4);    // layer-3 folded interleaved weights
  float* c4   = (float*)alloc(4*4);
  float* part = (float*)alloc((size_t)256*2048*4); // bnstats8 partials (2 MB)

  // ---- CSR by dst (two-level scan) ----
  int nsb = G(NN);   // 79 scan blocks
  hipMemsetAsync(cnts, 0, NN*sizeof(int), stream);
  k_count<<<G(EE),256,0,stream>>>(ei, cnts);
  k_scanA<<<nsb,256,0,stream>>>(cnts, iptr, bsum);
  k_scanB<<<1,128,0,stream>>>(bsum, boff, iptr+NN, nsb);
  k_scanC<<<nsb,256,0,stream>>>(boff, iptr);
  hipMemsetAsync(cnts, 0, NN*sizeof(int), stream);
  k_fill<<<G(EE),256,0,stream>>>(ei, iptr, cnts, eid);

  int gg = 1264;   // 79 row-tiles (256 rows) x 16 col-tiles (128 cols), XCD-swizzled in-kernel
  int gsd = (NN*4+3)/4;   // k_sdot: one wave per (n,h)

  // ---- layer 1 (A = bf16(x), Kp=192) ----
  {
    hipMemsetAsync(stats, 0, 2*FIN*sizeof(float), stream);
    dim3 bg(200, 1);
    k_bnstats<float><<<bg,256,0,stream>>>(FP(0), stats, FIN);
    k_bnfin<<<1,256,0,stream>>>(stats, FP(IG[0]), FP(IB[0]), scale, shift, FIN);
    k_cast<<<G((long)NN*KP1),256,0,stream>>>(FP(0), xbf);
    dim3 ft(KP1/32, 64);
    k_foldT<<<ft,256,0,stream>>>(FP(IWg[0]), FP(ILw[0]), scale, Wt, FIN, KP1);
    k_cinit<<<8,256,0,stream>>>(FP(ILb[0]), cst);
    dim3 cg(32, (FIN+127)/128);
    k_const<<<cg,256,0,stream>>>(FP(IWg[0]), FP(ILw[0]), shift, cst, FIN);
    k_we16<<<40,256,0,stream>>>(FP(IWe[0]), We16);
    k_gemm<<<gg,512,0,stream>>>(xbf, KP1, Wt, cst, buf0, bufA);
    k_sdot<<<gsd,256,0,stream>>>(buf0, FP(IAttn[0]), ssrc, sdst);
    k_q<<<1,64,0,stream>>>(FP(IWe[0]), FP(IAttn[0]), qbuf);
    k_logits<<<G(EE),256,0,stream>>>(ei, FP(2), qbuf, FP(IAt[0]), ssrc, sdst, L);
    k_mden<<<G(NN),256,0,stream>>>(iptr, eid, FP(2), L, cw);
    k_gath<<<(NN+NB-1)/NB,256,0,stream>>>(buf0, ei, iptr, eid, L, cw,
                                          We16, FP(ICb[0]), bufA);
  }
  // ---- layer 2 (A = bufA, K=1024) ----
  {
    k_bnstats8<<<256,256,0,stream>>>(bufA, part);
    k_pred<<<8,256,0,stream>>>(part, stats);
    k_bnfin<<<4,256,0,stream>>>(stats, FP(IG[1]), FP(IB[1]), scale, shift, HID);
    dim3 ft(HID/32, 64);
    k_foldT<<<ft,256,0,stream>>>(FP(IWg[1]), FP(ILw[1]), scale, Wt, HID, HID);
    k_cinit<<<8,256,0,stream>>>(FP(ILb[1]), cst);
    dim3 cg(32, HID/128);
    k_const<<<cg,256,0,stream>>>(FP(IWg[1]), FP(ILw[1]), shift, cst, HID);
    k_we16<<<40,256,0,stream>>>(FP(IWe[1]), We16);
    k_gemm<<<gg,512,0,stream>>>(bufA, HID, Wt, cst, buf0, bufB);
    k_sdot<<<gsd,256,0,stream>>>(buf0, FP(IAttn[1]), ssrc, sdst);
    k_q<<<1,64,0,stream>>>(FP(IWe[1]), FP(IAttn[1]), qbuf);
    k_logits<<<G(EE),256,0,stream>>>(ei, FP(2), qbuf, FP(IAt[1]), ssrc, sdst, L);
    k_mden<<<G(NN),256,0,stream>>>(iptr, eid, FP(2), L, cw);
    k_gath<<<(NN+NB-1)/NB,256,0,stream>>>(buf0, ei, iptr, eid, L, cw,
                                          We16, FP(ICb[1]), bufB);
  }

  // ---- layer 3 (input = bufB) ----
  k_bnstats8<<<256,256,0,stream>>>(bufB, part);
  k_pred<<<8,256,0,stream>>>(part, stats);
  k_bnfin<<<4,256,0,stream>>>(stats, FP(IG[2]), FP(IB[2]), scale, shift, HID);
  k_c4init<<<1,64,0,stream>>>(FP(ILb[2]), c4);
  k_fold3<<<HID/256,256,0,stream>>>(FP(IWg[2]), FP(ILw[2]), scale, shift, W4, c4);
  k_n3<<<NN/4,256,0,stream>>>(bufB, W4, c4, FP(IAttn[2]), hg3, lin3, ssrc, sdst);
  k_logits3<<<G(EE),256,0,stream>>>(ei, FP(2), FP(IWe[2]), FP(IAttn[2]), FP(IAt[2]), ssrc, sdst, L);
  k_mden3<<<G(NN),256,0,stream>>>(iptr, eid, FP(2), L, cw);
  k_gather3<<<G(NN),256,0,stream>>>(ei, iptr, eid, L, cw, hg3,
                                    FP(IWe[2]), lin3, FP(ICb[2]), (float*)d_out);
}

// Round 13
// 732.347 us; speedup vs baseline: 1.7076x; 1.0374x over previous
//
#include <hip/hip_runtime.h>
#include <math.h>

#define NN 20000
#define EE 100000
#define FIN 167
#define KP1 192    // layer-1 K padded to mult of 64
#define HID 1024   // H*O = 4*256
#define OO 256
#define NB 8       // nodes per k_gath block

typedef unsigned short u16;
typedef short bf16x8 __attribute__((ext_vector_type(8)));
typedef short s16x4  __attribute__((ext_vector_type(4)));
typedef float f32x4  __attribute__((ext_vector_type(4)));

__device__ __forceinline__ float bf(u16 u){ return __uint_as_float(((unsigned)u)<<16); }
__device__ __forceinline__ u16 fb(float v){            // f32 -> bf16 RNE
  unsigned u = __float_as_uint(v);
  return (u16)((u + 0x7FFFu + ((u>>16)&1u)) >> 16);
}
__device__ __forceinline__ float ldv(const float* p, long i){ return p[i]; }
__device__ __forceinline__ float ldv(const u16*   p, long i){ return bf(p[i]); }

// ---------------- CSR build ----------------
__global__ void k_count(const int* __restrict__ ei, int* __restrict__ counts){
  int e = blockIdx.x*256 + threadIdx.x;
  if (e < EE) atomicAdd(&counts[ei[EE+e]], 1);
}

// two-level scan
__global__ __launch_bounds__(256) void k_scanA(const int* __restrict__ counts,
                                               int* __restrict__ iptr, int* __restrict__ bsum){
  __shared__ int sd[256];
  int b = blockIdx.x, tid = threadIdx.x;
  int i = b*256 + tid;
  int v = (i<NN)? counts[i] : 0;
  sd[tid]=v; __syncthreads();
  for (int off=1; off<256; off<<=1){
    int t = (tid>=off)? sd[tid-off] : 0;
    __syncthreads();
    sd[tid] += t;
    __syncthreads();
  }
  if (i<NN) iptr[i] = sd[tid]-v;     // block-local exclusive
  if (tid==255) bsum[b]=sd[255];
}
__global__ __launch_bounds__(128) void k_scanB(const int* __restrict__ bsum,
                                               int* __restrict__ boff, int* __restrict__ iptrN,
                                               int nb){
  __shared__ int sd[128];
  int tid=threadIdx.x;
  int v=(tid<nb)? bsum[tid]:0;
  sd[tid]=v; __syncthreads();
  for (int off=1; off<128; off<<=1){
    int t=(tid>=off)?sd[tid-off]:0;
    __syncthreads();
    sd[tid]+=t;
    __syncthreads();
  }
  if (tid<nb) boff[tid]=sd[tid]-v;
  if (tid==127) *iptrN = sd[127];
}
__global__ void k_scanC(const int* __restrict__ boff, int* __restrict__ iptr){
  int i = blockIdx.x*256+threadIdx.x;
  if (i<NN) iptr[i] += boff[blockIdx.x];
}

__global__ void k_fill(const int* __restrict__ ei, const int* __restrict__ iptr,
                       int* __restrict__ cursor, int* __restrict__ eid){
  int e = blockIdx.x*256 + threadIdx.x;
  if (e < EE){
    int d = ei[EE+e];
    int pos = atomicAdd(&cursor[d],1);
    eid[iptr[d]+pos] = e;
  }
}

// ---------------- BatchNorm stats ----------------
// layer-1 (float input, F=167)
template<typename T>
__global__ void k_bnstats(const T* __restrict__ X, float* __restrict__ sums, int F){
  int f = blockIdx.y*256 + threadIdx.x;
  if (f >= F) return;
  int r0 = blockIdx.x*100, r1 = r0+100;
  float s=0.f, s2=0.f;
  for (int r=r0;r<r1;r++){ float v = ldv(X,(long)r*F+f); s += v; s2 += v*v; }
  atomicAdd(&sums[f], s);
  atomicAdd(&sums[F+f], s2);
}

// layers 2/3 (bf16, F=HID) stage A: zero-atomic partials
__global__ __launch_bounds__(256) void k_bnstats8(const u16* __restrict__ X, float* __restrict__ part){
  int tid = threadIdx.x;
  int f8 = (tid & 127)*8;
  int r0 = blockIdx.x*79, r1 = min(NN, r0+79);     // grid 256
  float s[8]={0,0,0,0,0,0,0,0}, s2[8]={0,0,0,0,0,0,0,0};
  for (int r=r0 + (tid>>7); r<r1; r+=2){
    bf16x8 v = *(const bf16x8*)(X + (long)r*HID + f8);
    #pragma unroll
    for (int j=0;j<8;j++){ float x=bf((u16)v[j]); s[j]+=x; s2[j]+=x*x; }
  }
  __shared__ float red[256][8];
  float* pb = part + (long)blockIdx.x*2048;
  #pragma unroll
  for (int j=0;j<8;j++) red[tid][j]=s[j];
  __syncthreads();
  if (tid<128){
    #pragma unroll
    for (int j=0;j<8;j++) pb[f8+j] = red[tid][j]+red[tid+128][j];
  }
  __syncthreads();
  #pragma unroll
  for (int j=0;j<8;j++) red[tid][j]=s2[j];
  __syncthreads();
  if (tid<128){
    #pragma unroll
    for (int j=0;j<8;j++) pb[1024+f8+j] = red[tid][j]+red[tid+128][j];
  }
}

// stage B: reduce 256 partials -> sums[2048]
__global__ __launch_bounds__(256) void k_pred(const float* __restrict__ part, float* __restrict__ sums){
  int idx = blockIdx.x*256 + threadIdx.x;   // grid 8 -> 2048 threads
  float s = 0.f;
  #pragma unroll 8
  for (int b=0;b<256;b++) s += part[(long)b*2048 + idx];
  sums[idx] = s;
}

__global__ void k_bnfin(const float* __restrict__ sums, const float* __restrict__ g,
                        const float* __restrict__ b, float* __restrict__ scale,
                        float* __restrict__ shift, int F){
  int f = blockIdx.x*256 + threadIdx.x;
  if (f >= F) return;
  float mu  = sums[f]   * (1.f/NN);
  float var = sums[F+f] * (1.f/NN) - mu*mu;
  float sc  = rsqrtf(var + 1e-5f) * g[f];
  scale[f] = sc;
  shift[f] = b[f] - mu*sc;
}

// ---------------- BN-folded fused weight prep ----------------
__global__ __launch_bounds__(256) void k_foldT(const float* __restrict__ Wg, const float* __restrict__ Wl,
                        const float* __restrict__ scale,
                        u16* __restrict__ Wt, int K, int Kp){
  __shared__ float t[32][33];
  int k0 = blockIdx.x*32, c0 = blockIdx.y*32;
  int tx = threadIdx.x & 31, ty = threadIdx.x >> 5;
  bool second = (c0 >= HID);
  const float* W = second ? Wl : Wg;
  int cc0 = second ? c0 - HID : c0;
  #pragma unroll
  for (int i=0;i<4;i++){
    int k = k0 + ty + i*8;
    t[ty+i*8][tx] = (k < K) ? W[(long)k*HID + cc0 + tx] * scale[k] : 0.f;
  }
  __syncthreads();
  #pragma unroll
  for (int i=0;i<4;i++){
    int c = c0 + ty + i*8;
    Wt[(long)c*Kp + k0 + tx] = fb(t[tx][ty+i*8]);
  }
}

// cst init: lb for lin half, 0 for hg half
__global__ void k_cinit(const float* __restrict__ lb, float* __restrict__ cst){
  int c = blockIdx.x*256 + threadIdx.x;
  if (c < 2*HID) cst[c] = (c >= HID) ? lb[c-HID] : 0.f;
}

// cst[c] += sum_k shift[k]*W[k][c]
__global__ __launch_bounds__(256) void k_const(const float* __restrict__ Wg, const float* __restrict__ Wl,
                        const float* __restrict__ shift, float* __restrict__ cst, int K){
  int tx = threadIdx.x & 63, ty = threadIdx.x >> 6;
  int c = blockIdx.x*64 + tx;
  bool second = c >= HID;
  const float* W = second ? Wl : Wg;
  int cc = second ? c-HID : c;
  int k0 = blockIdx.y*128;
  int k1 = min(K, k0+128);
  float s = 0.f;
  for (int k=k0+ty; k<k1; k+=4) s += shift[k]*W[(long)k*HID+cc];
  __shared__ float red[256];
  red[threadIdx.x] = s;
  __syncthreads();
  if (ty == 0){
    float tot = red[tx] + red[tx+64] + red[tx+128] + red[tx+192];
    atomicAdd(&cst[c], tot);
  }
}

__global__ void k_cast(const float* __restrict__ x, u16* __restrict__ xb){
  long idx = (long)blockIdx.x*256 + threadIdx.x;
  if (idx >= (long)NN*KP1) return;
  int n = (int)(idx / KP1), k = (int)(idx % KP1);
  xb[idx] = (k<FIN)? fb(x[(long)n*FIN+k]) : (u16)0;
}

__global__ void k_we16(const float* __restrict__ We, u16* __restrict__ We16){
  int i = blockIdx.x*256 + threadIdx.x;
  if (i < 10*HID) We16[i] = fb(We[i]);
}

// ---------------- MFMA GEMM v6 (setprio removed: r12 A/B showed it -1.7% on this structure) ----------------
#define MF(a_,b_,c_) __builtin_amdgcn_mfma_f32_16x16x32_bf16(a_,b_,c_,0,0,0)
#define FENCE asm volatile("" ::: "memory")
#define BAR do { FENCE; __builtin_amdgcn_s_barrier(); FENCE; } while(0)

__global__ __launch_bounds__(512,2) void k_gemm(const u16* __restrict__ A, int K,
                     const u16* __restrict__ Wt, const float* __restrict__ cst,
                     u16* __restrict__ Chg, u16* __restrict__ Clin){
  __shared__ u16 lds[3][12288];   // 3 x (A 8192 u16 | B 4096 u16) = 72 KB -> 2 blocks/CU
  int b = blockIdx.x;
  int wg = (b & 7)*158 + (b >> 3);          // 1264 % 8 == 0 -> bijective XCD swizzle
  int row0 = (wg >> 4)*256, col0 = (wg & 15)*128;
  int tid = threadIdx.x;
  int wave = tid >> 6, lane = tid & 63, quad = lane >> 4, lo = lane & 15;
  int wm = wave >> 1, wn = wave & 1;        // 4 M-waves x 2 N-waves, 64x64 out each
  const u16* Apt[2];
  #pragma unroll
  for (int i=0;i<2;i++){
    int s = i*512 + tid, srow = s>>2;
    int gr = row0 + srow; if (gr >= NN) gr = NN-1;      // clamp: garbage rows never stored
    Apt[i] = A + (long)gr*K + (((s&3)^((srow>>1)&3))*8);
  }
  int brow = tid>>2;
  const u16* Bpt = Wt + (long)(col0 + brow)*K + ((((tid&3)^((brow>>1)&3)))*8);
  const char* ldsc = (const char*)&lds[0][0];
  int axor = (lo>>1) & 3;
  int aoff = (wm*64 + lo)*64 + ((quad^axor)*16);            // A frag i at +i*1024 B
  int boff = 16384 + (wn*64 + lo)*64 + ((quad^axor)*16);    // B frag n at +n*1024 B
  int NT = K >> 5;
  f32x4 acc[4][4] = {};
  // ---- prologue: stage tiles 0,1 into buffers 0,1 ----
  {
    u16* d0 = (u16*)&lds[0][0];
    u16* d1 = (u16*)&lds[1][0];
    __builtin_amdgcn_global_load_lds(Apt[0],      d0 +         tid*8, 16, 0, 0);
    __builtin_amdgcn_global_load_lds(Apt[1],      d0 + 4096 +  tid*8, 16, 0, 0);
    __builtin_amdgcn_global_load_lds(Bpt,         d0 + 8192 +  tid*8, 16, 0, 0);
    __builtin_amdgcn_global_load_lds(Apt[0] + 32, d1 +         tid*8, 16, 0, 0);
    __builtin_amdgcn_global_load_lds(Apt[1] + 32, d1 + 4096 +  tid*8, 16, 0, 0);
    __builtin_amdgcn_global_load_lds(Bpt    + 32, d1 + 8192 +  tid*8, 16, 0, 0);
    asm volatile("s_waitcnt vmcnt(3)" ::: "memory");   // tile-0 panels landed
    BAR;
  }
  int cb = 0;
  for (int t=0; t<NT; t++){
    const char* Lb = ldsc + cb*24576;
    bf16x8 af[4], bfr[4];
    #pragma unroll
    for (int i=0;i<4;i++) af[i]  = *(const bf16x8*)(Lb + aoff + i*1024);
    #pragma unroll
    for (int n=0;n<4;n++) bfr[n] = *(const bf16x8*)(Lb + boff + n*1024);
    int nx2 = (t+2 < NT);
    if (nx2){
      int sb = cb+2; if (sb>=3) sb-=3;       // buffer holding tile t-1 (consumed, barrier-safe)
      u16* Sd = (u16*)&lds[0][0] + sb*12288;
      int ko = (t+2) << 5;
      __builtin_amdgcn_global_load_lds(Apt[0] + ko, Sd +         tid*8, 16, 0, 0);
      __builtin_amdgcn_global_load_lds(Apt[1] + ko, Sd + 4096 +  tid*8, 16, 0, 0);
      __builtin_amdgcn_global_load_lds(Bpt    + ko, Sd + 8192 +  tid*8, 16, 0, 0);
    }
    #pragma unroll
    for (int i=0;i<4;i++)
      #pragma unroll
      for (int n=0;n<4;n++)
        acc[i][n] = MF(af[i], bfr[n], acc[i][n]);
    if (t+1 < NT){
      if (nx2) asm volatile("s_waitcnt vmcnt(3)" ::: "memory");  // tile t+1 landed
      else     asm volatile("s_waitcnt vmcnt(0)" ::: "memory");  // tail (once)
      BAR;
    }
    cb++; if (cb>=3) cb=0;
  }
  // ---- epilogue (verified mapping) ----
  #pragma unroll
  for (int i=0;i<4;i++){
    #pragma unroll
    for (int n=0;n<4;n++){
      int col = col0 + wn*64 + n*16 + lo;
      float cs = cst[col];
      #pragma unroll
      for (int r=0;r<4;r++){
        int row = row0 + wm*64 + i*16 + quad*4 + r;   // C/D: col=lane&15, row=quad*4+reg
        if (row < NN){
          u16 o = fb(acc[i][n][r] + cs);
          if (col < HID) Chg[(long)row*HID + col] = o;
          else           Clin[(long)row*HID + col - HID] = o;
        }
      }
    }
  }
}
#undef MF
#undef BAR
#undef FENCE

// ---------------- per-(node,head) attention dots: wave-parallel, coalesced ----------------
__global__ __launch_bounds__(256) void k_sdot(const u16* __restrict__ hg, const float* __restrict__ attn,
                       float* __restrict__ ssrc, float* __restrict__ sdst){
  int unit = blockIdx.x*4 + (threadIdx.x >> 6);   // one wave per (n,h)
  if (unit >= NN*4) return;
  int lane = threadIdx.x & 63;
  int n = unit >> 2, h = unit & 3;
  const u16* hp = hg + (long)n*HID + h*OO + lane*4;
  s16x4 v = *(const s16x4*)hp;
  float4 x0 = *(const float4*)(attn + h*OO + lane*4);
  float4 x1 = *(const float4*)(attn + HID + h*OO + lane*4);
  float f0 = bf((u16)v.x), f1 = bf((u16)v.y), f2 = bf((u16)v.z), f3 = bf((u16)v.w);
  float ss = f0*x0.x + f1*x0.y + f2*x0.z + f3*x0.w;
  float sd = f0*x1.x + f1*x1.y + f2*x1.z + f3*x1.w;
  #pragma unroll
  for (int off=32; off>0; off>>=1){
    ss += __shfl_down(ss, off);
    sd += __shfl_down(sd, off);
  }
  if (lane==0){ ssrc[unit]=ss; sdst[unit]=sd; }
}

__global__ void k_q(const float* __restrict__ We, const float* __restrict__ attn,
                    float* __restrict__ q){
  int t = threadIdx.x;
  if (t >= 40) return;
  int k = t >> 2, h = t & 3;
  float s = 0.f;
  for (int d=0; d<OO; d++) s += We[(long)k*HID + h*OO + d] * attn[2*HID + h*OO + d];
  q[k*4+h] = s;
}

// per-EDGE logits: ea read once, all 4 heads computed, float4 write
__global__ void k_logits(const int* __restrict__ ei, const float* __restrict__ ea,
                         const float* __restrict__ q, const float* __restrict__ at,
                         const float* __restrict__ ssrc, const float* __restrict__ sdst,
                         float* __restrict__ L){
  int e = blockIdx.x*256 + threadIdx.x;
  if (e >= EE) return;
  int s = ei[e], dd = ei[EE+e];
  float4 a0 = *(const float4*)(ea + (long)e*12);
  float4 a1 = *(const float4*)(ea + (long)e*12 + 4);
  float4 a2 = *(const float4*)(ea + (long)e*12 + 8);
  float t = a0.x;
  float cc[10] = {a0.y,a0.z,a0.w, a1.x,a1.y,a1.z,a1.w, a2.x,a2.y,a2.z};
  float4 ss = *(const float4*)(ssrc + (long)s*4);
  float4 sd = *(const float4*)(sdst + (long)dd*4);
  float sv[4] = {ss.x+sd.x, ss.y+sd.y, ss.z+sd.z, ss.w+sd.w};
  float4 out;
  #pragma unroll
  for (int h=0;h<4;h++){
    float se = 0.f;
    #pragma unroll
    for (int k=0;k<10;k++) se += cc[k]*q[k*4+h];
    float v = sv[h] + se + t*at[h];
    ((float*)&out)[h] = (v>0.f)? v : 0.2f*v;
  }
  *(float4*)(L + (long)e*4) = out;
}

// softmax finalize v2: TWO passes (max; exp+sum+cw). Stores UNNORMALIZED p in L,
// folds dinv into cw at write, emits dv4[n][4] for k_gath to apply once per node.
// (was 3 passes; removes one full random-edge pass. 128-thr blocks: 157 blocks
//  spread over CUs vs 79 — latency-bound kernel, G11.)
__global__ __launch_bounds__(128) void k_mden(const int* __restrict__ iptr, const int* __restrict__ eid,
                       const float* __restrict__ ea, float* __restrict__ L,
                       float* __restrict__ cw, float* __restrict__ dv4){
  int n = blockIdx.x*128 + threadIdx.x;
  if (n >= NN) return;
  int b = iptr[n], e1 = iptr[n+1];
  float m0=-INFINITY, m1=-INFINITY, m2=-INFINITY, m3=-INFINITY;
  for (int i=b;i<e1;i++){
    float4 l = *(const float4*)(L + (long)eid[i]*4);
    m0=fmaxf(m0,l.x); m1=fmaxf(m1,l.y); m2=fmaxf(m2,l.z); m3=fmaxf(m3,l.w);
  }
  if (b==e1){ m0=m1=m2=m3=0.f; }
  float s0=0.f,s1=0.f,s2=0.f,s3=0.f;
  float c[4][10] = {};
  for (int i=b;i<e1;i++){
    int e = eid[i];
    float4 l = *(const float4*)(L + (long)e*4);
    float4 p = { expf(l.x-m0), expf(l.y-m1), expf(l.z-m2), expf(l.w-m3) };
    *(float4*)(L + (long)e*4) = p;
    s0+=p.x; s1+=p.y; s2+=p.z; s3+=p.w;
    float4 a0 = *(const float4*)(ea + (long)e*12);
    float4 a1 = *(const float4*)(ea + (long)e*12 + 4);
    float4 a2 = *(const float4*)(ea + (long)e*12 + 8);
    float cc[10] = {a0.y,a0.z,a0.w, a1.x,a1.y,a1.z,a1.w, a2.x,a2.y,a2.z};
    #pragma unroll
    for (int k=0;k<10;k++){
      c[0][k] += p.x*cc[k]; c[1][k] += p.y*cc[k];
      c[2][k] += p.z*cc[k]; c[3][k] += p.w*cc[k];
    }
  }
  float d0=1.f/(s0+1e-16f), d1=1.f/(s1+1e-16f), d2=1.f/(s2+1e-16f), d3=1.f/(s3+1e-16f);
  float* cp = cw + (long)n*40;
  #pragma unroll
  for (int k=0;k<10;k++){
    cp[k]    = c[0][k]*d0;
    cp[10+k] = c[1][k]*d1;
    cp[20+k] = c[2][k]*d2;
    cp[30+k] = c[3][k]*d3;
  }
  float4 dv = {d0,d1,d2,d3};
  *(float4*)(dv4 + (long)n*4) = dv;
}

// ---------------- edge gather: 8B/lane + 2-deep prefetch + deferred dinv ----------------
__global__ __launch_bounds__(256) void k_gath(
    const u16* __restrict__ hg, const int* __restrict__ ei,
    const int* __restrict__ iptr, const int* __restrict__ eid,
    const float* __restrict__ L,      // holds UNNORMALIZED p[e][h]
    const float* __restrict__ cw,     // [NN][4][10] (dinv-folded)
    const float* __restrict__ dv4,    // [NN][4]
    const u16* __restrict__ We16, const float* __restrict__ cb,
    u16* __restrict__ lio)
{
  __shared__ u16  sWe[10*HID];   // 20 KB
  __shared__ float scb[HID];     // 4 KB
  int tid = threadIdx.x;
  for (int i=tid;i<10*HID;i+=256) sWe[i] = We16[i];
  for (int i=tid;i<HID;i+=256) scb[i] = cb[i];
  __syncthreads();
  int h = tid >> 6;
  int f0 = tid*4;
  int d0 = blockIdx.x*NB, dend = min(NN, d0+NB);
  for (int d=d0; d<dend; d++){
    s16x4 a0 = *(const s16x4*)(lio + (long)d*HID + f0);
    float acc0=bf((u16)a0.x), acc1=bf((u16)a0.y), acc2=bf((u16)a0.z), acc3=bf((u16)a0.w);
    float gt0=0.f, gt1=0.f, gt2=0.f, gt3=0.f;
    float dv = dv4[(long)d*4 + h];                     // wave-uniform broadcast
    int b0 = iptr[d], en = iptr[d+1];
    float wN = 0.f; s16x4 vN = {};
    if (b0 < en){
      int e = eid[b0], s_ = ei[e];
      wN = L[(long)e*4 + h];
      vN = *(const s16x4*)(hg + (long)s_*HID + f0);
    }
    for (int i=b0;i<en;i++){
      float w = wN; s16x4 v = vN;
      if (i+1 < en){
        int e2 = eid[i+1], s2 = ei[e2];
        wN = L[(long)e2*4 + h];
        vN = *(const s16x4*)(hg + (long)s2*HID + f0);
      }
      gt0 += w*bf((u16)v.x); gt1 += w*bf((u16)v.y);
      gt2 += w*bf((u16)v.z); gt3 += w*bf((u16)v.w);
    }
    acc0 += dv*gt0; acc1 += dv*gt1; acc2 += dv*gt2; acc3 += dv*gt3;
    const float* cp = cw + (long)d*40 + h*10;
    float ew0=0.f, ew1=0.f, ew2=0.f, ew3=0.f;
    #pragma unroll
    for (int k=0;k<10;k++){
      float c = cp[k];
      s16x4 wv = *(const s16x4*)(sWe + k*HID + f0);
      ew0 += c*bf((u16)wv.x); ew1 += c*bf((u16)wv.y);
      ew2 += c*bf((u16)wv.z); ew3 += c*bf((u16)wv.w);
    }
    acc0 += ew0; acc1 += ew1; acc2 += ew2; acc3 += ew3;
    u16 o[4];
    o[0] = fb(fmaxf(acc0 + scb[f0  ], 0.f));
    o[1] = fb(fmaxf(acc1 + scb[f0+1], 0.f));
    o[2] = fb(fmaxf(acc2 + scb[f0+2], 0.f));
    o[3] = fb(fmaxf(acc3 + scb[f0+3], 0.f));
    *(s16x4*)(lio + (long)d*HID + f0) = *(const s16x4*)o;
  }
}

// ---------------- layer 3 ----------------
__global__ void k_c4init(const float* __restrict__ lb, float* __restrict__ c4){
  if (threadIdx.x==0 && blockIdx.x==0){ c4[0]=0.f; c4[1]=0.f; c4[2]=lb[0]; c4[3]=lb[1]; }
}

// fold BN scale into interleaved weights W4[k][4] = {Wg0,Wg1,lw0,lw1}*sc; shift -> c4
__global__ __launch_bounds__(256) void k_fold3(const float* __restrict__ Wg, const float* __restrict__ lw,
                        const float* __restrict__ scale, const float* __restrict__ shift,
                        float* __restrict__ W4, float* __restrict__ c4){
  int k = blockIdx.x*256 + threadIdx.x;   // grid 4, covers HID exactly
  float sc = scale[k], sh = shift[k];
  float w0=Wg[k*2], w1=Wg[k*2+1], l0=lw[k*2], l1=lw[k*2+1];
  float4 o = {w0*sc, w1*sc, l0*sc, l1*sc};
  *(float4*)(W4 + (long)k*4) = o;
  __shared__ float red[256][4];
  int tid = threadIdx.x;
  red[tid][0]=sh*w0; red[tid][1]=sh*w1; red[tid][2]=sh*l0; red[tid][3]=sh*l1;
  __syncthreads();
  for (int o2=128;o2>0;o2>>=1){
    if (tid<o2){
      #pragma unroll
      for (int j=0;j<4;j++) red[tid][j]+=red[tid+o2][j];
    }
    __syncthreads();
  }
  if (tid==0){
    #pragma unroll
    for (int j=0;j<4;j++) atomicAdd(&c4[j], red[0][j]);
  }
}

// wave-per-node GEMV: x-rows and W4 staged in LDS, shuffle reduce
__global__ __launch_bounds__(256) void k_n3(const u16* __restrict__ in,
    const float* __restrict__ W4, const float* __restrict__ c4,
    const float* __restrict__ attn,
    float* __restrict__ hg3, float* __restrict__ lin3,
    float* __restrict__ ssrc, float* __restrict__ sdst)
{
  __shared__ float sW[HID*4];   // 16 KB
  __shared__ float sx[4][HID];  // 16 KB
  int tid = threadIdx.x;
  int n0 = blockIdx.x*4;        // grid 5000 exact
  for (int i=tid; i<HID; i+=256) *(float4*)&sW[i*4] = *(const float4*)(W4 + (long)i*4);
  for (int idx=tid; idx<512; idx+=256){
    int rr = idx>>7, ch = idx&127;
    bf16x8 v = *(const bf16x8*)(in + (long)(n0+rr)*HID + ch*8);
    #pragma unroll
    for (int j=0;j<8;j++) sx[rr][ch*8+j] = bf((u16)v[j]);
  }
  __syncthreads();
  int w = tid>>6, lane = tid&63;
  float p0=0.f,p1=0.f,p2=0.f,p3=0.f;
  #pragma unroll
  for (int g=0; g<16; g++){
    int k = g*64 + lane;                      // lanes consecutive -> conflict-free
    float x = sx[w][k];
    float4 wv = *(const float4*)&sW[k*4];
    p0 += x*wv.x; p1 += x*wv.y; p2 += x*wv.z; p3 += x*wv.w;
  }
  #pragma unroll
  for (int off=32; off>0; off>>=1){
    p0 += __shfl_down(p0, off);
    p1 += __shfl_down(p1, off);
    p2 += __shfl_down(p2, off);
    p3 += __shfl_down(p3, off);
  }
  if (lane==0){
    int n = n0 + w;
    float r0=p0+c4[0], r1=p1+c4[1], r2=p2+c4[2], r3=p3+c4[3];
    hg3[n*2]=r0; hg3[n*2+1]=r1;
    lin3[n*2]=r2; lin3[n*2+1]=r3;
    ssrc[n]=r0*attn[0]+r1*attn[1];
    sdst[n]=r0*attn[2]+r1*attn[3];
  }
}

__global__ void k_logits3(const int* __restrict__ ei, const float* __restrict__ ea,
                          const float* __restrict__ We, const float* __restrict__ attn,
                          const float* __restrict__ at, const float* __restrict__ ssrc,
                          const float* __restrict__ sdst, float* __restrict__ L){
  int e = blockIdx.x*256 + threadIdx.x;
  if (e >= EE) return;
  int s = ei[e], d = ei[EE+e];
  float e0=0.f, e1=0.f;
  #pragma unroll
  for (int k=0;k<10;k++){
    float c = ea[e*12+1+k];
    e0 += c*We[k*2]; e1 += c*We[k*2+1];
  }
  float se = e0*attn[4] + e1*attn[5];
  float v = ssrc[s] + sdst[d] + se + ea[e*12]*at[0];
  L[e] = (v>0.f)? v : 0.2f*v;
}

// layer-3 softmax finalize v2: 2-pass, unnormalized p in L, dinv folded into cw, dv out
__global__ __launch_bounds__(128) void k_mden3(const int* __restrict__ iptr, const int* __restrict__ eid,
                        const float* __restrict__ ea, float* __restrict__ L,
                        float* __restrict__ cw, float* __restrict__ dvn){
  int n = blockIdx.x*128 + threadIdx.x;
  if (n >= NN) return;
  int b = iptr[n], e1 = iptr[n+1];
  float mx = -INFINITY;
  for (int i=b;i<e1;i++) mx = fmaxf(mx, L[eid[i]]);
  if (b == e1) mx = 0.f;
  float s = 0.f;
  float c[10] = {0.f,0.f,0.f,0.f,0.f,0.f,0.f,0.f,0.f,0.f};
  for (int i=b;i<e1;i++){
    int e = eid[i];
    float p = expf(L[e]-mx);
    L[e] = p;
    s += p;
    #pragma unroll
    for (int k=0;k<10;k++) c[k] += p*ea[e*12+1+k];
  }
  float dv = 1.f/(s+1e-16f);
  float* cp = cw + (long)n*10;
  #pragma unroll
  for (int k=0;k<10;k++) cp[k] = c[k]*dv;
  dvn[n] = dv;
}

__global__ __launch_bounds__(128) void k_gather3(const int* __restrict__ ei,
                          const int* __restrict__ iptr, const int* __restrict__ eid,
                          const float* __restrict__ L,      // holds unnormalized p[e]
                          const float* __restrict__ cw,     // [NN][10] (dinv-folded)
                          const float* __restrict__ dvn,    // [NN]
                          const float* __restrict__ hg3,
                          const float* __restrict__ We, const float* __restrict__ lin3,
                          const float* __restrict__ cb, float* __restrict__ out){
  int n = blockIdx.x*128 + threadIdx.x;
  if (n >= NN) return;
  int b = iptr[n], en = iptr[n+1];
  const float* cp = cw + (long)n*10;
  float e0f=0.f, e1f=0.f;
  #pragma unroll
  for (int k=0;k<10;k++){ e0f += cp[k]*We[k*2]; e1f += cp[k]*We[k*2+1]; }
  float a0=0.f, a1=0.f;
  for (int i=b;i<en;i++){
    int e = eid[i], s_ = ei[e];
    float w = L[e];
    a0 += w*hg3[s_*2];
    a1 += w*hg3[s_*2+1];
  }
  float dv = dvn[n];
  out[n*2]   = fmaxf(lin3[n*2]  +dv*a0+e0f+cb[0], 0.f);
  out[n*2+1] = fmaxf(lin3[n*2+1]+dv*a1+e1f+cb[1], 0.f);
}

extern "C" void kernel_launch(void* const* d_in, const int* in_sizes, int n_in,
                              void* d_out, int out_size, void* d_ws, size_t ws_size,
                              hipStream_t stream){
  const int* ei = (const int*)d_in[1];

  long long sz[64];
  {
    const long long* s64 = (const long long*)(const void*)in_sizes;
    bool is64 = (n_in >= 2) && (in_sizes[0] == 3340000) && (in_sizes[1] == 0)
                && (s64[1] == 200000);
    for (int i=0;i<n_in && i<64;i++) sz[i] = is64 ? s64[i] : (long long)in_sizes[i];
  }

  int IWg[3], IWe[3], IAttn[3], IAt[3], ICb[3], ILw[3], ILb[3], IG[3], IB[3];
  if (n_in > 8 && sz[8] == (long long)HID*HID){ // setup_inputs() dict order
    for (int l=0;l<3;l++){
      IWg[l]=3+l*5; IWe[l]=4+l*5; IAttn[l]=5+l*5; IAt[l]=6+l*5; ICb[l]=7+l*5;
      ILw[l]=18+l*4; ILb[l]=19+l*4; IG[l]=20+l*4; IB[l]=21+l*4;
    }
  } else {
    int idx=3;
    for (int l=0;l<3;l++){
      IWg[l]=idx++; IWe[l]=idx++; IAttn[l]=idx++; IAt[l]=idx++; ICb[l]=idx++;
      ILw[l]=idx++; ILb[l]=idx++; IG[l]=idx++; IB[l]=idx++;
    }
  }
  #define FP(i) ((const float*)d_in[(i)])

  char* ws = (char*)d_ws;
  size_t off = 0;
  auto alloc = [&](size_t bytes)->void*{ void* p = ws + off; off += (bytes + 255) & ~(size_t)255; return p; };
  auto G = [](long n){ return (int)((n+255)/256); };

  u16*   buf0 = (u16*)  alloc((size_t)NN*HID*2);   // hg (bf16)
  u16*   bufA = (u16*)  alloc((size_t)NN*HID*2);   // layer-1 lin/result
  u16*   bufB = (u16*)  alloc((size_t)NN*HID*2);   // layer-2 lin/result
  u16*   xbf  = (u16*)  alloc((size_t)NN*KP1*2);   // layer-1 A (bf16, padded)
  u16*   Wt   = (u16*)  alloc((size_t)2*HID*HID*2);// fused folded weights [2048][K] K-major
  u16*   We16 = (u16*)  alloc((size_t)10*HID*2);
  float* cst  = (float*)alloc(2*HID*4);
  float* L    = (float*)alloc((size_t)EE*4*4);
  float* ssrc = (float*)alloc((size_t)NN*4*4);
  float* sdst = (float*)alloc((size_t)NN*4*4);
  float* dv4  = (float*)alloc((size_t)NN*4*4);     // deferred softmax denominators
  int*   iptr = (int*)  alloc((size_t)(NN+4)*4);
  int*   cnts = (int*)  alloc((size_t)NN*4);
  int*   eid  = (int*)  alloc((size_t)EE*4);
  int*   bsum = (int*)  alloc(256*4);
  int*   boff = (int*)  alloc(256*4);
  float* stats= (float*)alloc(2*HID*4);
  float* scale= (float*)alloc(HID*4);
  float* shift= (float*)alloc(HID*4);
  float* qbuf = (float*)alloc(64*4);
  float* hg3  = (float*)alloc((size_t)NN*2*4);
  float* lin3 = (float*)alloc((size_t)NN*2*4);
  float* cw   = (float*)alloc((size_t)NN*40*4);    // factored edge-feature weights
  float* W4   = (float*)alloc((size_t)HID*4*4);    // layer-3 folded interleaved weights
  float* c4   = (float*)alloc(4*4);
  float* part = (float*)alloc((size_t)256*2048*4); // bnstats8 partials (2 MB)

  // ---- CSR by dst (two-level scan) ----
  int nsb = G(NN);   // 79 scan blocks
  hipMemsetAsync(cnts, 0, NN*sizeof(int), stream);
  k_count<<<G(EE),256,0,stream>>>(ei, cnts);
  k_scanA<<<nsb,256,0,stream>>>(cnts, iptr, bsum);
  k_scanB<<<1,128,0,stream>>>(bsum, boff, iptr+NN, nsb);
  k_scanC<<<nsb,256,0,stream>>>(boff, iptr);
  hipMemsetAsync(cnts, 0, NN*sizeof(int), stream);
  k_fill<<<G(EE),256,0,stream>>>(ei, iptr, cnts, eid);

  int gg = 1264;   // 79 row-tiles (256 rows) x 16 col-tiles (128 cols), XCD-swizzled in-kernel
  int gsd = (NN*4+3)/4;     // k_sdot: one wave per (n,h)
  int gnd = (NN+127)/128;   // 128-thr node-parallel kernels

  // ---- layer 1 (A = bf16(x), Kp=192) ----
  {
    hipMemsetAsync(stats, 0, 2*FIN*sizeof(float), stream);
    dim3 bg(200, 1);
    k_bnstats<float><<<bg,256,0,stream>>>(FP(0), stats, FIN);
    k_bnfin<<<1,256,0,stream>>>(stats, FP(IG[0]), FP(IB[0]), scale, shift, FIN);
    k_cast<<<G((long)NN*KP1),256,0,stream>>>(FP(0), xbf);
    dim3 ft(KP1/32, 64);
    k_foldT<<<ft,256,0,stream>>>(FP(IWg[0]), FP(ILw[0]), scale, Wt, FIN, KP1);
    k_cinit<<<8,256,0,stream>>>(FP(ILb[0]), cst);
    dim3 cg(32, (FIN+127)/128);
    k_const<<<cg,256,0,stream>>>(FP(IWg[0]), FP(ILw[0]), shift, cst, FIN);
    k_we16<<<40,256,0,stream>>>(FP(IWe[0]), We16);
    k_gemm<<<gg,512,0,stream>>>(xbf, KP1, Wt, cst, buf0, bufA);
    k_sdot<<<gsd,256,0,stream>>>(buf0, FP(IAttn[0]), ssrc, sdst);
    k_q<<<1,64,0,stream>>>(FP(IWe[0]), FP(IAttn[0]), qbuf);
    k_logits<<<G(EE),256,0,stream>>>(ei, FP(2), qbuf, FP(IAt[0]), ssrc, sdst, L);
    k_mden<<<gnd,128,0,stream>>>(iptr, eid, FP(2), L, cw, dv4);
    k_gath<<<(NN+NB-1)/NB,256,0,stream>>>(buf0, ei, iptr, eid, L, cw, dv4,
                                          We16, FP(ICb[0]), bufA);
  }
  // ---- layer 2 (A = bufA, K=1024) ----
  {
    k_bnstats8<<<256,256,0,stream>>>(bufA, part);
    k_pred<<<8,256,0,stream>>>(part, stats);
    k_bnfin<<<4,256,0,stream>>>(stats, FP(IG[1]), FP(IB[1]), scale, shift, HID);
    dim3 ft(HID/32, 64);
    k_foldT<<<ft,256,0,stream>>>(FP(IWg[1]), FP(ILw[1]), scale, Wt, HID, HID);
    k_cinit<<<8,256,0,stream>>>(FP(ILb[1]), cst);
    dim3 cg(32, HID/128);
    k_const<<<cg,256,0,stream>>>(FP(IWg[1]), FP(ILw[1]), shift, cst, HID);
    k_we16<<<40,256,0,stream>>>(FP(IWe[1]), We16);
    k_gemm<<<gg,512,0,stream>>>(bufA, HID, Wt, cst, buf0, bufB);
    k_sdot<<<gsd,256,0,stream>>>(buf0, FP(IAttn[1]), ssrc, sdst);
    k_q<<<1,64,0,stream>>>(FP(IWe[1]), FP(IAttn[1]), qbuf);
    k_logits<<<G(EE),256,0,stream>>>(ei, FP(2), qbuf, FP(IAt[1]), ssrc, sdst, L);
    k_mden<<<gnd,128,0,stream>>>(iptr, eid, FP(2), L, cw, dv4);
    k_gath<<<(NN+NB-1)/NB,256,0,stream>>>(buf0, ei, iptr, eid, L, cw, dv4,
                                          We16, FP(ICb[1]), bufB);
  }

  // ---- layer 3 (input = bufB) ----
  k_bnstats8<<<256,256,0,stream>>>(bufB, part);
  k_pred<<<8,256,0,stream>>>(part, stats);
  k_bnfin<<<4,256,0,stream>>>(stats, FP(IG[2]), FP(IB[2]), scale, shift, HID);
  k_c4init<<<1,64,0,stream>>>(FP(ILb[2]), c4);
  k_fold3<<<HID/256,256,0,stream>>>(FP(IWg[2]), FP(ILw[2]), scale, shift, W4, c4);
  k_n3<<<NN/4,256,0,stream>>>(bufB, W4, c4, FP(IAttn[2]), hg3, lin3, ssrc, sdst);
  k_logits3<<<G(EE),256,0,stream>>>(ei, FP(2), FP(IWe[2]), FP(IAttn[2]), FP(IAt[2]), ssrc, sdst, L);
  k_mden3<<<gnd,128,0,stream>>>(iptr, eid, FP(2), L, cw, dv4);
  k_gather3<<<gnd,128,0,stream>>>(ei, iptr, eid, L, cw, dv4, hg3,
                                  FP(IWe[2]), lin3, FP(ICb[2]), (float*)d_out);
}